// Round 1
// baseline (471.160 us; speedup 1.0000x reference)
//
#include <hip/hip_runtime.h>
#include <stdint.h>

typedef unsigned short u16;
typedef float f32x4 __attribute__((ext_vector_type(4)));
typedef __bf16 bf16x8 __attribute__((ext_vector_type(8)));
typedef u16 u16x8 __attribute__((ext_vector_type(8)));
typedef u16 u16x4 __attribute__((ext_vector_type(4)));

#define SCALE_QK 0.35355339059327373f

__device__ __forceinline__ u16 f2bf(float f) {
  union { float f; uint32_t u; } x; x.f = f;
  uint32_t r = x.u + 0x7fffu + ((x.u >> 16) & 1u);
  return (u16)(r >> 16);
}
__device__ __forceinline__ float bf2f(u16 h) {
  union { uint32_t u; float f; } x; x.u = ((uint32_t)h) << 16;
  return x.f;
}
__device__ __forceinline__ void gload16(const void* g, void* l) {
  __builtin_amdgcn_global_load_lds((const __attribute__((address_space(1))) void*)g,
                                   (__attribute__((address_space(3))) void*)l, 16, 0, 0);
}

// ---------------- weight transpose + bf16:  Wt[w][n][k] = bf16(W_w[k][n]) ----------------
__global__ __launch_bounds__(256) void k_wt(const float* __restrict__ Wq, const float* __restrict__ Wk,
                                            const float* __restrict__ Wv, u16* __restrict__ Wt) {
  __shared__ float tile[64][65];
  const int bx = blockIdx.x;
  const int w = bx >> 8, tn = (bx >> 4) & 15, tk = bx & 15;
  const float* W = (w == 0) ? Wq : ((w == 1) ? Wk : Wv);
  const int t = threadIdx.x;
  const int r = t >> 2, c0 = (t & 3) * 16;
  const float* src = W + (size_t)(tk * 64 + r) * 1024 + tn * 64 + c0;
#pragma unroll
  for (int j = 0; j < 16; j += 4) {
    f32x4 x = *(const f32x4*)(src + j);
    tile[r][c0 + j + 0] = x[0]; tile[r][c0 + j + 1] = x[1];
    tile[r][c0 + j + 2] = x[2]; tile[r][c0 + j + 3] = x[3];
  }
  __syncthreads();
  u16* dst = Wt + (size_t)(w * 1024 + tn * 64 + r) * 1024 + tk * 64 + c0;
#pragma unroll
  for (int j = 0; j < 16; ++j) dst[j] = f2bf(tile[c0 + j][r]);
}

// ---------------- hidden -> bf16 ----------------
__global__ __launch_bounds__(256) void k_hb(const float* __restrict__ in, u16* __restrict__ out) {
  const size_t i = ((size_t)blockIdx.x * 256 + threadIdx.x) * 8;
  f32x4 v0 = *(const f32x4*)(in + i);
  f32x4 v1 = *(const f32x4*)(in + i + 4);
  u16x8 o;
  o[0] = f2bf(v0[0]); o[1] = f2bf(v0[1]); o[2] = f2bf(v0[2]); o[3] = f2bf(v0[3]);
  o[4] = f2bf(v1[0]); o[5] = f2bf(v1[1]); o[6] = f2bf(v1[2]); o[7] = f2bf(v1[3]);
  *(u16x8*)(out + i) = o;
}

// ---------------- fused QKV GEMM: C[16384,3072] = hidden_bf16 @ W, epilogue bias+scale, bf16 out [B,H,S,D] ----------------
__global__ __launch_bounds__(256) void k_gemm(const u16* __restrict__ A, const u16* __restrict__ Bt,
                                              const float* __restrict__ bq, const float* __restrict__ bk,
                                              const float* __restrict__ bv,
                                              u16* __restrict__ oq, u16* __restrict__ ok, u16* __restrict__ ov) {
  __shared__ __align__(16) u16 As[128 * 32];
  __shared__ __align__(16) u16 Bs[128 * 32];
  const int t = threadIdx.x;
  const int lane = t & 63;
  const int wv = t >> 6;
  const int wr = wv >> 1, wc = wv & 1;
  const int bm = blockIdx.x, bn = blockIdx.y;

  const u16* aSrc = A + ((size_t)(bm * 128 + wv * 32 + (lane >> 2)) << 10) + ((lane & 3) << 3);
  const u16* bSrc = Bt + ((size_t)(bn * 128 + wv * 32 + (lane >> 2)) << 10) + ((lane & 3) << 3);
  u16* aDst0 = &As[(wv * 32) * 32];
  u16* aDst1 = &As[(wv * 32 + 16) * 32];
  u16* bDst0 = &Bs[(wv * 32) * 32];
  u16* bDst1 = &Bs[(wv * 32 + 16) * 32];

  f32x4 acc[4][4];
#pragma unroll
  for (int m = 0; m < 4; ++m)
#pragma unroll
    for (int n = 0; n < 4; ++n) acc[m][n] = (f32x4){0.f, 0.f, 0.f, 0.f};

  const int kg = (lane >> 4) << 3;
  const int rA = (wr << 6) + (lane & 15);
  const int rB = (wc << 6) + (lane & 15);

  for (int kt = 0; kt < 32; ++kt) {
    const int ko = kt << 5;
    gload16(aSrc + ko, aDst0);
    gload16(aSrc + ko + (16 << 10), aDst1);
    gload16(bSrc + ko, bDst0);
    gload16(bSrc + ko + (16 << 10), bDst1);
    __syncthreads();
    bf16x8 af[4], bfr[4];
#pragma unroll
    for (int m = 0; m < 4; ++m) af[m] = *reinterpret_cast<const bf16x8*>(&As[(rA + m * 16) * 32 + kg]);
#pragma unroll
    for (int n = 0; n < 4; ++n) bfr[n] = *reinterpret_cast<const bf16x8*>(&Bs[(rB + n * 16) * 32 + kg]);
#pragma unroll
    for (int m = 0; m < 4; ++m)
#pragma unroll
      for (int n = 0; n < 4; ++n)
        acc[m][n] = __builtin_amdgcn_mfma_f32_16x16x32_bf16(af[m], bfr[n], acc[m][n], 0, 0, 0);
    __syncthreads();
  }

  const int which = bn >> 3;
  const float* bias = (which == 0) ? bq : ((which == 1) ? bk : bv);
  u16* op = (which == 0) ? oq : ((which == 1) ? ok : ov);
  const float scl = (which < 2) ? SCALE_QK : 1.0f;
  const int colBase = ((bn & 7) << 7) + (wc << 6) + (lane & 15);
  const int rowBase = (bm << 7) + (wr << 6) + ((lane >> 4) << 2);
#pragma unroll
  for (int n = 0; n < 4; ++n) {
    const int c = colBase + n * 16;
    const float bb = bias[c];
    const int h = c >> 6, d = c & 63;
#pragma unroll
    for (int m = 0; m < 4; ++m) {
#pragma unroll
      for (int r = 0; r < 4; ++r) {
        const int gm = rowBase + m * 16 + r;
        const int b = gm >> 12, s = gm & 4095;
        const float val = (acc[m][n][r] + bb) * scl;
        const size_t idx = (((size_t)b * 16 + h) * 4096 + s) * 64 + d;
        op[idx] = f2bf(val);
      }
    }
  }
}

// ---------------- landmarks: ql/kl [BH,64,64] f32 = segment means ----------------
__global__ __launch_bounds__(64) void k_lm(const u16* __restrict__ q, const u16* __restrict__ k,
                                           float* __restrict__ ql, float* __restrict__ kl) {
  const int bid = blockIdx.x;  // bh*64 + l
  const int d = threadIdx.x;
  const u16* qp = q + (size_t)bid * 4096 + d;
  const u16* kp = k + (size_t)bid * 4096 + d;
  float sq = 0.f, sk = 0.f;
#pragma unroll 4
  for (int m = 0; m < 64; ++m) { sq += bf2f(qp[m * 64]); sk += bf2f(kp[m * 64]); }
  ql[(size_t)bid * 64 + d] = sq * 0.015625f;
  kl[(size_t)bid * 64 + d] = sk * 0.015625f;
}

// ---------------- kernel_2 = softmax(ql@kl^T); write k2t (transposed) + per-bh max colsum ----------------
__global__ __launch_bounds__(256) void k_k2(const float* __restrict__ ql, const float* __restrict__ kl,
                                            float* __restrict__ k2t, float* __restrict__ colmax) {
  __shared__ __align__(16) float qlT[64 * 68];
  __shared__ __align__(16) float klT[64 * 68];
  __shared__ __align__(16) float sc[64 * 68];
  const int bh = blockIdx.x, t = threadIdx.x;
  {
    const int r = t >> 2, c0 = (t & 3) * 16;
    const float* qp = ql + (size_t)bh * 4096 + r * 64 + c0;
    const float* kp = kl + (size_t)bh * 4096 + r * 64 + c0;
#pragma unroll
    for (int j = 0; j < 16; ++j) { qlT[(c0 + j) * 68 + r] = qp[j]; klT[(c0 + j) * 68 + r] = kp[j]; }
  }
  __syncthreads();
  {
    const int mg = (t >> 4) * 4, lg = (t & 15) * 4;
    float acc[4][4];
#pragma unroll
    for (int i = 0; i < 4; ++i)
#pragma unroll
      for (int j = 0; j < 4; ++j) acc[i][j] = 0.f;
    for (int d0 = 0; d0 < 64; ++d0) {
      f32x4 x = *(const f32x4*)&qlT[d0 * 68 + mg];
      f32x4 y = *(const f32x4*)&klT[d0 * 68 + lg];
#pragma unroll
      for (int i = 0; i < 4; ++i)
#pragma unroll
        for (int j = 0; j < 4; ++j) acc[i][j] += x[i] * y[j];
    }
#pragma unroll
    for (int i = 0; i < 4; ++i)
#pragma unroll
      for (int j = 0; j < 4; ++j) sc[(mg + i) * 68 + lg + j] = acc[i][j];
  }
  __syncthreads();
  if (t < 64) {  // softmax row t over 64 cols
    float mx = -1e30f;
    for (int l = 0; l < 64; ++l) mx = fmaxf(mx, sc[t * 68 + l]);
    float sum = 0.f;
    for (int l = 0; l < 64; ++l) { float e = __expf(sc[t * 68 + l] - mx); sc[t * 68 + l] = e; sum += e; }
    const float inv = 1.0f / sum;
    for (int l = 0; l < 64; ++l) sc[t * 68 + l] *= inv;
  }
  __syncthreads();
  {
    const int r = t >> 2, c0 = (t & 3) * 16;
    float* ot = k2t + (size_t)bh * 4096 + r * 64 + c0;
#pragma unroll
    for (int j = 0; j < 16; ++j) ot[j] = sc[(c0 + j) * 68 + r];  // k2t[l][m] = k2[m][l]
  }
  if (t < 64) {
    float s = 0.f;
    for (int m = 0; m < 64; ++m) s += sc[m * 68 + t];
    for (int off = 32; off; off >>= 1) s = fmaxf(s, __shfl_down(s, off, 64));
    if (t == 0) colmax[bh] = s;
  }
}

// ---------------- global max of 64 colmax values ----------------
__global__ __launch_bounds__(64) void k_max(const float* __restrict__ colmax, float* __restrict__ gmax) {
  const int t = threadIdx.x;
  float v = colmax[t];
  for (int off = 32; off; off >>= 1) v = fmaxf(v, __shfl_down(v, off, 64));
  if (t == 0) *gmax = v;
}

// ---------------- iterative pinv (6 iters, f32, per-bh block) ----------------
__global__ __launch_bounds__(256) void k_pinv(const float* __restrict__ k2t, const float* __restrict__ gmaxp,
                                              float* __restrict__ pinv) {
  __shared__ float valN[4096];
  __shared__ float kvT[4096];
  __shared__ float t1N[4096];
  __shared__ float t2N[4096];
  const int bh = blockIdx.x, t = threadIdx.x;
  const float* aT = k2t + (size_t)bh * 4096;  // aT[k][r] = a[r][k]
  const float ginv = 1.0f / gmaxp[0];
  const int rt = t >> 2, ct0 = (t & 3) * 16;
  {
    const float* p = aT + rt * 64 + ct0;  // val0[r][c] = a[c][r]/g = aT[r][c]/g
#pragma unroll
    for (int j = 0; j < 16; ++j) valN[rt * 64 + ct0 + j] = p[j] * ginv;
  }
  __syncthreads();
  const int rg = (t >> 4) * 4, cg = (t & 15) * 4;
  float acc[4][4];
  for (int it = 0; it < 6; ++it) {
    // kv = a@val, stored transposed into kvT
#pragma unroll
    for (int i = 0; i < 4; ++i)
#pragma unroll
      for (int j = 0; j < 4; ++j) acc[i][j] = 0.f;
    for (int k = 0; k < 64; ++k) {
      f32x4 x = *(const f32x4*)(aT + k * 64 + rg);
      f32x4 y = *(const f32x4*)&valN[k * 64 + cg];
#pragma unroll
      for (int i = 0; i < 4; ++i)
#pragma unroll
        for (int j = 0; j < 4; ++j) acc[i][j] += x[i] * y[j];
    }
#pragma unroll
    for (int i = 0; i < 4; ++i)
#pragma unroll
      for (int j = 0; j < 4; ++j) kvT[(cg + j) * 64 + rg + i] = acc[i][j];
    __syncthreads();
    // t1 = 7I - kv
#pragma unroll
    for (int j = 0; j < 16; ++j) {
      const int c = ct0 + j;
      t1N[rt * 64 + c] = ((rt == c) ? 7.0f : 0.0f) - kvT[c * 64 + rt];
    }
    __syncthreads();
    // t2 = 15I - kv@t1
#pragma unroll
    for (int i = 0; i < 4; ++i)
#pragma unroll
      for (int j = 0; j < 4; ++j) acc[i][j] = 0.f;
    for (int k = 0; k < 64; ++k) {
      f32x4 x = *(const f32x4*)&kvT[k * 64 + rg];
      f32x4 y = *(const f32x4*)&t1N[k * 64 + cg];
#pragma unroll
      for (int i = 0; i < 4; ++i)
#pragma unroll
        for (int j = 0; j < 4; ++j) acc[i][j] += x[i] * y[j];
    }
#pragma unroll
    for (int i = 0; i < 4; ++i)
#pragma unroll
      for (int j = 0; j < 4; ++j) {
        const int r_ = rg + i, c_ = cg + j;
        t2N[r_ * 64 + c_] = ((r_ == c_) ? 15.0f : 0.0f) - acc[i][j];
      }
    __syncthreads();
    // t1 = 13I - kv@t2
#pragma unroll
    for (int i = 0; i < 4; ++i)
#pragma unroll
      for (int j = 0; j < 4; ++j) acc[i][j] = 0.f;
    for (int k = 0; k < 64; ++k) {
      f32x4 x = *(const f32x4*)&kvT[k * 64 + rg];
      f32x4 y = *(const f32x4*)&t2N[k * 64 + cg];
#pragma unroll
      for (int i = 0; i < 4; ++i)
#pragma unroll
        for (int j = 0; j < 4; ++j) acc[i][j] += x[i] * y[j];
    }
#pragma unroll
    for (int i = 0; i < 4; ++i)
#pragma unroll
      for (int j = 0; j < 4; ++j) {
        const int r_ = rg + i, c_ = cg + j;
        t1N[r_ * 64 + c_] = ((r_ == c_) ? 13.0f : 0.0f) - acc[i][j];
      }
    __syncthreads();
    // t2 = val^T
#pragma unroll
    for (int j = 0; j < 16; ++j) t2N[(ct0 + j) * 64 + rt] = valN[rt * 64 + ct0 + j];
    __syncthreads();
    // val = 0.25 * val@t1  (X from t2N = val^T)
#pragma unroll
    for (int i = 0; i < 4; ++i)
#pragma unroll
      for (int j = 0; j < 4; ++j) acc[i][j] = 0.f;
    for (int k = 0; k < 64; ++k) {
      f32x4 x = *(const f32x4*)&t2N[k * 64 + rg];
      f32x4 y = *(const f32x4*)&t1N[k * 64 + cg];
#pragma unroll
      for (int i = 0; i < 4; ++i)
#pragma unroll
        for (int j = 0; j < 4; ++j) acc[i][j] += x[i] * y[j];
    }
#pragma unroll
    for (int i = 0; i < 4; ++i)
#pragma unroll
      for (int j = 0; j < 4; ++j) valN[(rg + i) * 64 + cg + j] = 0.25f * acc[i][j];
    __syncthreads();
  }
  {
    float* o = pinv + (size_t)bh * 4096 + rt * 64 + ct0;
#pragma unroll
    for (int j = 0; j < 16; ++j) o[j] = valN[rt * 64 + ct0 + j];
  }
}

// ---------------- scores3[bh][l][s] = ql[l]·k[s] ----------------
__global__ __launch_bounds__(256) void k_s3(const float* __restrict__ ql, const u16* __restrict__ kb,
                                            float* __restrict__ s3) {
  __shared__ __align__(16) float qlT[64 * 68];
  __shared__ __align__(16) float kT[64 * 68];
  const int bid = blockIdx.x;
  const int bh = bid >> 6, st = bid & 63;
  const int t = threadIdx.x;
  {
    const int r = t >> 2, c0 = (t & 3) * 16;
    const float* qp = ql + (size_t)bh * 4096 + r * 64 + c0;
#pragma unroll
    for (int j = 0; j < 16; ++j) qlT[(c0 + j) * 68 + r] = qp[j];
    const u16* kp = kb + ((size_t)bh * 4096 + st * 64 + r) * 64 + c0;
    u16x8 h0 = *(const u16x8*)kp;
    u16x8 h1 = *(const u16x8*)(kp + 8);
#pragma unroll
    for (int j = 0; j < 8; ++j) { kT[(c0 + j) * 68 + r] = bf2f(h0[j]); kT[(c0 + 8 + j) * 68 + r] = bf2f(h1[j]); }
  }
  __syncthreads();
  const int lg = (t >> 4) * 4, sg = (t & 15) * 4;
  float acc[4][4];
#pragma unroll
  for (int i = 0; i < 4; ++i)
#pragma unroll
    for (int j = 0; j < 4; ++j) acc[i][j] = 0.f;
  for (int d0 = 0; d0 < 64; ++d0) {
    f32x4 x = *(const f32x4*)&qlT[d0 * 68 + lg];
    f32x4 y = *(const f32x4*)&kT[d0 * 68 + sg];
#pragma unroll
    for (int i = 0; i < 4; ++i)
#pragma unroll
      for (int j = 0; j < 4; ++j) acc[i][j] += x[i] * y[j];
  }
#pragma unroll
  for (int i = 0; i < 4; ++i) {
    f32x4 o = {acc[i][0], acc[i][1], acc[i][2], acc[i][3]};
    *(f32x4*)&s3[((size_t)bh * 64 + lg + i) * 4096 + st * 64 + sg] = o;
  }
}

// ---------------- in-place row softmax over S=4096 ----------------
__global__ __launch_bounds__(256) void k_sm3(float* __restrict__ s3) {
  __shared__ float red[8];
  const int t = threadIdx.x;
  float* p = s3 + (size_t)blockIdx.x * 4096;
  f32x4 v[4];
#pragma unroll
  for (int j = 0; j < 4; ++j) v[j] = *(const f32x4*)(p + (j * 256 + t) * 4);
  float mx = -1e30f;
#pragma unroll
  for (int j = 0; j < 4; ++j)
#pragma unroll
    for (int c = 0; c < 4; ++c) mx = fmaxf(mx, v[j][c]);
  for (int off = 32; off; off >>= 1) mx = fmaxf(mx, __shfl_down(mx, off, 64));
  if ((t & 63) == 0) red[t >> 6] = mx;
  __syncthreads();
  mx = fmaxf(fmaxf(red[0], red[1]), fmaxf(red[2], red[3]));
  float sum = 0.f;
#pragma unroll
  for (int j = 0; j < 4; ++j)
#pragma unroll
    for (int c = 0; c < 4; ++c) { float e = __expf(v[j][c] - mx); v[j][c] = e; sum += e; }
  for (int off = 32; off; off >>= 1) sum += __shfl_down(sum, off, 64);
  if ((t & 63) == 0) red[4 + (t >> 6)] = sum;
  __syncthreads();
  sum = (red[4] + red[5]) + (red[6] + red[7]);
  const float inv = 1.0f / sum;
#pragma unroll
  for (int j = 0; j < 4; ++j) {
    v[j] *= inv;
    *(f32x4*)(p + (j * 256 + t) * 4) = v[j];
  }
}

// ---------------- new_value partials: nv[bh][l][d] += P[l][s-range]·v[s-range][d] ----------------
__global__ __launch_bounds__(256) void k_nv(const float* __restrict__ s3, const u16* __restrict__ vb,
                                            float* __restrict__ nv) {
  __shared__ __align__(16) float PT[64 * 68];
  __shared__ __align__(16) float VN[64 * 68];
  const int bh = blockIdx.x >> 3, scn = blockIdx.x & 7;
  const int t = threadIdx.x;
  const int lg = (t >> 4) * 4, dg = (t & 15) * 4;
  float acc[4][4];
#pragma unroll
  for (int i = 0; i < 4; ++i)
#pragma unroll
    for (int j = 0; j < 4; ++j) acc[i][j] = 0.f;
  for (int sub = 0; sub < 8; ++sub) {
    const int s0 = scn * 512 + sub * 64;
    __syncthreads();
    {
      const int r = t >> 2, c0 = (t & 3) * 16;
      const float* pp = s3 + ((size_t)bh * 64 + r) * 4096 + s0 + c0;
#pragma unroll
      for (int j = 0; j < 16; ++j) PT[(c0 + j) * 68 + r] = pp[j];
      const u16* vp = vb + ((size_t)bh * 4096 + s0 + r) * 64 + c0;
      u16x8 h0 = *(const u16x8*)vp, h1 = *(const u16x8*)(vp + 8);
#pragma unroll
      for (int j = 0; j < 8; ++j) { VN[r * 68 + c0 + j] = bf2f(h0[j]); VN[r * 68 + c0 + 8 + j] = bf2f(h1[j]); }
    }
    __syncthreads();
    for (int s = 0; s < 64; ++s) {
      f32x4 x = *(const f32x4*)&PT[s * 68 + lg];
      f32x4 y = *(const f32x4*)&VN[s * 68 + dg];
#pragma unroll
      for (int i = 0; i < 4; ++i)
#pragma unroll
        for (int j = 0; j < 4; ++j) acc[i][j] += x[i] * y[j];
    }
  }
#pragma unroll
  for (int i = 0; i < 4; ++i)
#pragma unroll
    for (int j = 0; j < 4; ++j)
      atomicAdd(&nv[(size_t)bh * 4096 + (lg + i) * 64 + dg + j], acc[i][j]);
}

// ---------------- M = pinv @ nv ----------------
__global__ __launch_bounds__(256) void k_pnv(const float* __restrict__ pinv, const float* __restrict__ nv,
                                             float* __restrict__ M) {
  __shared__ __align__(16) float XT[64 * 68];
  __shared__ __align__(16) float Y[64 * 68];
  const int bh = blockIdx.x, t = threadIdx.x;
  {
    const int r = t >> 2, c0 = (t & 3) * 16;
    const float* pp = pinv + (size_t)bh * 4096 + r * 64 + c0;
#pragma unroll
    for (int j = 0; j < 16; ++j) XT[(c0 + j) * 68 + r] = pp[j];
    const float* np = nv + (size_t)bh * 4096 + r * 64 + c0;
#pragma unroll
    for (int j = 0; j < 16; j += 4) *(f32x4*)&Y[r * 68 + c0 + j] = *(const f32x4*)(np + j);
  }
  __syncthreads();
  const int rg = (t >> 4) * 4, cg = (t & 15) * 4;
  float acc[4][4];
#pragma unroll
  for (int i = 0; i < 4; ++i)
#pragma unroll
    for (int j = 0; j < 4; ++j) acc[i][j] = 0.f;
  for (int k = 0; k < 64; ++k) {
    f32x4 x = *(const f32x4*)&XT[k * 68 + rg];
    f32x4 y = *(const f32x4*)&Y[k * 68 + cg];
#pragma unroll
    for (int i = 0; i < 4; ++i)
#pragma unroll
      for (int j = 0; j < 4; ++j) acc[i][j] += x[i] * y[j];
  }
#pragma unroll
  for (int i = 0; i < 4; ++i) {
    f32x4 o = {acc[i][0], acc[i][1], acc[i][2], acc[i][3]};
    *(f32x4*)&M[(size_t)bh * 4096 + (rg + i) * 64 + cg] = o;
  }
}

// ---------------- final: softmax(q·kl^T) @ M + depthwise conv, write out ----------------
__global__ __launch_bounds__(256) void k_out(const u16* __restrict__ qb, const u16* __restrict__ vb,
                                             const float* __restrict__ kl, const float* __restrict__ Mg,
                                             const float* __restrict__ cw, float* __restrict__ out) {
  __shared__ __align__(16) float sc[64 * 68];
  __shared__ __align__(16) float bufA[64 * 68];  // qT -> M
  __shared__ __align__(16) float bufB[64 * 68];  // klT -> scT
  __shared__ __align__(16) u16 vtile[96 * 68];
  __shared__ float wsh[33];
  const int bid = blockIdx.x;
  const int bh = bid >> 6, st = bid & 63;
  const int b = bh >> 4, h = bh & 15;
  const int t = threadIdx.x;
  const int sbase = st * 64;
  // phase 1: stage qT [d][s], klT [d][l]
  {
    const int r = t >> 2, c0 = (t & 3) * 16;
    const u16* qp = qb + ((size_t)bh * 4096 + sbase + r) * 64 + c0;
    u16x8 h0 = *(const u16x8*)qp, h1 = *(const u16x8*)(qp + 8);
#pragma unroll
    for (int j = 0; j < 8; ++j) { bufA[(c0 + j) * 68 + r] = bf2f(h0[j]); bufA[(c0 + 8 + j) * 68 + r] = bf2f(h1[j]); }
    const float* kp = kl + (size_t)bh * 4096 + r * 64 + c0;
#pragma unroll
    for (int j = 0; j < 16; ++j) bufB[(c0 + j) * 68 + r] = kp[j];
  }
  if (t < 33) wsh[t] = cw[h * 33 + t];
  __syncthreads();
  // scores sc[s][l]
  {
    const int sg = (t >> 4) * 4, lg = (t & 15) * 4;
    float acc[4][4];
#pragma unroll
    for (int i = 0; i < 4; ++i)
#pragma unroll
      for (int j = 0; j < 4; ++j) acc[i][j] = 0.f;
    for (int d0 = 0; d0 < 64; ++d0) {
      f32x4 x = *(const f32x4*)&bufA[d0 * 68 + sg];
      f32x4 y = *(const f32x4*)&bufB[d0 * 68 + lg];
#pragma unroll
      for (int i = 0; i < 4; ++i)
#pragma unroll
        for (int j = 0; j < 4; ++j) acc[i][j] += x[i] * y[j];
    }
#pragma unroll
    for (int i = 0; i < 4; ++i)
#pragma unroll
      for (int j = 0; j < 4; ++j) sc[(sg + i) * 68 + lg + j] = acc[i][j];
  }
  __syncthreads();
  // wave0: row softmax -> transposed into bufB (scT[l][s])
  if (t < 64) {
    float mx = -1e30f;
    for (int l = 0; l < 64; ++l) mx = fmaxf(mx, sc[t * 68 + l]);
    float sum = 0.f;
    for (int l = 0; l < 64; ++l) { float e = __expf(sc[t * 68 + l] - mx); bufB[l * 68 + t] = e; sum += e; }
    const float inv = 1.0f / sum;
    for (int l = 0; l < 64; ++l) bufB[l * 68 + t] *= inv;
  }
  // all threads: stage M into bufA, v into vtile
  {
    const int r = t >> 2, c0 = (t & 3) * 16;
    const float* mp = Mg + (size_t)bh * 4096 + r * 64 + c0;
#pragma unroll
    for (int j = 0; j < 16; j += 4) *(f32x4*)&bufA[r * 68 + c0 + j] = *(const f32x4*)(mp + j);
  }
  for (int idx = t; idx < 96 * 8; idx += 256) {
    const int row = idx >> 3, ch = idx & 7;
    const int sgl = sbase + row - 16;
    u16x8 val = {0, 0, 0, 0, 0, 0, 0, 0};
    if (sgl >= 0 && sgl < 4096) val = *(const u16x8*)(vb + ((size_t)bh * 4096 + sgl) * 64 + ch * 8);
    u16x4 lo = {val[0], val[1], val[2], val[3]};
    u16x4 hi = {val[4], val[5], val[6], val[7]};
    *(u16x4*)&vtile[row * 68 + ch * 8] = lo;
    *(u16x4*)&vtile[row * 68 + ch * 8 + 4] = hi;
  }
  __syncthreads();
  // ctx = scT^T @ M + conv, write out
  {
    const int sg = (t >> 4) * 4, dg = (t & 15) * 4;
    float acc[4][4];
#pragma unroll
    for (int i = 0; i < 4; ++i)
#pragma unroll
      for (int j = 0; j < 4; ++j) acc[i][j] = 0.f;
    for (int l = 0; l < 64; ++l) {
      f32x4 x = *(const f32x4*)&bufB[l * 68 + sg];
      f32x4 y = *(const f32x4*)&bufA[l * 68 + dg];
#pragma unroll
      for (int i = 0; i < 4; ++i)
#pragma unroll
        for (int j = 0; j < 4; ++j) acc[i][j] += x[i] * y[j];
    }
    for (int jt = 0; jt < 33; ++jt) {
      const float w = wsh[jt];
#pragma unroll
      for (int i = 0; i < 4; ++i) {
        u16x4 hv = *(const u16x4*)&vtile[(sg + i + jt) * 68 + dg];
        acc[i][0] += bf2f(hv[0]) * w;
        acc[i][1] += bf2f(hv[1]) * w;
        acc[i][2] += bf2f(hv[2]) * w;
        acc[i][3] += bf2f(hv[3]) * w;
      }
    }
#pragma unroll
    for (int i = 0; i < 4; ++i) {
      const int sgl = sbase + sg + i;
      f32x4 o = {acc[i][0], acc[i][1], acc[i][2], acc[i][3]};
      *(f32x4*)&out[((size_t)b * 4096 + sgl) * 1024 + h * 64 + dg] = o;
    }
  }
}

extern "C" void kernel_launch(void* const* d_in, const int* in_sizes, int n_in,
                              void* d_out, int out_size, void* d_ws, size_t ws_size,
                              hipStream_t stream) {
  const float* hidden = (const float*)d_in[0];
  const float* Wq = (const float*)d_in[1];
  const float* bq = (const float*)d_in[2];
  const float* Wk = (const float*)d_in[3];
  const float* bk = (const float*)d_in[4];
  const float* Wv = (const float*)d_in[5];
  const float* bv = (const float*)d_in[6];
  const float* cw = (const float*)d_in[7];
  float* out = (float*)d_out;

  char* ws = (char*)d_ws;
  u16* qb = (u16*)(ws);
  u16* kb = (u16*)(ws + (size_t)33554432);
  u16* vb = (u16*)(ws + (size_t)67108864);
  float* ql = (float*)(ws + (size_t)100663296);
  float* kl = (float*)(ws + (size_t)101711872);
  float* k2t = (float*)(ws + (size_t)102760448);
  float* pinvb = (float*)(ws + (size_t)103809024);
  float* nv = (float*)(ws + (size_t)104857600);
  float* Mb = (float*)(ws + (size_t)105906176);
  float* stats = (float*)(ws + (size_t)106954752);
  u16* hb = (u16*)(ws + (size_t)106955264);      // 32MB, dead after k_gemm
  u16* wt = (u16*)(ws + (size_t)140509696);      // 6MB,  dead after k_gemm
  float* s3 = (float*)(ws + (size_t)106955264);  // 64MB, overlaps hb+wt

  k_wt<<<768, 256, 0, stream>>>(Wq, Wk, Wv, wt);
  k_hb<<<8192, 256, 0, stream>>>(hidden, hb);
  k_gemm<<<dim3(128, 24), 256, 0, stream>>>(hb, wt, bq, bk, bv, qb, kb, vb);
  k_lm<<<4096, 64, 0, stream>>>(qb, kb, ql, kl);
  k_k2<<<64, 256, 0, stream>>>(ql, kl, k2t, stats);
  k_max<<<1, 64, 0, stream>>>(stats, stats + 64);
  k_pinv<<<64, 256, 0, stream>>>(k2t, stats + 64, pinvb);
  k_s3<<<4096, 256, 0, stream>>>(ql, kb, s3);
  k_sm3<<<4096, 256, 0, stream>>>(s3);
  hipMemsetAsync(nv, 0, (size_t)1048576, stream);
  k_nv<<<512, 256, 0, stream>>>(s3, vb, nv);
  k_pnv<<<64, 256, 0, stream>>>(pinvb, nv, Mb);
  k_out<<<4096, 256, 0, stream>>>(qb, vb, kl, Mb, cw, out);
  (void)in_sizes; (void)n_in; (void)out_size; (void)ws_size;
}

// Round 2
// 390.401 us; speedup vs baseline: 1.2069x; 1.2069x over previous
//
#include <hip/hip_runtime.h>
#include <stdint.h>

typedef unsigned short u16;
typedef float f32x4 __attribute__((ext_vector_type(4)));
typedef __bf16 bf16x8 __attribute__((ext_vector_type(8)));
typedef u16 u16x8 __attribute__((ext_vector_type(8)));
typedef u16 u16x4 __attribute__((ext_vector_type(4)));

#define SCALE_QK 0.35355339059327373f

__device__ __forceinline__ u16 f2bf(float f) {
  union { float f; uint32_t u; } x; x.f = f;
  uint32_t r = x.u + 0x7fffu + ((x.u >> 16) & 1u);
  return (u16)(r >> 16);
}
__device__ __forceinline__ float bf2f(u16 h) {
  union { uint32_t u; float f; } x; x.u = ((uint32_t)h) << 16;
  return x.f;
}
__device__ __forceinline__ void gload16(const void* g, void* l) {
  __builtin_amdgcn_global_load_lds((const __attribute__((address_space(1))) void*)g,
                                   (__attribute__((address_space(3))) void*)l, 16, 0, 0);
}
__device__ __forceinline__ bf16x8 ld_f32_to_bf8(const float* p) {
  f32x4 a = *(const f32x4*)p, b = *(const f32x4*)(p + 4);
  union { u16x8 u; bf16x8 h; } c;
  c.u[0] = f2bf(a[0]); c.u[1] = f2bf(a[1]); c.u[2] = f2bf(a[2]); c.u[3] = f2bf(a[3]);
  c.u[4] = f2bf(b[0]); c.u[5] = f2bf(b[1]); c.u[6] = f2bf(b[2]); c.u[7] = f2bf(b[3]);
  return c.h;
}

// ---------------- weight transpose + bf16:  Wt[w][n][k] = bf16(W_w[k][n]) ----------------
__global__ __launch_bounds__(256) void k_wt(const float* __restrict__ Wq, const float* __restrict__ Wk,
                                            const float* __restrict__ Wv, u16* __restrict__ Wt) {
  __shared__ float tile[64][65];
  const int bx = blockIdx.x;
  const int w = bx >> 8, tn = (bx >> 4) & 15, tk = bx & 15;
  const float* W = (w == 0) ? Wq : ((w == 1) ? Wk : Wv);
  const int t = threadIdx.x;
  const int r = t >> 2, c0 = (t & 3) * 16;
  const float* src = W + (size_t)(tk * 64 + r) * 1024 + tn * 64 + c0;
#pragma unroll
  for (int j = 0; j < 16; j += 4) {
    f32x4 x = *(const f32x4*)(src + j);
    tile[r][c0 + j + 0] = x[0]; tile[r][c0 + j + 1] = x[1];
    tile[r][c0 + j + 2] = x[2]; tile[r][c0 + j + 3] = x[3];
  }
  __syncthreads();
  u16* dst = Wt + (size_t)(w * 1024 + tn * 64 + r) * 1024 + tk * 64 + c0;
#pragma unroll
  for (int j = 0; j < 16; ++j) dst[j] = f2bf(tile[c0 + j][r]);
}

// ---------------- hidden -> bf16 ----------------
__global__ __launch_bounds__(256) void k_hb(const float* __restrict__ in, u16* __restrict__ out) {
  const size_t i = ((size_t)blockIdx.x * 256 + threadIdx.x) * 8;
  f32x4 v0 = *(const f32x4*)(in + i);
  f32x4 v1 = *(const f32x4*)(in + i + 4);
  u16x8 o;
  o[0] = f2bf(v0[0]); o[1] = f2bf(v0[1]); o[2] = f2bf(v0[2]); o[3] = f2bf(v0[3]);
  o[4] = f2bf(v1[0]); o[5] = f2bf(v1[1]); o[6] = f2bf(v1[2]); o[7] = f2bf(v1[3]);
  *(u16x8*)(out + i) = o;
}

// ---------------- fused QKV GEMM: swizzled LDS (source-pre-permuted, rule #21) ----------------
__global__ __launch_bounds__(256) void k_gemm(const u16* __restrict__ A, const u16* __restrict__ Bt,
                                              const float* __restrict__ bq, const float* __restrict__ bk,
                                              const float* __restrict__ bv,
                                              u16* __restrict__ oq, u16* __restrict__ ok, u16* __restrict__ ov) {
  __shared__ __align__(16) u16 As[128 * 32];
  __shared__ __align__(16) u16 Bs[128 * 32];
  const int t = threadIdx.x;
  const int lane = t & 63;
  const int wv = t >> 6;
  const int wr = wv >> 1, wc = wv & 1;
  const int bm = blockIdx.x, bn = blockIdx.y;

  // write-side swizzle: slot gx holds global chunk gx ^ swz(R), swz(R)=(R&3)^((R>>2)&3)
  const int swzW = ((lane >> 2) & 3) ^ ((lane >> 4) & 3);
  const int chW = (((lane & 3) ^ swzW)) << 3;
  const u16* aSrc = A + ((size_t)(bm * 128 + wv * 32 + (lane >> 2)) << 10) + chW;
  const u16* bSrc = Bt + ((size_t)(bn * 128 + wv * 32 + (lane >> 2)) << 10) + chW;
  u16* aDst0 = &As[(wv * 32) * 32];
  u16* aDst1 = &As[(wv * 32 + 16) * 32];
  u16* bDst0 = &Bs[(wv * 32) * 32];
  u16* bDst1 = &Bs[(wv * 32 + 16) * 32];

  f32x4 acc[4][4];
#pragma unroll
  for (int m = 0; m < 4; ++m)
#pragma unroll
    for (int n = 0; n < 4; ++n) acc[m][n] = (f32x4){0.f, 0.f, 0.f, 0.f};

  // read-side: want chunk (lane>>4); read slot (lane>>4)^swz(R) with swz(R)=(lane&3)^((lane>>2)&3)
  const int kgS = (((lane >> 4) ^ (lane & 3) ^ ((lane >> 2) & 3))) << 3;
  const int rA = (wr << 6) + (lane & 15);
  const int rB = (wc << 6) + (lane & 15);

  for (int kt = 0; kt < 32; ++kt) {
    const int ko = kt << 5;
    gload16(aSrc + ko, aDst0);
    gload16(aSrc + ko + (16 << 10), aDst1);
    gload16(bSrc + ko, bDst0);
    gload16(bSrc + ko + (16 << 10), bDst1);
    __syncthreads();
    bf16x8 af[4], bfr[4];
#pragma unroll
    for (int m = 0; m < 4; ++m) af[m] = *reinterpret_cast<const bf16x8*>(&As[(rA + m * 16) * 32 + kgS]);
#pragma unroll
    for (int n = 0; n < 4; ++n) bfr[n] = *reinterpret_cast<const bf16x8*>(&Bs[(rB + n * 16) * 32 + kgS]);
#pragma unroll
    for (int m = 0; m < 4; ++m)
#pragma unroll
      for (int n = 0; n < 4; ++n)
        acc[m][n] = __builtin_amdgcn_mfma_f32_16x16x32_bf16(af[m], bfr[n], acc[m][n], 0, 0, 0);
    __syncthreads();
  }

  const int which = bn >> 3;
  const float* bias = (which == 0) ? bq : ((which == 1) ? bk : bv);
  u16* op = (which == 0) ? oq : ((which == 1) ? ok : ov);
  const float scl = (which < 2) ? SCALE_QK : 1.0f;
  const int colBase = ((bn & 7) << 7) + (wc << 6) + (lane & 15);
  const int rowBase = (bm << 7) + (wr << 6) + ((lane >> 4) << 2);
#pragma unroll
  for (int n = 0; n < 4; ++n) {
    const int c = colBase + n * 16;
    const float bb = bias[c];
    const int h = c >> 6, d = c & 63;
#pragma unroll
    for (int m = 0; m < 4; ++m) {
#pragma unroll
      for (int r = 0; r < 4; ++r) {
        const int gm = rowBase + m * 16 + r;
        const int b = gm >> 12, s = gm & 4095;
        const float val = (acc[m][n][r] + bb) * scl;
        const size_t idx = (((size_t)b * 16 + h) * 4096 + s) * 64 + d;
        op[idx] = f2bf(val);
      }
    }
  }
}

// ---------------- landmarks: ql/kl [BH,64,64] f32 = segment means ----------------
__global__ __launch_bounds__(64) void k_lm(const u16* __restrict__ q, const u16* __restrict__ k,
                                           float* __restrict__ ql, float* __restrict__ kl) {
  const int bid = blockIdx.x;  // bh*64 + l
  const int d = threadIdx.x;
  const u16* qp = q + (size_t)bid * 4096 + d;
  const u16* kp = k + (size_t)bid * 4096 + d;
  float sq = 0.f, sk = 0.f;
#pragma unroll 4
  for (int m = 0; m < 64; ++m) { sq += bf2f(qp[m * 64]); sk += bf2f(kp[m * 64]); }
  ql[(size_t)bid * 64 + d] = sq * 0.015625f;
  kl[(size_t)bid * 64 + d] = sk * 0.015625f;
}

// ---------------- kernel_2 = softmax(ql@kl^T); write k2t (transposed) + per-bh max colsum ----------------
__global__ __launch_bounds__(256) void k_k2(const float* __restrict__ ql, const float* __restrict__ kl,
                                            float* __restrict__ k2t, float* __restrict__ colmax) {
  __shared__ __align__(16) float qlT[64 * 68];
  __shared__ __align__(16) float klT[64 * 68];
  __shared__ __align__(16) float sc[64 * 68];
  const int bh = blockIdx.x, t = threadIdx.x;
  {
    const int r = t >> 2, c0 = (t & 3) * 16;
    const float* qp = ql + (size_t)bh * 4096 + r * 64 + c0;
    const float* kp = kl + (size_t)bh * 4096 + r * 64 + c0;
#pragma unroll
    for (int j = 0; j < 16; ++j) { qlT[(c0 + j) * 68 + r] = qp[j]; klT[(c0 + j) * 68 + r] = kp[j]; }
  }
  __syncthreads();
  {
    const int mg = (t >> 4) * 4, lg = (t & 15) * 4;
    float acc[4][4];
#pragma unroll
    for (int i = 0; i < 4; ++i)
#pragma unroll
      for (int j = 0; j < 4; ++j) acc[i][j] = 0.f;
    for (int d0 = 0; d0 < 64; ++d0) {
      f32x4 x = *(const f32x4*)&qlT[d0 * 68 + mg];
      f32x4 y = *(const f32x4*)&klT[d0 * 68 + lg];
#pragma unroll
      for (int i = 0; i < 4; ++i)
#pragma unroll
        for (int j = 0; j < 4; ++j) acc[i][j] += x[i] * y[j];
    }
#pragma unroll
    for (int i = 0; i < 4; ++i)
#pragma unroll
      for (int j = 0; j < 4; ++j) sc[(mg + i) * 68 + lg + j] = acc[i][j];
  }
  __syncthreads();
  if (t < 64) {
    float mx = -1e30f;
    for (int l = 0; l < 64; ++l) mx = fmaxf(mx, sc[t * 68 + l]);
    float sum = 0.f;
    for (int l = 0; l < 64; ++l) { float e = __expf(sc[t * 68 + l] - mx); sc[t * 68 + l] = e; sum += e; }
    const float inv = 1.0f / sum;
    for (int l = 0; l < 64; ++l) sc[t * 68 + l] *= inv;
  }
  __syncthreads();
  {
    const int r = t >> 2, c0 = (t & 3) * 16;
    float* ot = k2t + (size_t)bh * 4096 + r * 64 + c0;
#pragma unroll
    for (int j = 0; j < 16; ++j) ot[j] = sc[(c0 + j) * 68 + r];
  }
  if (t < 64) {
    float s = 0.f;
    for (int m = 0; m < 64; ++m) s += sc[m * 68 + t];
    for (int off = 32; off; off >>= 1) s = fmaxf(s, __shfl_down(s, off, 64));
    if (t == 0) colmax[bh] = s;
  }
}

// ---------------- global max of 64 colmax values ----------------
__global__ __launch_bounds__(64) void k_max(const float* __restrict__ colmax, float* __restrict__ gmax) {
  const int t = threadIdx.x;
  float v = colmax[t];
  for (int off = 32; off; off >>= 1) v = fmaxf(v, __shfl_down(v, off, 64));
  if (t == 0) *gmax = v;
}

// ---------------- iterative pinv (6 iters, f32, per-bh block) ----------------
__global__ __launch_bounds__(256) void k_pinv(const float* __restrict__ k2t, const float* __restrict__ gmaxp,
                                              float* __restrict__ pinv) {
  __shared__ float valN[4096];
  __shared__ float kvT[4096];
  __shared__ float t1N[4096];
  __shared__ float t2N[4096];
  const int bh = blockIdx.x, t = threadIdx.x;
  const float* aT = k2t + (size_t)bh * 4096;
  const float ginv = 1.0f / gmaxp[0];
  const int rt = t >> 2, ct0 = (t & 3) * 16;
  {
    const float* p = aT + rt * 64 + ct0;
#pragma unroll
    for (int j = 0; j < 16; ++j) valN[rt * 64 + ct0 + j] = p[j] * ginv;
  }
  __syncthreads();
  const int rg = (t >> 4) * 4, cg = (t & 15) * 4;
  float acc[4][4];
  for (int it = 0; it < 6; ++it) {
#pragma unroll
    for (int i = 0; i < 4; ++i)
#pragma unroll
      for (int j = 0; j < 4; ++j) acc[i][j] = 0.f;
    for (int k = 0; k < 64; ++k) {
      f32x4 x = *(const f32x4*)(aT + k * 64 + rg);
      f32x4 y = *(const f32x4*)&valN[k * 64 + cg];
#pragma unroll
      for (int i = 0; i < 4; ++i)
#pragma unroll
        for (int j = 0; j < 4; ++j) acc[i][j] += x[i] * y[j];
    }
#pragma unroll
    for (int i = 0; i < 4; ++i)
#pragma unroll
      for (int j = 0; j < 4; ++j) kvT[(cg + j) * 64 + rg + i] = acc[i][j];
    __syncthreads();
#pragma unroll
    for (int j = 0; j < 16; ++j) {
      const int c = ct0 + j;
      t1N[rt * 64 + c] = ((rt == c) ? 7.0f : 0.0f) - kvT[c * 64 + rt];
    }
    __syncthreads();
#pragma unroll
    for (int i = 0; i < 4; ++i)
#pragma unroll
      for (int j = 0; j < 4; ++j) acc[i][j] = 0.f;
    for (int k = 0; k < 64; ++k) {
      f32x4 x = *(const f32x4*)&kvT[k * 64 + rg];
      f32x4 y = *(const f32x4*)&t1N[k * 64 + cg];
#pragma unroll
      for (int i = 0; i < 4; ++i)
#pragma unroll
        for (int j = 0; j < 4; ++j) acc[i][j] += x[i] * y[j];
    }
#pragma unroll
    for (int i = 0; i < 4; ++i)
#pragma unroll
      for (int j = 0; j < 4; ++j) {
        const int r_ = rg + i, c_ = cg + j;
        t2N[r_ * 64 + c_] = ((r_ == c_) ? 15.0f : 0.0f) - acc[i][j];
      }
    __syncthreads();
#pragma unroll
    for (int i = 0; i < 4; ++i)
#pragma unroll
      for (int j = 0; j < 4; ++j) acc[i][j] = 0.f;
    for (int k = 0; k < 64; ++k) {
      f32x4 x = *(const f32x4*)&kvT[k * 64 + rg];
      f32x4 y = *(const f32x4*)&t2N[k * 64 + cg];
#pragma unroll
      for (int i = 0; i < 4; ++i)
#pragma unroll
        for (int j = 0; j < 4; ++j) acc[i][j] += x[i] * y[j];
    }
#pragma unroll
    for (int i = 0; i < 4; ++i)
#pragma unroll
      for (int j = 0; j < 4; ++j) {
        const int r_ = rg + i, c_ = cg + j;
        t1N[r_ * 64 + c_] = ((r_ == c_) ? 13.0f : 0.0f) - acc[i][j];
      }
    __syncthreads();
#pragma unroll
    for (int j = 0; j < 16; ++j) t2N[(ct0 + j) * 64 + rt] = valN[rt * 64 + ct0 + j];
    __syncthreads();
#pragma unroll
    for (int i = 0; i < 4; ++i)
#pragma unroll
      for (int j = 0; j < 4; ++j) acc[i][j] = 0.f;
    for (int k = 0; k < 64; ++k) {
      f32x4 x = *(const f32x4*)&t2N[k * 64 + rg];
      f32x4 y = *(const f32x4*)&t1N[k * 64 + cg];
#pragma unroll
      for (int i = 0; i < 4; ++i)
#pragma unroll
        for (int j = 0; j < 4; ++j) acc[i][j] += x[i] * y[j];
    }
#pragma unroll
    for (int i = 0; i < 4; ++i)
#pragma unroll
      for (int j = 0; j < 4; ++j) valN[(rg + i) * 64 + cg + j] = 0.25f * acc[i][j];
    __syncthreads();
  }
  {
    float* o = pinv + (size_t)bh * 4096 + rt * 64 + ct0;
#pragma unroll
    for (int j = 0; j < 16; ++j) o[j] = valN[rt * 64 + ct0 + j];
  }
}

// ---------------- s3e: e = exp(ql·k^T) bf16 (no max-sub; scores tiny) + atomic row sums ----------------
__global__ __launch_bounds__(256) void k_s3e(const float* __restrict__ ql, const u16* __restrict__ kb,
                                             u16* __restrict__ s3b, float* __restrict__ rowZ) {
  __shared__ __align__(16) u16 bounce[4][16][72];
  const int bid = blockIdx.x;
  const int bh = bid >> 6, st = bid & 63;
  const int t = threadIdx.x, lane = t & 63, w = t >> 6;
  const int s0 = st * 64;
  const int l15 = lane & 15, kg = (lane >> 4) << 3, rl = (lane >> 4) << 2;
  const int Lbase = w * 16;
  f32x4 acc[4];
#pragma unroll
  for (int n = 0; n < 4; ++n) acc[n] = (f32x4){0.f, 0.f, 0.f, 0.f};
  const float* aRow = ql + (size_t)bh * 4096 + (Lbase + l15) * 64 + kg;
  const u16* bRow = kb + ((size_t)bh * 4096 + s0 + l15) * 64 + kg;
#pragma unroll
  for (int ks = 0; ks < 2; ++ks) {
    bf16x8 af = ld_f32_to_bf8(aRow + ks * 32);
#pragma unroll
    for (int n = 0; n < 4; ++n) {
      bf16x8 bf_ = *reinterpret_cast<const bf16x8*>(bRow + n * 1024 + ks * 32);
      acc[n] = __builtin_amdgcn_mfma_f32_16x16x32_bf16(af, bf_, acc[n], 0, 0, 0);
    }
  }
  float z[4] = {0.f, 0.f, 0.f, 0.f};
#pragma unroll
  for (int n = 0; n < 4; ++n)
#pragma unroll
    for (int r = 0; r < 4; ++r) { float v = __expf(acc[n][r]); acc[n][r] = v; z[r] += v; }
#pragma unroll
  for (int r = 0; r < 4; ++r) {
    float s = z[r];
    s += __shfl_xor(s, 1, 64); s += __shfl_xor(s, 2, 64);
    s += __shfl_xor(s, 4, 64); s += __shfl_xor(s, 8, 64);
    z[r] = s;
  }
  if (l15 == 0) {
#pragma unroll
    for (int r = 0; r < 4; ++r) atomicAdd(&rowZ[bh * 64 + Lbase + rl + r], z[r]);
  }
#pragma unroll
  for (int n = 0; n < 4; ++n)
#pragma unroll
    for (int r = 0; r < 4; ++r)
      bounce[w][rl + r][n * 16 + l15] = f2bf(acc[n][r]);
  __syncthreads();
  const int rr = lane >> 2, cc = (lane & 3) * 16;
  u16* dst = s3b + ((size_t)bh * 64 + Lbase + rr) * 4096 + s0 + cc;
  *(u16x8*)dst = *(const u16x8*)&bounce[w][rr][cc];
  *(u16x8*)(dst + 8) = *(const u16x8*)&bounce[w][rr][cc + 8];
}

// ---------------- nv[l][d] = (1/Z_l)·Σ_s e[l][s]·V[s][d]  (MFMA, VT via LDS transpose) ----------------
__global__ __launch_bounds__(256) void k_nv2(const u16* __restrict__ s3b, const u16* __restrict__ vb,
                                             const float* __restrict__ rowZ, float* __restrict__ nv) {
  __shared__ __align__(16) u16 VT[64][72];
  const int bh = blockIdx.x >> 3, scn = blockIdx.x & 7;
  const int t = threadIdx.x, lane = t & 63, w = t >> 6;
  const int l15 = lane & 15, kg = (lane >> 4) << 3, rl = (lane >> 4) << 2;
  f32x4 acc[4];
#pragma unroll
  for (int n = 0; n < 4; ++n) acc[n] = (f32x4){0.f, 0.f, 0.f, 0.f};
  for (int sub = 0; sub < 8; ++sub) {
    const int s0 = scn * 512 + sub * 64;
    __syncthreads();
    {
      const int sv = lane;
      const int d0 = w * 16;
      const u16* vp = vb + ((size_t)bh * 4096 + s0 + sv) * 64 + d0;
      u16x8 h0 = *(const u16x8*)vp, h1 = *(const u16x8*)(vp + 8);
#pragma unroll
      for (int j = 0; j < 8; ++j) { VT[d0 + j][sv] = h0[j]; VT[d0 + 8 + j][sv] = h1[j]; }
    }
    __syncthreads();
    const u16* aRow = s3b + ((size_t)bh * 64 + w * 16 + l15) * 4096 + s0 + kg;
#pragma unroll
    for (int ks = 0; ks < 2; ++ks) {
      bf16x8 af = *reinterpret_cast<const bf16x8*>(aRow + ks * 32);
#pragma unroll
      for (int n = 0; n < 4; ++n) {
        bf16x8 bf_ = *reinterpret_cast<const bf16x8*>(&VT[n * 16 + l15][kg + ks * 32]);
        acc[n] = __builtin_amdgcn_mfma_f32_16x16x32_bf16(af, bf_, acc[n], 0, 0, 0);
      }
    }
  }
#pragma unroll
  for (int r = 0; r < 4; ++r) {
    const float iz = 1.0f / rowZ[bh * 64 + w * 16 + rl + r];
#pragma unroll
    for (int n = 0; n < 4; ++n)
      atomicAdd(&nv[(size_t)bh * 4096 + (w * 16 + rl + r) * 64 + n * 16 + l15], acc[n][r] * iz);
  }
}

// ---------------- M^T (bf16) = (pinv @ nv)^T ----------------
__global__ __launch_bounds__(256) void k_pnv(const float* __restrict__ pinv, const float* __restrict__ nv,
                                             u16* __restrict__ Mtb) {
  __shared__ __align__(16) float XT[64 * 68];
  __shared__ __align__(16) float Y[64 * 68];
  const int bh = blockIdx.x, t = threadIdx.x;
  {
    const int r = t >> 2, c0 = (t & 3) * 16;
    const float* pp = pinv + (size_t)bh * 4096 + r * 64 + c0;
#pragma unroll
    for (int j = 0; j < 16; ++j) XT[(c0 + j) * 68 + r] = pp[j];
    const float* np = nv + (size_t)bh * 4096 + r * 64 + c0;
#pragma unroll
    for (int j = 0; j < 16; j += 4) *(f32x4*)&Y[r * 68 + c0 + j] = *(const f32x4*)(np + j);
  }
  __syncthreads();
  const int rg = (t >> 4) * 4, cg = (t & 15) * 4;
  float acc[4][4];
#pragma unroll
  for (int i = 0; i < 4; ++i)
#pragma unroll
    for (int j = 0; j < 4; ++j) acc[i][j] = 0.f;
  for (int k = 0; k < 64; ++k) {
    f32x4 x = *(const f32x4*)&XT[k * 68 + rg];
    f32x4 y = *(const f32x4*)&Y[k * 68 + cg];
#pragma unroll
    for (int i = 0; i < 4; ++i)
#pragma unroll
      for (int j = 0; j < 4; ++j) acc[i][j] += x[i] * y[j];
  }
#pragma unroll
  for (int j = 0; j < 4; ++j) {
    u16x4 o = {f2bf(acc[0][j]), f2bf(acc[1][j]), f2bf(acc[2][j]), f2bf(acc[3][j])};
    *(u16x4*)&Mtb[(size_t)bh * 4096 + (cg + j) * 64 + rg] = o;
  }
}

// ---------------- final: softmax(q·kl^T) @ M^T + depthwise conv (MFMA + in-reg softmax) ----------------
__global__ __launch_bounds__(256) void k_out(const u16* __restrict__ qb, const u16* __restrict__ vb,
                                             const float* __restrict__ kl, const u16* __restrict__ Mtb,
                                             const float* __restrict__ cw, float* __restrict__ out) {
  __shared__ __align__(16) u16 P_lds[4][16][72];
  __shared__ __align__(16) u16 vtile[96][72];
  __shared__ float wsh[33];
  const int bid = blockIdx.x;
  const int bh = bid >> 6, st = bid & 63;
  const int b = bh >> 4, h = bh & 15;
  const int t = threadIdx.x, lane = t & 63, w = t >> 6;
  const int sbase = st * 64;
  const int l15 = lane & 15, kg = (lane >> 4) << 3, rl = (lane >> 4) << 2;

  if (t < 33) wsh[t] = cw[h * 33 + t];
  for (int idx = t; idx < 96 * 8; idx += 256) {
    const int row = idx >> 3, c8 = idx & 7;
    const int sg = sbase + row - 16;
    u16x8 val = {0, 0, 0, 0, 0, 0, 0, 0};
    if (sg >= 0 && sg < 4096) val = *(const u16x8*)(vb + ((size_t)bh * 4096 + sg) * 64 + c8 * 8);
    *(u16x8*)&vtile[row][c8 * 8] = val;
  }

  // QK^T: A = q rows (bf16, global), B = kl rows (f32 -> bf16 inline)
  f32x4 c1[4];
#pragma unroll
  for (int n = 0; n < 4; ++n) c1[n] = (f32x4){0.f, 0.f, 0.f, 0.f};
  {
    const u16* aRow = qb + ((size_t)bh * 4096 + sbase + w * 16 + l15) * 64 + kg;
    const float* kRow = kl + (size_t)bh * 4096 + l15 * 64 + kg;
#pragma unroll
    for (int ks = 0; ks < 2; ++ks) {
      bf16x8 af = *reinterpret_cast<const bf16x8*>(aRow + ks * 32);
#pragma unroll
      for (int n = 0; n < 4; ++n) {
        bf16x8 bf_ = ld_f32_to_bf8(kRow + n * 1024 + ks * 32);
        c1[n] = __builtin_amdgcn_mfma_f32_16x16x32_bf16(af, bf_, c1[n], 0, 0, 0);
      }
    }
  }
  // in-register softmax over l (no max-sub; scores tiny), P -> LDS (per-wave region)
  float invZ[4];
  {
    float z[4] = {0.f, 0.f, 0.f, 0.f};
#pragma unroll
    for (int n = 0; n < 4; ++n)
#pragma unroll
      for (int r = 0; r < 4; ++r) { float v = __expf(c1[n][r]); c1[n][r] = v; z[r] += v; }
#pragma unroll
    for (int r = 0; r < 4; ++r) {
      float s = z[r];
      s += __shfl_xor(s, 1, 64); s += __shfl_xor(s, 2, 64);
      s += __shfl_xor(s, 4, 64); s += __shfl_xor(s, 8, 64);
      invZ[r] = 1.0f / s;
    }
#pragma unroll
    for (int n = 0; n < 4; ++n)
#pragma unroll
      for (int r = 0; r < 4; ++r)
        P_lds[w][rl + r][n * 16 + l15] = f2bf(c1[n][r]);
  }
  __syncthreads();
  // PV: A = P_lds[w], B = Mtb[d][l]
  f32x4 c2[4];
#pragma unroll
  for (int n = 0; n < 4; ++n) c2[n] = (f32x4){0.f, 0.f, 0.f, 0.f};
  {
    const u16* mRow = Mtb + (size_t)bh * 4096 + l15 * 64 + kg;
#pragma unroll
    for (int ks = 0; ks < 2; ++ks) {
      bf16x8 af = *reinterpret_cast<const bf16x8*>(&P_lds[w][l15][kg + ks * 32]);
#pragma unroll
      for (int n = 0; n < 4; ++n) {
        bf16x8 bf_ = *reinterpret_cast<const bf16x8*>(mRow + n * 1024 + ks * 32);
        c2[n] = __builtin_amdgcn_mfma_f32_16x16x32_bf16(af, bf_, c2[n], 0, 0, 0);
      }
    }
  }
  // conv + epilogue: lane owns rows s_loc = w*16 + rl + r, col d = n*16 + l15
#pragma unroll
  for (int n = 0; n < 4; ++n) {
    const int d = n * 16 + l15;
    const int base = w * 16 + rl;
    float vcol[36];
#pragma unroll
    for (int j = 0; j < 36; ++j) vcol[j] = bf2f(vtile[base + j][d]);
    float cv[4] = {0.f, 0.f, 0.f, 0.f};
#pragma unroll
    for (int jt = 0; jt < 33; ++jt) {
      const float ww = wsh[jt];
#pragma unroll
      for (int r = 0; r < 4; ++r) cv[r] += ww * vcol[r + jt];
    }
#pragma unroll
    for (int r = 0; r < 4; ++r) {
      const int sgl = sbase + base + r;
      out[((size_t)b * 4096 + sgl) * 1024 + h * 64 + d] = c2[n][r] * invZ[r] + cv[r];
    }
  }
}

extern "C" void kernel_launch(void* const* d_in, const int* in_sizes, int n_in,
                              void* d_out, int out_size, void* d_ws, size_t ws_size,
                              hipStream_t stream) {
  const float* hidden = (const float*)d_in[0];
  const float* Wq = (const float*)d_in[1];
  const float* bq = (const float*)d_in[2];
  const float* Wk = (const float*)d_in[3];
  const float* bk = (const float*)d_in[4];
  const float* Wv = (const float*)d_in[5];
  const float* bv = (const float*)d_in[6];
  const float* cw = (const float*)d_in[7];
  float* out = (float*)d_out;

  char* ws = (char*)d_ws;
  u16* qb = (u16*)(ws);
  u16* kb = (u16*)(ws + 33554432ull);
  u16* vb = (u16*)(ws + 67108864ull);
  float* ql = (float*)(ws + 100663296ull);
  float* kl = (float*)(ws + 101711872ull);
  float* k2t = (float*)(ws + 102760448ull);
  float* pinvb = (float*)(ws + 103809024ull);
  float* nv = (float*)(ws + 104857600ull);      // 1 MiB
  float* rowZ = (float*)(ws + 105906176ull);    // 16 KiB, contiguous after nv
  u16* Mtb = (u16*)(ws + 105922560ull);         // 512 KiB
  float* stats = (float*)(ws + 106446848ull);   // 4 KiB pad
  u16* wt = (u16*)(ws + 106450944ull);          // 6 MiB, dead after k_gemm
  u16* hb = (u16*)(ws + 112742400ull);          // 32 MiB, dead after k_gemm
  u16* s3b = (u16*)(ws + 112742400ull);         // 32 MiB, overlaps hb

  k_wt<<<768, 256, 0, stream>>>(Wq, Wk, Wv, wt);
  k_hb<<<8192, 256, 0, stream>>>(hidden, hb);
  k_gemm<<<dim3(128, 24), 256, 0, stream>>>(hb, wt, bq, bk, bv, qb, kb, vb);
  k_lm<<<4096, 64, 0, stream>>>(qb, kb, ql, kl);
  k_k2<<<64, 256, 0, stream>>>(ql, kl, k2t, stats);
  k_max<<<1, 64, 0, stream>>>(stats, stats + 64);
  k_pinv<<<64, 256, 0, stream>>>(k2t, stats + 64, pinvb);
  hipMemsetAsync(nv, 0, 1048576 + 16384, stream);  // nv + rowZ
  k_s3e<<<4096, 256, 0, stream>>>(ql, kb, s3b, rowZ);
  k_nv2<<<512, 256, 0, stream>>>(s3b, vb, rowZ, nv);
  k_pnv<<<64, 256, 0, stream>>>(pinvb, nv, Mtb);
  k_out<<<4096, 256, 0, stream>>>(qb, vb, kl, Mtb, cw, out);
  (void)in_sizes; (void)n_in; (void)out_size; (void)ws_size;
}

// Round 3
// 386.368 us; speedup vs baseline: 1.2195x; 1.0104x over previous
//
#include <hip/hip_runtime.h>
#include <stdint.h>

typedef unsigned short u16;
typedef float f32x4 __attribute__((ext_vector_type(4)));
typedef __bf16 bf16x8 __attribute__((ext_vector_type(8)));
typedef u16 u16x8 __attribute__((ext_vector_type(8)));
typedef u16 u16x4 __attribute__((ext_vector_type(4)));

#define SCALE_QK 0.35355339059327373f

#define BAR() asm volatile("s_barrier" ::: "memory")
#define WAIT_LGKM0() do { asm volatile("s_waitcnt lgkmcnt(0)" ::: "memory"); __builtin_amdgcn_sched_barrier(0); } while (0)
#define WAIT_VM(n) do { asm volatile("s_waitcnt vmcnt(" #n ")" ::: "memory"); __builtin_amdgcn_sched_barrier(0); } while (0)

__device__ __forceinline__ u16 f2bf(float f) {
  union { float f; uint32_t u; } x; x.f = f;
  uint32_t r = x.u + 0x7fffu + ((x.u >> 16) & 1u);
  return (u16)(r >> 16);
}
__device__ __forceinline__ float bf2f(u16 h) {
  union { uint32_t u; float f; } x; x.u = ((uint32_t)h) << 16;
  return x.f;
}
__device__ __forceinline__ void gload16(const void* g, void* l) {
  __builtin_amdgcn_global_load_lds((const __attribute__((address_space(1))) void*)g,
                                   (__attribute__((address_space(3))) void*)l, 16, 0, 0);
}
__device__ __forceinline__ bf16x8 ld_f32_to_bf8(const float* p) {
  f32x4 a = *(const f32x4*)p, b = *(const f32x4*)(p + 4);
  union { u16x8 u; bf16x8 h; } c;
  c.u[0] = f2bf(a[0]); c.u[1] = f2bf(a[1]); c.u[2] = f2bf(a[2]); c.u[3] = f2bf(a[3]);
  c.u[4] = f2bf(b[0]); c.u[5] = f2bf(b[1]); c.u[6] = f2bf(b[2]); c.u[7] = f2bf(b[3]);
  return c.h;
}

// ---------------- weight transpose + bf16:  Wt[w][n][k] = bf16(W_w[k][n]) ----------------
__global__ __launch_bounds__(256) void k_wt(const float* __restrict__ Wq, const float* __restrict__ Wk,
                                            const float* __restrict__ Wv, u16* __restrict__ Wt) {
  __shared__ float tile[64][65];
  const int bx = blockIdx.x;
  const int w = bx >> 8, tn = (bx >> 4) & 15, tk = bx & 15;
  const float* W = (w == 0) ? Wq : ((w == 1) ? Wk : Wv);
  const int t = threadIdx.x;
  const int r = t >> 2, c0 = (t & 3) * 16;
  const float* src = W + (size_t)(tk * 64 + r) * 1024 + tn * 64 + c0;
#pragma unroll
  for (int j = 0; j < 16; j += 4) {
    f32x4 x = *(const f32x4*)(src + j);
    tile[r][c0 + j + 0] = x[0]; tile[r][c0 + j + 1] = x[1];
    tile[r][c0 + j + 2] = x[2]; tile[r][c0 + j + 3] = x[3];
  }
  __syncthreads();
  u16* dst = Wt + (size_t)(w * 1024 + tn * 64 + r) * 1024 + tk * 64 + c0;
#pragma unroll
  for (int j = 0; j < 16; ++j) dst[j] = f2bf(tile[c0 + j][r]);
}

// ---------------- hidden -> bf16 ----------------
__global__ __launch_bounds__(256) void k_hb(const float* __restrict__ in, u16* __restrict__ out) {
  const size_t i = ((size_t)blockIdx.x * 256 + threadIdx.x) * 8;
  f32x4 v0 = *(const f32x4*)(in + i);
  f32x4 v1 = *(const f32x4*)(in + i + 4);
  u16x8 o;
  o[0] = f2bf(v0[0]); o[1] = f2bf(v0[1]); o[2] = f2bf(v0[2]); o[3] = f2bf(v0[3]);
  o[4] = f2bf(v1[0]); o[5] = f2bf(v1[1]); o[6] = f2bf(v1[2]); o[7] = f2bf(v1[3]);
  *(u16x8*)(out + i) = o;
}

// ---------------- 256x256x64 8-wave 8-phase GEMM (T2+T3+T4+T5), fused QKV epilogue ----------------
// LDS tile layout: [256 rows][64 k] bf16, row stride 128B, 16B-chunk swizzle: ck_lds = ck ^ (row & 7).
__device__ __forceinline__ bf16x8 frg(const u16* buf, int row, int ks, int lhi) {
  const int ck = (ks << 2) + lhi;
  return *reinterpret_cast<const bf16x8*>(buf + (row << 6) + ((ck ^ (row & 7)) << 3));
}
// one 8KB block-load (64 rows x 64k): all 8 waves issue 1 gload each; LDS dest linear.
__device__ __forceinline__ void issue(const u16* g, int rowbase, int tc, u16* ldsbase, int wid) {
  gload16(g + (((size_t)rowbase) << 10) + tc, ldsbase + ((rowbase + (wid << 3)) << 6));
}
template <int Q>
__device__ __forceinline__ void quad_mfma(const bf16x8 (&af)[2][2], const bf16x8 (&bf)[4][2],
                                          f32x4 (&acc)[8][4]) {
#pragma unroll
  for (int mm = 0; mm < 2; ++mm)
#pragma unroll
    for (int n = 0; n < 4; ++n) {
      acc[Q * 2 + mm][n] = __builtin_amdgcn_mfma_f32_16x16x32_bf16(af[mm][0], bf[n][0], acc[Q * 2 + mm][n], 0, 0, 0);
      acc[Q * 2 + mm][n] = __builtin_amdgcn_mfma_f32_16x16x32_bf16(af[mm][1], bf[n][1], acc[Q * 2 + mm][n], 0, 0, 0);
    }
}
#define LOADA(Q)                                             \
  af[0][0] = frg(ASr, rA0 + (Q)*32, 0, lhi);                 \
  af[0][1] = frg(ASr, rA0 + (Q)*32, 1, lhi);                 \
  af[1][0] = frg(ASr, rA0 + (Q)*32 + 16, 0, lhi);            \
  af[1][1] = frg(ASr, rA0 + (Q)*32 + 16, 1, lhi);

__global__ __launch_bounds__(512) void k_gemm2(const u16* __restrict__ A, const u16* __restrict__ Bt,
                                               const float* __restrict__ bq, const float* __restrict__ bk,
                                               const float* __restrict__ bv,
                                               u16* __restrict__ oq, u16* __restrict__ ok, u16* __restrict__ ov) {
  __shared__ __align__(16) u16 AS[2][256 * 64];
  __shared__ __align__(16) u16 BS[2][256 * 64];
  const int t = threadIdx.x, lane = t & 63, wid = t >> 6;
  const int wm = wid >> 2, wn = wid & 3;
  const int bm = blockIdx.x, bn = blockIdx.y;
  const int l15 = lane & 15, lhi = lane >> 4;

  // staging: thread covers row (t>>3), 16B-chunk (t&7); global chunk pre-swizzled (rule #21)
  const int rowoff = t >> 3;
  const int cswz = (t & 7) ^ (rowoff & 7);
  const u16* aG = A + (((size_t)(bm * 256 + rowoff)) << 10) + (cswz << 3);
  const u16* bG = Bt + (((size_t)(bn * 256 + rowoff)) << 10) + (cswz << 3);

  const int rA0 = wm * 128 + l15;
  const int rB0 = wn * 64 + l15;

  f32x4 acc[8][4];
#pragma unroll
  for (int m = 0; m < 8; ++m)
#pragma unroll
    for (int n = 0; n < 4; ++n) acc[m][n] = (f32x4){0.f, 0.f, 0.f, 0.f};

  // prologue: stage tile 0 into buf 0. Order: B0,B1,B2,B3, A(0-63), A(128-191), A(64-127), A(192-255)
  issue(bG, 0, 0, BS[0], wid);
  issue(bG, 64, 0, BS[0], wid);
  issue(bG, 128, 0, BS[0], wid);
  issue(bG, 192, 0, BS[0], wid);
  issue(aG, 0, 0, AS[0], wid);
  issue(aG, 128, 0, AS[0], wid);
  issue(aG, 64, 0, AS[0], wid);
  issue(aG, 192, 0, AS[0], wid);
  WAIT_VM(2);  // B + A rows {0-63,128-191} landed; A rows {64-127,192-255} still in flight
  BAR();

  for (int u = 0; u < 15; ++u) {
    const int pu = u & 1;
    const u16* ASr = AS[pu];
    const u16* BSr = BS[pu];
    u16* ASw = AS[pu ^ 1];
    u16* BSw = BS[pu ^ 1];
    const int tc = (u + 1) << 6;
    bf16x8 bf[4][2];
    bf16x8 af[2][2];
    // ---- phase 1 (quad 0): 12 ds_reads, issue next-tile B halves 0-1
#pragma unroll
    for (int n = 0; n < 4; ++n) {
      bf[n][0] = frg(BSr, rB0 + n * 16, 0, lhi);
      bf[n][1] = frg(BSr, rB0 + n * 16, 1, lhi);
    }
    LOADA(0)
    issue(bG, 0, tc, BSw, wid);
    issue(bG, 64, tc, BSw, wid);
    BAR();
    WAIT_LGKM0();
    __builtin_amdgcn_s_setprio(1);
    quad_mfma<0>(af, bf, acc);
    __builtin_amdgcn_s_setprio(0);
    BAR();
    // ---- phase 2 (quad 1): issue next-tile B halves 2-3; end: vmcnt(4) (old A tail landed)
    LOADA(1)
    issue(bG, 128, tc, BSw, wid);
    issue(bG, 192, tc, BSw, wid);
    BAR();
    WAIT_LGKM0();
    __builtin_amdgcn_s_setprio(1);
    quad_mfma<1>(af, bf, acc);
    __builtin_amdgcn_s_setprio(0);
    WAIT_VM(4);
    BAR();
    // ---- phase 3 (quad 2): issue next-tile A rows {0-63},{128-191}
    LOADA(2)
    issue(aG, 0, tc, ASw, wid);
    issue(aG, 128, tc, ASw, wid);
    BAR();
    WAIT_LGKM0();
    __builtin_amdgcn_s_setprio(1);
    quad_mfma<2>(af, bf, acc);
    __builtin_amdgcn_s_setprio(0);
    BAR();
    // ---- phase 4 (quad 3): issue next-tile A rows {64-127},{192-255}; end: vmcnt(2)
    LOADA(3)
    issue(aG, 64, tc, ASw, wid);
    issue(aG, 192, tc, ASw, wid);
    BAR();
    WAIT_LGKM0();
    __builtin_amdgcn_s_setprio(1);
    quad_mfma<3>(af, bf, acc);
    __builtin_amdgcn_s_setprio(0);
    WAIT_VM(2);
    BAR();
  }
  // ---- tile 15 (peeled, no staging): drain and compute
  {
    const u16* ASr = AS[1];
    const u16* BSr = BS[1];
    WAIT_VM(0);
    BAR();
    bf16x8 bf[4][2];
    bf16x8 af[2][2];
#pragma unroll
    for (int n = 0; n < 4; ++n) {
      bf[n][0] = frg(BSr, rB0 + n * 16, 0, lhi);
      bf[n][1] = frg(BSr, rB0 + n * 16, 1, lhi);
    }
    LOADA(0) quad_mfma<0>(af, bf, acc);
    LOADA(1) quad_mfma<1>(af, bf, acc);
    LOADA(2) quad_mfma<2>(af, bf, acc);
    LOADA(3) quad_mfma<3>(af, bf, acc);
  }

  // ---- epilogue: bias + scale, write bf16 [B,H,S,D]
  const int which = bn >> 2;
  const float* bias = (which == 0) ? bq : ((which == 1) ? bk : bv);
  u16* op = (which == 0) ? oq : ((which == 1) ? ok : ov);
  const float scl = (which < 2) ? SCALE_QK : 1.0f;
  const int colBase = ((bn & 3) << 8) + (wn << 6) + l15;  // within-projection col 0..1023
  const int rowBase = (bm << 8) + (wm << 7) + (lhi << 2);
#pragma unroll
  for (int n = 0; n < 4; ++n) {
    const int c = colBase + n * 16;
    const float bb = bias[c];
    const int h = c >> 6, d = c & 63;
#pragma unroll
    for (int m = 0; m < 8; ++m) {
#pragma unroll
      for (int r = 0; r < 4; ++r) {
        const int gm = rowBase + m * 16 + r;
        const int b_ = gm >> 12, s = gm & 4095;
        op[(((size_t)b_ * 16 + h) * 4096 + s) * 64 + d] = f2bf((acc[m][n][r] + bb) * scl);
      }
    }
  }
}

// ---------------- landmarks: ql/kl [BH,64,64] f32 = segment means ----------------
__global__ __launch_bounds__(64) void k_lm(const u16* __restrict__ q, const u16* __restrict__ k,
                                           float* __restrict__ ql, float* __restrict__ kl) {
  const int bid = blockIdx.x;  // bh*64 + l
  const int d = threadIdx.x;
  const u16* qp = q + (size_t)bid * 4096 + d;
  const u16* kp = k + (size_t)bid * 4096 + d;
  float sq = 0.f, sk = 0.f;
#pragma unroll 4
  for (int m = 0; m < 64; ++m) { sq += bf2f(qp[m * 64]); sk += bf2f(kp[m * 64]); }
  ql[(size_t)bid * 64 + d] = sq * 0.015625f;
  kl[(size_t)bid * 64 + d] = sk * 0.015625f;
}

// ---------------- kernel_2 = softmax(ql@kl^T); write k2t (transposed) + per-bh max colsum ----------------
__global__ __launch_bounds__(256) void k_k2(const float* __restrict__ ql, const float* __restrict__ kl,
                                            float* __restrict__ k2t, float* __restrict__ colmax) {
  __shared__ __align__(16) float qlT[64 * 68];
  __shared__ __align__(16) float klT[64 * 68];
  __shared__ __align__(16) float sc[64 * 68];
  const int bh = blockIdx.x, t = threadIdx.x;
  {
    const int r = t >> 2, c0 = (t & 3) * 16;
    const float* qp = ql + (size_t)bh * 4096 + r * 64 + c0;
    const float* kp = kl + (size_t)bh * 4096 + r * 64 + c0;
#pragma unroll
    for (int j = 0; j < 16; ++j) { qlT[(c0 + j) * 68 + r] = qp[j]; klT[(c0 + j) * 68 + r] = kp[j]; }
  }
  __syncthreads();
  {
    const int mg = (t >> 4) * 4, lg = (t & 15) * 4;
    float acc[4][4];
#pragma unroll
    for (int i = 0; i < 4; ++i)
#pragma unroll
      for (int j = 0; j < 4; ++j) acc[i][j] = 0.f;
    for (int d0 = 0; d0 < 64; ++d0) {
      f32x4 x = *(const f32x4*)&qlT[d0 * 68 + mg];
      f32x4 y = *(const f32x4*)&klT[d0 * 68 + lg];
#pragma unroll
      for (int i = 0; i < 4; ++i)
#pragma unroll
        for (int j = 0; j < 4; ++j) acc[i][j] += x[i] * y[j];
    }
#pragma unroll
    for (int i = 0; i < 4; ++i)
#pragma unroll
      for (int j = 0; j < 4; ++j) sc[(mg + i) * 68 + lg + j] = acc[i][j];
  }
  __syncthreads();
  if (t < 64) {
    float mx = -1e30f;
    for (int l = 0; l < 64; ++l) mx = fmaxf(mx, sc[t * 68 + l]);
    float sum = 0.f;
    for (int l = 0; l < 64; ++l) { float e = __expf(sc[t * 68 + l] - mx); sc[t * 68 + l] = e; sum += e; }
    const float inv = 1.0f / sum;
    for (int l = 0; l < 64; ++l) sc[t * 68 + l] *= inv;
  }
  __syncthreads();
  {
    const int r = t >> 2, c0 = (t & 3) * 16;
    float* ot = k2t + (size_t)bh * 4096 + r * 64 + c0;
#pragma unroll
    for (int j = 0; j < 16; ++j) ot[j] = sc[(c0 + j) * 68 + r];
  }
  if (t < 64) {
    float s = 0.f;
    for (int m = 0; m < 64; ++m) s += sc[m * 68 + t];
    for (int off = 32; off; off >>= 1) s = fmaxf(s, __shfl_down(s, off, 64));
    if (t == 0) colmax[bh] = s;
  }
}

// ---------------- global max of 64 colmax values ----------------
__global__ __launch_bounds__(64) void k_max(const float* __restrict__ colmax, float* __restrict__ gmax) {
  const int t = threadIdx.x;
  float v = colmax[t];
  for (int off = 32; off; off >>= 1) v = fmaxf(v, __shfl_down(v, off, 64));
  if (t == 0) *gmax = v;
}

// ---------------- iterative pinv (6 iters, f32, per-bh block) ----------------
__global__ __launch_bounds__(256) void k_pinv(const float* __restrict__ k2t, const float* __restrict__ gmaxp,
                                              float* __restrict__ pinv) {
  __shared__ float valN[4096];
  __shared__ float kvT[4096];
  __shared__ float t1N[4096];
  __shared__ float t2N[4096];
  const int bh = blockIdx.x, t = threadIdx.x;
  const float* aT = k2t + (size_t)bh * 4096;
  const float ginv = 1.0f / gmaxp[0];
  const int rt = t >> 2, ct0 = (t & 3) * 16;
  {
    const float* p = aT + rt * 64 + ct0;
#pragma unroll
    for (int j = 0; j < 16; ++j) valN[rt * 64 + ct0 + j] = p[j] * ginv;
  }
  __syncthreads();
  const int rg = (t >> 4) * 4, cg = (t & 15) * 4;
  float acc[4][4];
  for (int it = 0; it < 6; ++it) {
#pragma unroll
    for (int i = 0; i < 4; ++i)
#pragma unroll
      for (int j = 0; j < 4; ++j) acc[i][j] = 0.f;
    for (int k = 0; k < 64; ++k) {
      f32x4 x = *(const f32x4*)(aT + k * 64 + rg);
      f32x4 y = *(const f32x4*)&valN[k * 64 + cg];
#pragma unroll
      for (int i = 0; i < 4; ++i)
#pragma unroll
        for (int j = 0; j < 4; ++j) acc[i][j] += x[i] * y[j];
    }
#pragma unroll
    for (int i = 0; i < 4; ++i)
#pragma unroll
      for (int j = 0; j < 4; ++j) kvT[(cg + j) * 64 + rg + i] = acc[i][j];
    __syncthreads();
#pragma unroll
    for (int j = 0; j < 16; ++j) {
      const int c = ct0 + j;
      t1N[rt * 64 + c] = ((rt == c) ? 7.0f : 0.0f) - kvT[c * 64 + rt];
    }
    __syncthreads();
#pragma unroll
    for (int i = 0; i < 4; ++i)
#pragma unroll
      for (int j = 0; j < 4; ++j) acc[i][j] = 0.f;
    for (int k = 0; k < 64; ++k) {
      f32x4 x = *(const f32x4*)&kvT[k * 64 + rg];
      f32x4 y = *(const f32x4*)&t1N[k * 64 + cg];
#pragma unroll
      for (int i = 0; i < 4; ++i)
#pragma unroll
        for (int j = 0; j < 4; ++j) acc[i][j] += x[i] * y[j];
    }
#pragma unroll
    for (int i = 0; i < 4; ++i)
#pragma unroll
      for (int j = 0; j < 4; ++j) {
        const int r_ = rg + i, c_ = cg + j;
        t2N[r_ * 64 + c_] = ((r_ == c_) ? 15.0f : 0.0f) - acc[i][j];
      }
    __syncthreads();
#pragma unroll
    for (int i = 0; i < 4; ++i)
#pragma unroll
      for (int j = 0; j < 4; ++j) acc[i][j] = 0.f;
    for (int k = 0; k < 64; ++k) {
      f32x4 x = *(const f32x4*)&kvT[k * 64 + rg];
      f32x4 y = *(const f32x4*)&t2N[k * 64 + cg];
#pragma unroll
      for (int i = 0; i < 4; ++i)
#pragma unroll
        for (int j = 0; j < 4; ++j) acc[i][j] += x[i] * y[j];
    }
#pragma unroll
    for (int i = 0; i < 4; ++i)
#pragma unroll
      for (int j = 0; j < 4; ++j) {
        const int r_ = rg + i, c_ = cg + j;
        t1N[r_ * 64 + c_] = ((r_ == c_) ? 13.0f : 0.0f) - acc[i][j];
      }
    __syncthreads();
#pragma unroll
    for (int j = 0; j < 16; ++j) t2N[(ct0 + j) * 64 + rt] = valN[rt * 64 + ct0 + j];
    __syncthreads();
#pragma unroll
    for (int i = 0; i < 4; ++i)
#pragma unroll
      for (int j = 0; j < 4; ++j) acc[i][j] = 0.f;
    for (int k = 0; k < 64; ++k) {
      f32x4 x = *(const f32x4*)&t2N[k * 64 + rg];
      f32x4 y = *(const f32x4*)&t1N[k * 64 + cg];
#pragma unroll
      for (int i = 0; i < 4; ++i)
#pragma unroll
        for (int j = 0; j < 4; ++j) acc[i][j] += x[i] * y[j];
    }
#pragma unroll
    for (int i = 0; i < 4; ++i)
#pragma unroll
      for (int j = 0; j < 4; ++j) valN[(rg + i) * 64 + cg + j] = 0.25f * acc[i][j];
    __syncthreads();
  }
  {
    float* o = pinv + (size_t)bh * 4096 + rt * 64 + ct0;
#pragma unroll
    for (int j = 0; j < 16; ++j) o[j] = valN[rt * 64 + ct0 + j];
  }
}

// ---------------- s3e: e = exp(ql·k^T) bf16 (no max-sub; scores tiny) + atomic row sums ----------------
__global__ __launch_bounds__(256) void k_s3e(const float* __restrict__ ql, const u16* __restrict__ kb,
                                             u16* __restrict__ s3b, float* __restrict__ rowZ) {
  __shared__ __align__(16) u16 bounce[4][16][72];
  const int bid = blockIdx.x;
  const int bh = bid >> 6, st = bid & 63;
  const int t = threadIdx.x, lane = t & 63, w = t >> 6;
  const int s0 = st * 64;
  const int l15 = lane & 15, kg = (lane >> 4) << 3, rl = (lane >> 4) << 2;
  const int Lbase = w * 16;
  f32x4 acc[4];
#pragma unroll
  for (int n = 0; n < 4; ++n) acc[n] = (f32x4){0.f, 0.f, 0.f, 0.f};
  const float* aRow = ql + (size_t)bh * 4096 + (Lbase + l15) * 64 + kg;
  const u16* bRow = kb + ((size_t)bh * 4096 + s0 + l15) * 64 + kg;
#pragma unroll
  for (int ks = 0; ks < 2; ++ks) {
    bf16x8 af = ld_f32_to_bf8(aRow + ks * 32);
#pragma unroll
    for (int n = 0; n < 4; ++n) {
      bf16x8 bf_ = *reinterpret_cast<const bf16x8*>(bRow + n * 1024 + ks * 32);
      acc[n] = __builtin_amdgcn_mfma_f32_16x16x32_bf16(af, bf_, acc[n], 0, 0, 0);
    }
  }
  float z[4] = {0.f, 0.f, 0.f, 0.f};
#pragma unroll
  for (int n = 0; n < 4; ++n)
#pragma unroll
    for (int r = 0; r < 4; ++r) { float v = __expf(acc[n][r]); acc[n][r] = v; z[r] += v; }
#pragma unroll
  for (int r = 0; r < 4; ++r) {
    float s = z[r];
    s += __shfl_xor(s, 1, 64); s += __shfl_xor(s, 2, 64);
    s += __shfl_xor(s, 4, 64); s += __shfl_xor(s, 8, 64);
    z[r] = s;
  }
  if (l15 == 0) {
#pragma unroll
    for (int r = 0; r < 4; ++r) atomicAdd(&rowZ[bh * 64 + Lbase + rl + r], z[r]);
  }
#pragma unroll
  for (int n = 0; n < 4; ++n)
#pragma unroll
    for (int r = 0; r < 4; ++r)
      bounce[w][rl + r][n * 16 + l15] = f2bf(acc[n][r]);
  __syncthreads();
  const int rr = lane >> 2, cc = (lane & 3) * 16;
  u16* dst = s3b + ((size_t)bh * 64 + Lbase + rr) * 4096 + s0 + cc;
  *(u16x8*)dst = *(const u16x8*)&bounce[w][rr][cc];
  *(u16x8*)(dst + 8) = *(const u16x8*)&bounce[w][rr][cc + 8];
}

// ---------------- nv[l][d] = (1/Z_l)·Σ_s e[l][s]·V[s][d]  (MFMA, VT via LDS transpose) ----------------
__global__ __launch_bounds__(256) void k_nv2(const u16* __restrict__ s3b, const u16* __restrict__ vb,
                                             const float* __restrict__ rowZ, float* __restrict__ nv) {
  __shared__ __align__(16) u16 VT[64][72];
  const int bh = blockIdx.x >> 3, scn = blockIdx.x & 7;
  const int t = threadIdx.x, lane = t & 63, w = t >> 6;
  const int l15 = lane & 15, kg = (lane >> 4) << 3, rl = (lane >> 4) << 2;
  f32x4 acc[4];
#pragma unroll
  for (int n = 0; n < 4; ++n) acc[n] = (f32x4){0.f, 0.f, 0.f, 0.f};
  for (int sub = 0; sub < 8; ++sub) {
    const int s0 = scn * 512 + sub * 64;
    __syncthreads();
    {
      const int sv = lane;
      const int d0 = w * 16;
      const u16* vp = vb + ((size_t)bh * 4096 + s0 + sv) * 64 + d0;
      u16x8 h0 = *(const u16x8*)vp, h1 = *(const u16x8*)(vp + 8);
#pragma unroll
      for (int j = 0; j < 8; ++j) { VT[d0 + j][sv] = h0[j]; VT[d0 + 8 + j][sv] = h1[j]; }
    }
    __syncthreads();
    const u16* aRow = s3b + ((size_t)bh * 64 + w * 16 + l15) * 4096 + s0 + kg;
#pragma unroll
    for (int ks = 0; ks < 2; ++ks) {
      bf16x8 af = *reinterpret_cast<const bf16x8*>(aRow + ks * 32);
#pragma unroll
      for (int n = 0; n < 4; ++n) {
        bf16x8 bf_ = *reinterpret_cast<const bf16x8*>(&VT[n * 16 + l15][kg + ks * 32]);
        acc[n] = __builtin_amdgcn_mfma_f32_16x16x32_bf16(af, bf_, acc[n], 0, 0, 0);
      }
    }
  }
#pragma unroll
  for (int r = 0; r < 4; ++r) {
    const float iz = 1.0f / rowZ[bh * 64 + w * 16 + rl + r];
#pragma unroll
    for (int n = 0; n < 4; ++n)
      atomicAdd(&nv[(size_t)bh * 4096 + (w * 16 + rl + r) * 64 + n * 16 + l15], acc[n][r] * iz);
  }
}

// ---------------- M^T (bf16) = (pinv @ nv)^T ----------------
__global__ __launch_bounds__(256) void k_pnv(const float* __restrict__ pinv, const float* __restrict__ nv,
                                             u16* __restrict__ Mtb) {
  __shared__ __align__(16) float XT[64 * 68];
  __shared__ __align__(16) float Y[64 * 68];
  const int bh = blockIdx.x, t = threadIdx.x;
  {
    const int r = t >> 2, c0 = (t & 3) * 16;
    const float* pp = pinv + (size_t)bh * 4096 + r * 64 + c0;
#pragma unroll
    for (int j = 0; j < 16; ++j) XT[(c0 + j) * 68 + r] = pp[j];
    const float* np = nv + (size_t)bh * 4096 + r * 64 + c0;
#pragma unroll
    for (int j = 0; j < 16; j += 4) *(f32x4*)&Y[r * 68 + c0 + j] = *(const f32x4*)(np + j);
  }
  __syncthreads();
  const int rg = (t >> 4) * 4, cg = (t & 15) * 4;
  float acc[4][4];
#pragma unroll
  for (int i = 0; i < 4; ++i)
#pragma unroll
    for (int j = 0; j < 4; ++j) acc[i][j] = 0.f;
  for (int k = 0; k < 64; ++k) {
    f32x4 x = *(const f32x4*)&XT[k * 68 + rg];
    f32x4 y = *(const f32x4*)&Y[k * 68 + cg];
#pragma unroll
    for (int i = 0; i < 4; ++i)
#pragma unroll
      for (int j = 0; j < 4; ++j) acc[i][j] += x[i] * y[j];
  }
#pragma unroll
  for (int j = 0; j < 4; ++j) {
    u16x4 o = {f2bf(acc[0][j]), f2bf(acc[1][j]), f2bf(acc[2][j]), f2bf(acc[3][j])};
    *(u16x4*)&Mtb[(size_t)bh * 4096 + (cg + j) * 64 + rg] = o;
  }
}

// ---------------- final: softmax(q·kl^T) @ M^T + depthwise conv (MFMA + in-reg softmax) ----------------
__global__ __launch_bounds__(256) void k_out(const u16* __restrict__ qb, const u16* __restrict__ vb,
                                             const float* __restrict__ kl, const u16* __restrict__ Mtb,
                                             const float* __restrict__ cw, float* __restrict__ out) {
  __shared__ __align__(16) u16 P_lds[4][16][72];
  __shared__ __align__(16) u16 vtile[96][72];
  __shared__ float wsh[33];
  const int bid = blockIdx.x;
  const int bh = bid >> 6, st = bid & 63;
  const int b = bh >> 4, h = bh & 15;
  const int t = threadIdx.x, lane = t & 63, w = t >> 6;
  const int sbase = st * 64;
  const int l15 = lane & 15, kg = (lane >> 4) << 3, rl = (lane >> 4) << 2;

  if (t < 33) wsh[t] = cw[h * 33 + t];
  for (int idx = t; idx < 96 * 8; idx += 256) {
    const int row = idx >> 3, c8 = idx & 7;
    const int sg = sbase + row - 16;
    u16x8 val = {0, 0, 0, 0, 0, 0, 0, 0};
    if (sg >= 0 && sg < 4096) val = *(const u16x8*)(vb + ((size_t)bh * 4096 + sg) * 64 + c8 * 8);
    *(u16x8*)&vtile[row][c8 * 8] = val;
  }

  // QK^T: A = q rows (bf16, global), B = kl rows (f32 -> bf16 inline)
  f32x4 c1[4];
#pragma unroll
  for (int n = 0; n < 4; ++n) c1[n] = (f32x4){0.f, 0.f, 0.f, 0.f};
  {
    const u16* aRow = qb + ((size_t)bh * 4096 + sbase + w * 16 + l15) * 64 + kg;
    const float* kRow = kl + (size_t)bh * 4096 + l15 * 64 + kg;
#pragma unroll
    for (int ks = 0; ks < 2; ++ks) {
      bf16x8 af = *reinterpret_cast<const bf16x8*>(aRow + ks * 32);
#pragma unroll
      for (int n = 0; n < 4; ++n) {
        bf16x8 bf_ = ld_f32_to_bf8(kRow + n * 1024 + ks * 32);
        c1[n] = __builtin_amdgcn_mfma_f32_16x16x32_bf16(af, bf_, c1[n], 0, 0, 0);
      }
    }
  }
  // in-register softmax over l (no max-sub; scores tiny), P -> LDS (per-wave region)
  float invZ[4];
  {
    float z[4] = {0.f, 0.f, 0.f, 0.f};
#pragma unroll
    for (int n = 0; n < 4; ++n)
#pragma unroll
      for (int r = 0; r < 4; ++r) { float v = __expf(c1[n][r]); c1[n][r] = v; z[r] += v; }
#pragma unroll
    for (int r = 0; r < 4; ++r) {
      float s = z[r];
      s += __shfl_xor(s, 1, 64); s += __shfl_xor(s, 2, 64);
      s += __shfl_xor(s, 4, 64); s += __shfl_xor(s, 8, 64);
      invZ[r] = 1.0f / s;
    }
#pragma unroll
    for (int n = 0; n < 4; ++n)
#pragma unroll
      for (int r = 0; r < 4; ++r)
        P_lds[w][rl + r][n * 16 + l15] = f2bf(c1[n][r]);
  }
  __syncthreads();
  // PV: A = P_lds[w], B = Mtb[d][l]
  f32x4 c2[4];
#pragma unroll
  for (int n = 0; n < 4; ++n) c2[n] = (f32x4){0.f, 0.f, 0.f, 0.f};
  {
    const u16* mRow = Mtb + (size_t)bh * 4096 + l15 * 64 + kg;
#pragma unroll
    for (int ks = 0; ks < 2; ++ks) {
      bf16x8 af = *reinterpret_cast<const bf16x8*>(&P_lds[w][l15][kg + ks * 32]);
#pragma unroll
      for (int n = 0; n < 4; ++n) {
        bf16x8 bf_ = *reinterpret_cast<const bf16x8*>(mRow + n * 1024 + ks * 32);
        c2[n] = __builtin_amdgcn_mfma_f32_16x16x32_bf16(af, bf_, c2[n], 0, 0, 0);
      }
    }
  }
  // conv + epilogue: lane owns rows s_loc = w*16 + rl + r, col d = n*16 + l15
#pragma unroll
  for (int n = 0; n < 4; ++n) {
    const int d = n * 16 + l15;
    const int base = w * 16 + rl;
    float vcol[36];
#pragma unroll
    for (int j = 0; j < 36; ++j) vcol[j] = bf2f(vtile[base + j][d]);
    float cv[4] = {0.f, 0.f, 0.f, 0.f};
#pragma unroll
    for (int jt = 0; jt < 33; ++jt) {
      const float ww = wsh[jt];
#pragma unroll
      for (int r = 0; r < 4; ++r) cv[r] += ww * vcol[r + jt];
    }
#pragma unroll
    for (int r = 0; r < 4; ++r) {
      const int sgl = sbase + base + r;
      f32x4 o = {0.f, 0.f, 0.f, 0.f};
      out[((size_t)b * 4096 + sgl) * 1024 + h * 64 + d] = c2[n][r] * invZ[r] + cv[r];
      (void)o;
    }
  }
}

extern "C" void kernel_launch(void* const* d_in, const int* in_sizes, int n_in,
                              void* d_out, int out_size, void* d_ws, size_t ws_size,
                              hipStream_t stream) {
  const float* hidden = (const float*)d_in[0];
  const float* Wq = (const float*)d_in[1];
  const float* bq = (const float*)d_in[2];
  const float* Wk = (const float*)d_in[3];
  const float* bk = (const float*)d_in[4];
  const float* Wv = (const float*)d_in[5];
  const float* bv = (const float*)d_in[6];
  const float* cw = (const float*)d_in[7];
  float* out = (float*)d_out;

  char* ws = (char*)d_ws;
  u16* qb = (u16*)(ws);
  u16* kb = (u16*)(ws + 33554432ull);
  u16* vb = (u16*)(ws + 67108864ull);
  float* ql = (float*)(ws + 100663296ull);
  float* kl = (float*)(ws + 101711872ull);
  float* k2t = (float*)(ws + 102760448ull);
  float* pinvb = (float*)(ws + 103809024ull);
  float* nv = (float*)(ws + 104857600ull);      // 1 MiB
  float* rowZ = (float*)(ws + 105906176ull);    // 16 KiB, contiguous after nv
  u16* Mtb = (u16*)(ws + 105922560ull);         // 512 KiB
  float* stats = (float*)(ws + 106446848ull);   // 4 KiB pad
  u16* wt = (u16*)(ws + 106450944ull);          // 6 MiB, dead after k_gemm
  u16* hb = (u16*)(ws + 112742400ull);          // 32 MiB, dead after k_gemm
  u16* s3b = (u16*)(ws + 112742400ull);         // 32 MiB, overlaps hb

  k_wt<<<768, 256, 0, stream>>>(Wq, Wk, Wv, wt);
  k_hb<<<8192, 256, 0, stream>>>(hidden, hb);
  k_gemm2<<<dim3(64, 12), 512, 0, stream>>>(hb, wt, bq, bk, bv, qb, kb, vb);
  k_lm<<<4096, 64, 0, stream>>>(qb, kb, ql, kl);
  k_k2<<<64, 256, 0, stream>>>(ql, kl, k2t, stats);
  k_max<<<1, 64, 0, stream>>>(stats, stats + 64);
  k_pinv<<<64, 256, 0, stream>>>(k2t, stats + 64, pinvb);
  hipMemsetAsync(nv, 0, 1048576 + 16384, stream);  // nv + rowZ
  k_s3e<<<4096, 256, 0, stream>>>(ql, kb, s3b, rowZ);
  k_nv2<<<512, 256, 0, stream>>>(s3b, vb, rowZ, nv);
  k_pnv<<<64, 256, 0, stream>>>(pinvb, nv, Mtb);
  k_out<<<4096, 256, 0, stream>>>(qb, vb, kl, Mtb, cw, out);
  (void)in_sizes; (void)n_in; (void)out_size; (void)ws_size;
}

// Round 4
// 318.890 us; speedup vs baseline: 1.4775x; 1.2116x over previous
//
#include <hip/hip_runtime.h>
#include <stdint.h>

typedef unsigned short u16;
typedef float f32x4 __attribute__((ext_vector_type(4)));
typedef __bf16 bf16x8 __attribute__((ext_vector_type(8)));
typedef u16 u16x8 __attribute__((ext_vector_type(8)));
typedef u16 u16x4 __attribute__((ext_vector_type(4)));

#define SCALE_QK 0.35355339059327373f

#define BAR() asm volatile("s_barrier" ::: "memory")
#define WAIT_LGKM0() do { asm volatile("s_waitcnt lgkmcnt(0)" ::: "memory"); __builtin_amdgcn_sched_barrier(0); } while (0)
#define WAIT_VM(n) do { asm volatile("s_waitcnt vmcnt(" #n ")" ::: "memory"); __builtin_amdgcn_sched_barrier(0); } while (0)

__device__ __forceinline__ u16 f2bf(float f) {
  union { float f; uint32_t u; } x; x.f = f;
  uint32_t r = x.u + 0x7fffu + ((x.u >> 16) & 1u);
  return (u16)(r >> 16);
}
__device__ __forceinline__ float bf2f(u16 h) {
  union { uint32_t u; float f; } x; x.u = ((uint32_t)h) << 16;
  return x.f;
}
__device__ __forceinline__ void gload16(const void* g, void* l) {
  __builtin_amdgcn_global_load_lds((const __attribute__((address_space(1))) void*)g,
                                   (__attribute__((address_space(3))) void*)l, 16, 0, 0);
}
__device__ __forceinline__ bf16x8 ld_f32_to_bf8(const float* p) {
  f32x4 a = *(const f32x4*)p, b = *(const f32x4*)(p + 4);
  union { u16x8 u; bf16x8 h; } c;
  c.u[0] = f2bf(a[0]); c.u[1] = f2bf(a[1]); c.u[2] = f2bf(a[2]); c.u[3] = f2bf(a[3]);
  c.u[4] = f2bf(b[0]); c.u[5] = f2bf(b[1]); c.u[6] = f2bf(b[2]); c.u[7] = f2bf(b[3]);
  return c.h;
}

// ---------------- weight transpose + bf16:  Wt[w][n][k] = bf16(W_w[k][n]) ----------------
__global__ __launch_bounds__(256) void k_wt(const float* __restrict__ Wq, const float* __restrict__ Wk,
                                            const float* __restrict__ Wv, u16* __restrict__ Wt) {
  __shared__ float tile[64][65];
  const int bx = blockIdx.x;
  const int w = bx >> 8, tn = (bx >> 4) & 15, tk = bx & 15;
  const float* W = (w == 0) ? Wq : ((w == 1) ? Wk : Wv);
  const int t = threadIdx.x;
  const int r = t >> 2, c0 = (t & 3) * 16;
  const float* src = W + (size_t)(tk * 64 + r) * 1024 + tn * 64 + c0;
#pragma unroll
  for (int j = 0; j < 16; j += 4) {
    f32x4 x = *(const f32x4*)(src + j);
    tile[r][c0 + j + 0] = x[0]; tile[r][c0 + j + 1] = x[1];
    tile[r][c0 + j + 2] = x[2]; tile[r][c0 + j + 3] = x[3];
  }
  __syncthreads();
  u16* dst = Wt + (size_t)(w * 1024 + tn * 64 + r) * 1024 + tk * 64 + c0;
#pragma unroll
  for (int j = 0; j < 16; ++j) dst[j] = f2bf(tile[c0 + j][r]);
}

// ---------------- hidden -> bf16 ----------------
__global__ __launch_bounds__(256) void k_hb(const float* __restrict__ in, u16* __restrict__ out) {
  const size_t i = ((size_t)blockIdx.x * 256 + threadIdx.x) * 8;
  f32x4 v0 = *(const f32x4*)(in + i);
  f32x4 v1 = *(const f32x4*)(in + i + 4);
  u16x8 o;
  o[0] = f2bf(v0[0]); o[1] = f2bf(v0[1]); o[2] = f2bf(v0[2]); o[3] = f2bf(v0[3]);
  o[4] = f2bf(v1[0]); o[5] = f2bf(v1[1]); o[6] = f2bf(v1[2]); o[7] = f2bf(v1[3]);
  *(u16x8*)(out + i) = o;
}

// ---------------- 256x256x64 8-wave 4-phase GEMM, deep prefetch, fused QKV epilogue ----------------
__device__ __forceinline__ bf16x8 frg(const u16* buf, int row, int ks, int lhi) {
  const int ck = (ks << 2) + lhi;
  return *reinterpret_cast<const bf16x8*>(buf + (row << 6) + ((ck ^ (row & 7)) << 3));
}
__device__ __forceinline__ void issue(const u16* g, int rowbase, int tc, u16* ldsbase, int wid) {
  gload16(g + (((size_t)rowbase) << 10) + tc, ldsbase + ((rowbase + (wid << 3)) << 6));
}
template <int Q>
__device__ __forceinline__ void quad_mfma(const bf16x8 (&af)[2][2], const bf16x8 (&bf)[4][2],
                                          f32x4 (&acc)[8][4]) {
#pragma unroll
  for (int mm = 0; mm < 2; ++mm)
#pragma unroll
    for (int n = 0; n < 4; ++n) {
      acc[Q * 2 + mm][n] = __builtin_amdgcn_mfma_f32_16x16x32_bf16(af[mm][0], bf[n][0], acc[Q * 2 + mm][n], 0, 0, 0);
      acc[Q * 2 + mm][n] = __builtin_amdgcn_mfma_f32_16x16x32_bf16(af[mm][1], bf[n][1], acc[Q * 2 + mm][n], 0, 0, 0);
    }
}
#define LOADA(Q)                                             \
  af[0][0] = frg(ASr, rA0 + (Q)*32, 0, lhi);                 \
  af[0][1] = frg(ASr, rA0 + (Q)*32, 1, lhi);                 \
  af[1][0] = frg(ASr, rA0 + (Q)*32 + 16, 0, lhi);            \
  af[1][1] = frg(ASr, rA0 + (Q)*32 + 16, 1, lhi);

__global__ __launch_bounds__(512) void k_gemm2(const u16* __restrict__ A, const u16* __restrict__ Bt,
                                               const float* __restrict__ bq, const float* __restrict__ bk,
                                               const float* __restrict__ bv,
                                               u16* __restrict__ oq, u16* __restrict__ ok, u16* __restrict__ ov) {
  __shared__ __align__(16) u16 AS[2][256 * 64];
  __shared__ __align__(16) u16 BS[2][256 * 64];
  __shared__ __align__(16) u16 obuf[8][16][70];
  const int t = threadIdx.x, lane = t & 63, wid = t >> 6;
  const int wm = wid >> 2, wn = wid & 3;
  const int bm = blockIdx.x, bn = blockIdx.y;
  const int l15 = lane & 15, lhi = lane >> 4;

  const int rowoff = t >> 3;
  const int cswz = (t & 7) ^ (rowoff & 7);
  const u16* aG = A + (((size_t)(bm * 256 + rowoff)) << 10) + (cswz << 3);
  const u16* bG = Bt + (((size_t)(bn * 256 + rowoff)) << 10) + (cswz << 3);

  const int rA0 = wm * 128 + l15;
  const int rB0 = wn * 64 + l15;

  f32x4 acc[8][4];
#pragma unroll
  for (int m = 0; m < 8; ++m)
#pragma unroll
    for (int n = 0; n < 4; ++n) acc[m][n] = (f32x4){0.f, 0.f, 0.f, 0.f};

  // prologue: tile 0 -> buf 0
  issue(bG, 0, 0, BS[0], wid);
  issue(bG, 64, 0, BS[0], wid);
  issue(bG, 128, 0, BS[0], wid);
  issue(bG, 192, 0, BS[0], wid);
  issue(aG, 0, 0, AS[0], wid);
  issue(aG, 128, 0, AS[0], wid);
  issue(aG, 64, 0, AS[0], wid);
  issue(aG, 192, 0, AS[0], wid);
  WAIT_VM(2);  // B + A{0-63,128-191} landed; A{64-127,192-255} in flight
  BAR();

  for (int u = 0; u < 15; ++u) {
    const int pu = u & 1;
    const u16* ASr = AS[pu];
    const u16* BSr = BS[pu];
    u16* ASw = AS[pu ^ 1];
    u16* BSw = BS[pu ^ 1];
    const int tc = (u + 1) << 6;
    bf16x8 bf[4][2];
    bf16x8 af[2][2];
    // P1 (quad 0): all B reads + quad0 A reads; issue ALL next-tile B
#pragma unroll
    for (int n = 0; n < 4; ++n) {
      bf[n][0] = frg(BSr, rB0 + n * 16, 0, lhi);
      bf[n][1] = frg(BSr, rB0 + n * 16, 1, lhi);
    }
    LOADA(0)
    issue(bG, 0, tc, BSw, wid);
    issue(bG, 64, tc, BSw, wid);
    issue(bG, 128, tc, BSw, wid);
    issue(bG, 192, tc, BSw, wid);
    BAR();
    WAIT_LGKM0();
    __builtin_amdgcn_s_setprio(1);
    quad_mfma<0>(af, bf, acc);
    __builtin_amdgcn_s_setprio(0);
    // P2 (quad 1): issue next-tile A first half
    LOADA(1)
    issue(aG, 0, tc, ASw, wid);
    issue(aG, 128, tc, ASw, wid);
    BAR();
    WAIT_LGKM0();
    __builtin_amdgcn_s_setprio(1);
    quad_mfma<1>(af, bf, acc);
    __builtin_amdgcn_s_setprio(0);
    WAIT_VM(6);  // cur-tile A{64-127,192-255} landed
    // P3 (quad 2): issue next-tile A second half
    LOADA(2)
    issue(aG, 64, tc, ASw, wid);
    issue(aG, 192, tc, ASw, wid);
    BAR();
    WAIT_LGKM0();
    __builtin_amdgcn_s_setprio(1);
    quad_mfma<2>(af, bf, acc);
    __builtin_amdgcn_s_setprio(0);
    // P4 (quad 3): no issues
    LOADA(3)
    BAR();
    WAIT_LGKM0();
    __builtin_amdgcn_s_setprio(1);
    quad_mfma<3>(af, bf, acc);
    __builtin_amdgcn_s_setprio(0);
    WAIT_VM(2);  // next-tile B + A first half landed; A second half in flight
    BAR();       // tile boundary
  }
  // peeled tile 15
  {
    const u16* ASr = AS[1];
    const u16* BSr = BS[1];
    WAIT_VM(0);
    BAR();
    bf16x8 bf[4][2];
    bf16x8 af[2][2];
#pragma unroll
    for (int n = 0; n < 4; ++n) {
      bf[n][0] = frg(BSr, rB0 + n * 16, 0, lhi);
      bf[n][1] = frg(BSr, rB0 + n * 16, 1, lhi);
    }
    LOADA(0) quad_mfma<0>(af, bf, acc);
    LOADA(1) quad_mfma<1>(af, bf, acc);
    LOADA(2) quad_mfma<2>(af, bf, acc);
    LOADA(3) quad_mfma<3>(af, bf, acc);
  }

  // epilogue: bias+scale, bounce through LDS, coalesced u16x8 stores
  const int which = bn >> 2;
  const float* bias = (which == 0) ? bq : ((which == 1) ? bk : bv);
  u16* op = (which == 0) ? oq : ((which == 1) ? ok : ov);
  const float scl = (which < 2) ? SCALE_QK : 1.0f;
  const int h = ((bn & 3) << 2) + wn;        // wave's single head
  const int rowBase2 = (bm << 8) + (wm << 7);
  const int rl = lhi << 2;
  const int srow = lane >> 2, d0 = (lane & 3) * 16;
  float bb[4];
#pragma unroll
  for (int n = 0; n < 4; ++n) bb[n] = bias[((bn & 3) << 8) + (wn << 6) + n * 16 + l15];
#pragma unroll
  for (int m = 0; m < 8; ++m) {
#pragma unroll
    for (int n = 0; n < 4; ++n)
#pragma unroll
      for (int r = 0; r < 4; ++r)
        obuf[wid][rl + r][n * 16 + l15] = f2bf((acc[m][n][r] + bb[n]) * scl);
    const int gm = rowBase2 + m * 16 + srow;
    const int b_ = gm >> 12, s = gm & 4095;
    u16* dst = op + (((size_t)b_ * 16 + h) * 4096 + s) * 64 + d0;
    *(u16x8*)dst = *(const u16x8*)&obuf[wid][srow][d0];
    *(u16x8*)(dst + 8) = *(const u16x8*)&obuf[wid][srow][d0 + 8];
  }
}

// ---------------- landmarks: ql/kl f32 + klb bf16 ----------------
__global__ __launch_bounds__(64) void k_lm(const u16* __restrict__ q, const u16* __restrict__ k,
                                           float* __restrict__ ql, float* __restrict__ kl,
                                           u16* __restrict__ klb) {
  const int bid = blockIdx.x;  // bh*64 + l
  const int d = threadIdx.x;
  const u16* qp = q + (size_t)bid * 4096 + d;
  const u16* kp = k + (size_t)bid * 4096 + d;
  float sq = 0.f, sk = 0.f;
#pragma unroll 4
  for (int m = 0; m < 64; ++m) { sq += bf2f(qp[m * 64]); sk += bf2f(kp[m * 64]); }
  const float qm = sq * 0.015625f, km = sk * 0.015625f;
  ql[(size_t)bid * 64 + d] = qm;
  kl[(size_t)bid * 64 + d] = km;
  klb[(size_t)bid * 64 + d] = f2bf(km);
}

// ---------------- kernel_2 = softmax(ql@kl^T); k2t + per-bh max colsum ----------------
__global__ __launch_bounds__(256) void k_k2(const float* __restrict__ ql, const float* __restrict__ kl,
                                            float* __restrict__ k2t, float* __restrict__ colmax) {
  __shared__ __align__(16) float qlT[64 * 68];
  __shared__ __align__(16) float klT[64 * 68];
  __shared__ __align__(16) float sc[64 * 68];
  const int bh = blockIdx.x, t = threadIdx.x;
  {
    const int r = t >> 2, c0 = (t & 3) * 16;
    const float* qp = ql + (size_t)bh * 4096 + r * 64 + c0;
    const float* kp = kl + (size_t)bh * 4096 + r * 64 + c0;
#pragma unroll
    for (int j = 0; j < 16; ++j) { qlT[(c0 + j) * 68 + r] = qp[j]; klT[(c0 + j) * 68 + r] = kp[j]; }
  }
  __syncthreads();
  {
    const int mg = (t >> 4) * 4, lg = (t & 15) * 4;
    float acc[4][4];
#pragma unroll
    for (int i = 0; i < 4; ++i)
#pragma unroll
      for (int j = 0; j < 4; ++j) acc[i][j] = 0.f;
    for (int d0 = 0; d0 < 64; ++d0) {
      f32x4 x = *(const f32x4*)&qlT[d0 * 68 + mg];
      f32x4 y = *(const f32x4*)&klT[d0 * 68 + lg];
#pragma unroll
      for (int i = 0; i < 4; ++i)
#pragma unroll
        for (int j = 0; j < 4; ++j) acc[i][j] += x[i] * y[j];
    }
#pragma unroll
    for (int i = 0; i < 4; ++i)
#pragma unroll
      for (int j = 0; j < 4; ++j) sc[(mg + i) * 68 + lg + j] = acc[i][j];
  }
  __syncthreads();
  if (t < 64) {
    float mx = -1e30f;
    for (int l = 0; l < 64; ++l) mx = fmaxf(mx, sc[t * 68 + l]);
    float sum = 0.f;
    for (int l = 0; l < 64; ++l) { float e = __expf(sc[t * 68 + l] - mx); sc[t * 68 + l] = e; sum += e; }
    const float inv = 1.0f / sum;
    for (int l = 0; l < 64; ++l) sc[t * 68 + l] *= inv;
  }
  __syncthreads();
  {
    const int r = t >> 2, c0 = (t & 3) * 16;
    float* ot = k2t + (size_t)bh * 4096 + r * 64 + c0;
#pragma unroll
    for (int j = 0; j < 16; ++j) ot[j] = sc[(c0 + j) * 68 + r];
  }
  if (t < 64) {
    float s = 0.f;
    for (int m = 0; m < 64; ++m) s += sc[m * 68 + t];
    for (int off = 32; off; off >>= 1) s = fmaxf(s, __shfl_down(s, off, 64));
    if (t == 0) colmax[bh] = s;
  }
}

// ---------------- global max ----------------
__global__ __launch_bounds__(64) void k_max(const float* __restrict__ colmax, float* __restrict__ gmax) {
  const int t = threadIdx.x;
  float v = colmax[t];
  for (int off = 32; off; off >>= 1) v = fmaxf(v, __shfl_down(v, off, 64));
  if (t == 0) *gmax = v;
}

// ---------------- iterative pinv (6 iters, f32, 512 threads) ----------------
__global__ __launch_bounds__(512) void k_pinv(const float* __restrict__ k2t, const float* __restrict__ gmaxp,
                                              float* __restrict__ pinv) {
  __shared__ float valN[4096];
  __shared__ float kvT[4096];
  __shared__ float t1N[4096];
  __shared__ float t2N[4096];
  const int bh = blockIdx.x, t = threadIdx.x;
  const float* aT = k2t + (size_t)bh * 4096;
  const float ginv = 1.0f / gmaxp[0];
  const int rt = t >> 3, ct0 = (t & 7) * 8;
  {
    const float* p = aT + rt * 64 + ct0;
#pragma unroll
    for (int j = 0; j < 8; ++j) valN[rt * 64 + ct0 + j] = p[j] * ginv;
  }
  __syncthreads();
  const int rg = (t >> 4) * 2, cg = (t & 15) * 4;
  float acc[2][4];
  for (int it = 0; it < 6; ++it) {
    // kv = a@val -> kvT
#pragma unroll
    for (int i = 0; i < 2; ++i)
#pragma unroll
      for (int j = 0; j < 4; ++j) acc[i][j] = 0.f;
    for (int k = 0; k < 64; ++k) {
      const float x0 = aT[k * 64 + rg], x1 = aT[k * 64 + rg + 1];
      f32x4 y = *(const f32x4*)&valN[k * 64 + cg];
#pragma unroll
      for (int j = 0; j < 4; ++j) { acc[0][j] += x0 * y[j]; acc[1][j] += x1 * y[j]; }
    }
#pragma unroll
    for (int i = 0; i < 2; ++i)
#pragma unroll
      for (int j = 0; j < 4; ++j) kvT[(cg + j) * 64 + rg + i] = acc[i][j];
    __syncthreads();
    // t1 = 7I - kv
#pragma unroll
    for (int j = 0; j < 8; ++j) {
      const int c = ct0 + j;
      t1N[rt * 64 + c] = ((rt == c) ? 7.0f : 0.0f) - kvT[c * 64 + rt];
    }
    __syncthreads();
    // t2 = 15I - kv@t1
#pragma unroll
    for (int i = 0; i < 2; ++i)
#pragma unroll
      for (int j = 0; j < 4; ++j) acc[i][j] = 0.f;
    for (int k = 0; k < 64; ++k) {
      const float x0 = kvT[k * 64 + rg], x1 = kvT[k * 64 + rg + 1];
      f32x4 y = *(const f32x4*)&t1N[k * 64 + cg];
#pragma unroll
      for (int j = 0; j < 4; ++j) { acc[0][j] += x0 * y[j]; acc[1][j] += x1 * y[j]; }
    }
#pragma unroll
    for (int i = 0; i < 2; ++i)
#pragma unroll
      for (int j = 0; j < 4; ++j) {
        const int r_ = rg + i, c_ = cg + j;
        t2N[r_ * 64 + c_] = ((r_ == c_) ? 15.0f : 0.0f) - acc[i][j];
      }
    __syncthreads();
    // t1 = 13I - kv@t2
#pragma unroll
    for (int i = 0; i < 2; ++i)
#pragma unroll
      for (int j = 0; j < 4; ++j) acc[i][j] = 0.f;
    for (int k = 0; k < 64; ++k) {
      const float x0 = kvT[k * 64 + rg], x1 = kvT[k * 64 + rg + 1];
      f32x4 y = *(const f32x4*)&t2N[k * 64 + cg];
#pragma unroll
      for (int j = 0; j < 4; ++j) { acc[0][j] += x0 * y[j]; acc[1][j] += x1 * y[j]; }
    }
#pragma unroll
    for (int i = 0; i < 2; ++i)
#pragma unroll
      for (int j = 0; j < 4; ++j) {
        const int r_ = rg + i, c_ = cg + j;
        t1N[r_ * 64 + c_] = ((r_ == c_) ? 13.0f : 0.0f) - acc[i][j];
      }
    __syncthreads();
    // t2 = val^T
#pragma unroll
    for (int j = 0; j < 8; ++j) t2N[(ct0 + j) * 64 + rt] = valN[rt * 64 + ct0 + j];
    __syncthreads();
    // val = 0.25 * val@t1
#pragma unroll
    for (int i = 0; i < 2; ++i)
#pragma unroll
      for (int j = 0; j < 4; ++j) acc[i][j] = 0.f;
    for (int k = 0; k < 64; ++k) {
      const float x0 = t2N[k * 64 + rg], x1 = t2N[k * 64 + rg + 1];
      f32x4 y = *(const f32x4*)&t1N[k * 64 + cg];
#pragma unroll
      for (int j = 0; j < 4; ++j) { acc[0][j] += x0 * y[j]; acc[1][j] += x1 * y[j]; }
    }
#pragma unroll
    for (int i = 0; i < 2; ++i)
#pragma unroll
      for (int j = 0; j < 4; ++j) valN[(rg + i) * 64 + cg + j] = 0.25f * acc[i][j];
    __syncthreads();
  }
  {
    float* o = pinv + (size_t)bh * 4096 + rt * 64 + ct0;
#pragma unroll
    for (int j = 0; j < 8; ++j) o[j] = valN[rt * 64 + ct0 + j];
  }
}

// ---------------- fused s3+nv: per (bh,scn) accumulate e@V in regs; partials out, no atomics ----------------
__global__ __launch_bounds__(256) void k_s3nv(const float* __restrict__ ql, const u16* __restrict__ kb,
                                              const u16* __restrict__ vb,
                                              float* __restrict__ nvp, float* __restrict__ zp) {
  __shared__ __align__(16) u16 VT[64][72];
  __shared__ __align__(16) u16 e_lds[4][16][72];
  const int bh = blockIdx.x, scn = blockIdx.y;
  const int t = threadIdx.x, lane = t & 63, w = t >> 6;
  const int l15 = lane & 15, kg = (lane >> 4) << 3, rl = (lane >> 4) << 2;
  // hoist ql A-frags (rows w*16+l15)
  const float* aRow = ql + (size_t)bh * 4096 + (w * 16 + l15) * 64 + kg;
  bf16x8 aql[2];
  aql[0] = ld_f32_to_bf8(aRow);
  aql[1] = ld_f32_to_bf8(aRow + 32);
  f32x4 accv[4];
#pragma unroll
  for (int n = 0; n < 4; ++n) accv[n] = (f32x4){0.f, 0.f, 0.f, 0.f};
  float zacc[4] = {0.f, 0.f, 0.f, 0.f};

  for (int sub = 0; sub < 16; ++sub) {
    const int s0 = scn * 1024 + sub * 64;
    __syncthreads();  // WAR on VT vs prev-iter PV reads
    {
      const u16* vp = vb + ((size_t)bh * 4096 + s0 + lane) * 64 + w * 16;
      u16x8 h0 = *(const u16x8*)vp, h1 = *(const u16x8*)(vp + 8);
#pragma unroll
      for (int j = 0; j < 8; ++j) { VT[w * 16 + j][lane] = h0[j]; VT[w * 16 + 8 + j][lane] = h1[j]; }
    }
    __syncthreads();
    // e = exp(ql · k^T) for this 16L x 64s tile
    const u16* bRow = kb + ((size_t)bh * 4096 + s0 + l15) * 64 + kg;
    f32x4 e[4];
#pragma unroll
    for (int n = 0; n < 4; ++n) e[n] = (f32x4){0.f, 0.f, 0.f, 0.f};
#pragma unroll
    for (int ks = 0; ks < 2; ++ks)
#pragma unroll
      for (int n = 0; n < 4; ++n) {
        bf16x8 bk = *reinterpret_cast<const bf16x8*>(bRow + n * 1024 + ks * 32);
        e[n] = __builtin_amdgcn_mfma_f32_16x16x32_bf16(aql[ks], bk, e[n], 0, 0, 0);
      }
#pragma unroll
    for (int n = 0; n < 4; ++n)
#pragma unroll
      for (int r = 0; r < 4; ++r) {
        const float v = __expf(e[n][r]);
        zacc[r] += v;
        e_lds[w][rl + r][n * 16 + l15] = f2bf(v);
      }
    WAIT_LGKM0();  // e_lds writes complete (same wave)
    // PV: accv += e @ V
#pragma unroll
    for (int ks = 0; ks < 2; ++ks) {
      bf16x8 af = *reinterpret_cast<const bf16x8*>(&e_lds[w][l15][kg + ks * 32]);
#pragma unroll
      for (int n = 0; n < 4; ++n) {
        bf16x8 bf_ = *reinterpret_cast<const bf16x8*>(&VT[n * 16 + l15][kg + ks * 32]);
        accv[n] = __builtin_amdgcn_mfma_f32_16x16x32_bf16(af, bf_, accv[n], 0, 0, 0);
      }
    }
  }
  // write partials
#pragma unroll
  for (int r = 0; r < 4; ++r)
#pragma unroll
    for (int n = 0; n < 4; ++n)
      nvp[(((size_t)scn * 64 + bh) * 64 + w * 16 + rl + r) * 64 + n * 16 + l15] = accv[n][r];
#pragma unroll
  for (int r = 0; r < 4; ++r) {
    float s = zacc[r];
    s += __shfl_xor(s, 1, 64); s += __shfl_xor(s, 2, 64);
    s += __shfl_xor(s, 4, 64); s += __shfl_xor(s, 8, 64);
    if (l15 == 0) zp[((size_t)scn * 64 + bh) * 64 + w * 16 + rl + r] = s;
  }
}

// ---------------- M^T (bf16) = (pinv @ (sum(nvp)/sum(zp)))^T ----------------
__global__ __launch_bounds__(256) void k_pnv(const float* __restrict__ pinv, const float* __restrict__ nvp,
                                             const float* __restrict__ zp, u16* __restrict__ Mtb) {
  __shared__ __align__(16) float XT[64 * 68];
  __shared__ __align__(16) float Y[64 * 68];
  const int bh = blockIdx.x, t = threadIdx.x;
  {
    const int r = t >> 2, c0 = (t & 3) * 16;
    const float* pp = pinv + (size_t)bh * 4096 + r * 64 + c0;
#pragma unroll
    for (int j = 0; j < 16; ++j) XT[(c0 + j) * 68 + r] = pp[j];
    float zs = 0.f;
#pragma unroll
    for (int p = 0; p < 4; ++p) zs += zp[((size_t)p * 64 + bh) * 64 + r];
    const float iz = 1.0f / zs;
#pragma unroll
    for (int j = 0; j < 16; ++j) {
      float s = 0.f;
#pragma unroll
      for (int p = 0; p < 4; ++p) s += nvp[(((size_t)p * 64 + bh) * 64 + r) * 64 + c0 + j];
      Y[r * 68 + c0 + j] = s * iz;
    }
  }
  __syncthreads();
  const int rg = (t >> 4) * 4, cg = (t & 15) * 4;
  float acc[4][4];
#pragma unroll
  for (int i = 0; i < 4; ++i)
#pragma unroll
    for (int j = 0; j < 4; ++j) acc[i][j] = 0.f;
  for (int k = 0; k < 64; ++k) {
    f32x4 x = *(const f32x4*)&XT[k * 68 + rg];
    f32x4 y = *(const f32x4*)&Y[k * 68 + cg];
#pragma unroll
    for (int i = 0; i < 4; ++i)
#pragma unroll
      for (int j = 0; j < 4; ++j) acc[i][j] += x[i] * y[j];
  }
#pragma unroll
  for (int j = 0; j < 4; ++j) {
    u16x4 o = {f2bf(acc[0][j]), f2bf(acc[1][j]), f2bf(acc[2][j]), f2bf(acc[3][j])};
    *(u16x4*)&Mtb[(size_t)bh * 4096 + (cg + j) * 64 + rg] = o;
  }
}

// ---------------- final: softmax(q·kl^T) @ M^T + depthwise conv ----------------
__global__ __launch_bounds__(256) void k_out(const u16* __restrict__ qb, const u16* __restrict__ vb,
                                             const u16* __restrict__ klb, const u16* __restrict__ Mtb,
                                             const float* __restrict__ cw, float* __restrict__ out) {
  __shared__ __align__(16) u16 P_lds[4][16][72];
  __shared__ __align__(16) u16 vtile_t[64][100];  // [d][row]
  __shared__ float wsh[33];
  const int bid = blockIdx.x;
  const int bh = bid >> 6, st = bid & 63;
  const int b = bh >> 4, h = bh & 15;
  const int t = threadIdx.x, lane = t & 63, w = t >> 6;
  const int sbase = st * 64;
  const int l15 = lane & 15, kg = (lane >> 4) << 3, rl = (lane >> 4) << 2;

  if (t < 33) wsh[t] = cw[h * 33 + t];
  for (int idx = t; idx < 96 * 8; idx += 256) {
    const int row = idx >> 3, c8 = idx & 7;
    const int sg = sbase + row - 16;
    u16x8 val = {0, 0, 0, 0, 0, 0, 0, 0};
    if (sg >= 0 && sg < 4096) val = *(const u16x8*)(vb + ((size_t)bh * 4096 + sg) * 64 + c8 * 8);
#pragma unroll
    for (int j = 0; j < 8; ++j) vtile_t[c8 * 8 + j][row] = val[j];
  }

  // QK^T: A = q rows (bf16 global), B = klb rows (bf16)
  f32x4 c1[4];
#pragma unroll
  for (int n = 0; n < 4; ++n) c1[n] = (f32x4){0.f, 0.f, 0.f, 0.f};
  {
    const u16* aRow = qb + ((size_t)bh * 4096 + sbase + w * 16 + l15) * 64 + kg;
    const u16* kRow = klb + (size_t)bh * 4096 + l15 * 64 + kg;
#pragma unroll
    for (int ks = 0; ks < 2; ++ks) {
      bf16x8 af = *reinterpret_cast<const bf16x8*>(aRow + ks * 32);
#pragma unroll
      for (int n = 0; n < 4; ++n) {
        bf16x8 bf_ = *reinterpret_cast<const bf16x8*>(kRow + n * 1024 + ks * 32);
        c1[n] = __builtin_amdgcn_mfma_f32_16x16x32_bf16(af, bf_, c1[n], 0, 0, 0);
      }
    }
  }
  // in-register softmax (no max-sub; scores tiny)
  float invZ[4];
  {
    float z[4] = {0.f, 0.f, 0.f, 0.f};
#pragma unroll
    for (int n = 0; n < 4; ++n)
#pragma unroll
      for (int r = 0; r < 4; ++r) { float v = __expf(c1[n][r]); c1[n][r] = v; z[r] += v; }
#pragma unroll
    for (int r = 0; r < 4; ++r) {
      float s = z[r];
      s += __shfl_xor(s, 1, 64); s += __shfl_xor(s, 2, 64);
      s += __shfl_xor(s, 4, 64); s += __shfl_xor(s, 8, 64);
      invZ[r] = 1.0f / s;
    }
#pragma unroll
    for (int n = 0; n < 4; ++n)
#pragma unroll
      for (int r = 0; r < 4; ++r)
        P_lds[w][rl + r][n * 16 + l15] = f2bf(c1[n][r]);
  }
  __syncthreads();
  // PV: A = P_lds[w], B = Mtb
  f32x4 c2[4];
#pragma unroll
  for (int n = 0; n < 4; ++n) c2[n] = (f32x4){0.f, 0.f, 0.f, 0.f};
  {
    const u16* mRow = Mtb + (size_t)bh * 4096 + l15 * 64 + kg;
#pragma unroll
    for (int ks = 0; ks < 2; ++ks) {
      bf16x8 af = *reinterpret_cast<const bf16x8*>(&P_lds[w][l15][kg + ks * 32]);
#pragma unroll
      for (int n = 0; n < 4; ++n) {
        bf16x8 bf_ = *reinterpret_cast<const bf16x8*>(mRow + n * 1024 + ks * 32);
        c2[n] = __builtin_amdgcn_mfma_f32_16x16x32_bf16(af, bf_, c2[n], 0, 0, 0);
      }
    }
  }
  // conv (vectorized column loads from transposed vtile) + epilogue
  const int base = w * 16 + rl;
#pragma unroll
  for (int n = 0; n < 4; ++n) {
    const int d = n * 16 + l15;
    float vcol[36];
#pragma unroll
    for (int k8 = 0; k8 < 9; ++k8) {
      u16x4 vq = *(const u16x4*)&vtile_t[d][base + k8 * 4];
      vcol[k8 * 4 + 0] = bf2f(vq[0]); vcol[k8 * 4 + 1] = bf2f(vq[1]);
      vcol[k8 * 4 + 2] = bf2f(vq[2]); vcol[k8 * 4 + 3] = bf2f(vq[3]);
    }
    float cv[4] = {0.f, 0.f, 0.f, 0.f};
#pragma unroll
    for (int jt = 0; jt < 33; ++jt) {
      const float ww = wsh[jt];
#pragma unroll
      for (int r = 0; r < 4; ++r) cv[r] += ww * vcol[r + jt];
    }
#pragma unroll
    for (int r = 0; r < 4; ++r) {
      const int sgl = sbase + base + r;
      out[((size_t)b * 4096 + sgl) * 1024 + h * 64 + d] = c2[n][r] * invZ[r] + cv[r];
    }
  }
}

extern "C" void kernel_launch(void* const* d_in, const int* in_sizes, int n_in,
                              void* d_out, int out_size, void* d_ws, size_t ws_size,
                              hipStream_t stream) {
  const float* hidden = (const float*)d_in[0];
  const float* Wq = (const float*)d_in[1];
  const float* bq = (const float*)d_in[2];
  const float* Wk = (const float*)d_in[3];
  const float* bk = (const float*)d_in[4];
  const float* Wv = (const float*)d_in[5];
  const float* bv = (const float*)d_in[6];
  const float* cw = (const float*)d_in[7];
  float* out = (float*)d_out;

  char* ws = (char*)d_ws;
  u16* qb = (u16*)(ws);                           // 32MB
  u16* kb = (u16*)(ws + 33554432ull);             // 32MB
  u16* vb = (u16*)(ws + 67108864ull);             // 32MB
  float* ql = (float*)(ws + 100663296ull);        // 1MB
  float* kl = (float*)(ws + 101711872ull);        // 1MB
  float* k2t = (float*)(ws + 102760448ull);       // 1MB
  float* pinvb = (float*)(ws + 103809024ull);     // 1MB
  float* nvp = (float*)(ws + 104857600ull);       // 4MB
  float* zp = (float*)(ws + 109051904ull);        // 64KB
  u16* Mtb = (u16*)(ws + 109117440ull);           // 512KB
  u16* klb = (u16*)(ws + 109641728ull);           // 1MB
  float* stats = (float*)(ws + 110690304ull);     // 4KB
  u16* wt = (u16*)(ws + 110694400ull);            // 6MB, dead after k_gemm2
  u16* hb = (u16*)(ws + 116985856ull);            // 32MB, dead after k_gemm2

  k_wt<<<768, 256, 0, stream>>>(Wq, Wk, Wv, wt);
  k_hb<<<8192, 256, 0, stream>>>(hidden, hb);
  k_gemm2<<<dim3(64, 12), 512, 0, stream>>>(hb, wt, bq, bk, bv, qb, kb, vb);
  k_lm<<<4096, 64, 0, stream>>>(qb, kb, ql, kl, klb);
  k_k2<<<64, 256, 0, stream>>>(ql, kl, k2t, stats);
  k_max<<<1, 64, 0, stream>>>(stats, stats + 64);
  k_pinv<<<64, 512, 0, stream>>>(k2t, stats + 64, pinvb);
  k_s3nv<<<dim3(64, 4), 256, 0, stream>>>(ql, kb, vb, nvp, zp);
  k_pnv<<<64, 256, 0, stream>>>(pinvb, nvp, zp, Mtb);
  k_out<<<4096, 256, 0, stream>>>(qb, vb, klb, Mtb, cw, out);
  (void)in_sizes; (void)n_in; (void)out_size; (void)ws_size;
}

// Round 5
// 307.201 us; speedup vs baseline: 1.5337x; 1.0381x over previous
//
#include <hip/hip_runtime.h>
#include <stdint.h>

typedef unsigned short u16;
typedef float f32x4 __attribute__((ext_vector_type(4)));
typedef __bf16 bf16x8 __attribute__((ext_vector_type(8)));
typedef u16 u16x8 __attribute__((ext_vector_type(8)));
typedef u16 u16x4 __attribute__((ext_vector_type(4)));

#define SCALE_QK 0.35355339059327373f

#define BAR() asm volatile("s_barrier" ::: "memory")
#define WAIT_LGKM0() do { asm volatile("s_waitcnt lgkmcnt(0)" ::: "memory"); __builtin_amdgcn_sched_barrier(0); } while (0)
#define WAIT_VM(n) do { asm volatile("s_waitcnt vmcnt(" #n ")" ::: "memory"); __builtin_amdgcn_sched_barrier(0); } while (0)

__device__ __forceinline__ u16 f2bf(float f) {
  union { float f; uint32_t u; } x; x.f = f;
  uint32_t r = x.u + 0x7fffu + ((x.u >> 16) & 1u);
  return (u16)(r >> 16);
}
__device__ __forceinline__ float bf2f(u16 h) {
  union { uint32_t u; float f; } x; x.u = ((uint32_t)h) << 16;
  return x.f;
}
__device__ __forceinline__ void gload16(const void* g, void* l) {
  __builtin_amdgcn_global_load_lds((const __attribute__((address_space(1))) void*)g,
                                   (__attribute__((address_space(3))) void*)l, 16, 0, 0);
}
__device__ __forceinline__ bf16x8 ld_f32_to_bf8(const float* p) {
  f32x4 a = *(const f32x4*)p, b = *(const f32x4*)(p + 4);
  union { u16x8 u; bf16x8 h; } c;
  c.u[0] = f2bf(a[0]); c.u[1] = f2bf(a[1]); c.u[2] = f2bf(a[2]); c.u[3] = f2bf(a[3]);
  c.u[4] = f2bf(b[0]); c.u[5] = f2bf(b[1]); c.u[6] = f2bf(b[2]); c.u[7] = f2bf(b[3]);
  return c.h;
}

// ---------------- weight transpose + bf16:  Wt[w][n][k] = bf16(W_w[k][n]) ----------------
__global__ __launch_bounds__(256) void k_wt(const float* __restrict__ Wq, const float* __restrict__ Wk,
                                            const float* __restrict__ Wv, u16* __restrict__ Wt) {
  __shared__ float tile[64][65];
  const int bx = blockIdx.x;
  const int w = bx >> 8, tn = (bx >> 4) & 15, tk = bx & 15;
  const float* W = (w == 0) ? Wq : ((w == 1) ? Wk : Wv);
  const int t = threadIdx.x;
  const int r = t >> 2, c0 = (t & 3) * 16;
  const float* src = W + (size_t)(tk * 64 + r) * 1024 + tn * 64 + c0;
#pragma unroll
  for (int j = 0; j < 16; j += 4) {
    f32x4 x = *(const f32x4*)(src + j);
    tile[r][c0 + j + 0] = x[0]; tile[r][c0 + j + 1] = x[1];
    tile[r][c0 + j + 2] = x[2]; tile[r][c0 + j + 3] = x[3];
  }
  __syncthreads();
  u16* dst = Wt + (size_t)(w * 1024 + tn * 64 + r) * 1024 + tk * 64 + c0;
#pragma unroll
  for (int j = 0; j < 16; ++j) dst[j] = f2bf(tile[c0 + j][r]);
}

// ---------------- hidden -> bf16 ----------------
__global__ __launch_bounds__(256) void k_hb(const float* __restrict__ in, u16* __restrict__ out) {
  const size_t i = ((size_t)blockIdx.x * 256 + threadIdx.x) * 8;
  f32x4 v0 = *(const f32x4*)(in + i);
  f32x4 v1 = *(const f32x4*)(in + i + 4);
  u16x8 o;
  o[0] = f2bf(v0[0]); o[1] = f2bf(v0[1]); o[2] = f2bf(v0[2]); o[3] = f2bf(v0[3]);
  o[4] = f2bf(v1[0]); o[5] = f2bf(v1[1]); o[6] = f2bf(v1[2]); o[7] = f2bf(v1[3]);
  *(u16x8*)(out + i) = o;
}

// ---------------- 256x256x64 8-wave GEMM, software-pipelined frags, 1 barrier/tile ----------------
__device__ __forceinline__ bf16x8 frg(const u16* buf, int row, int ks, int lhi) {
  const int ck = (ks << 2) + lhi;
  return *reinterpret_cast<const bf16x8*>(buf + (row << 6) + ((ck ^ (row & 7)) << 3));
}
__device__ __forceinline__ void issue(const u16* g, int rowbase, int tc, u16* ldsbase, int wid) {
  gload16(g + (((size_t)rowbase) << 10) + tc, ldsbase + ((rowbase + (wid << 3)) << 6));
}
template <int Q>
__device__ __forceinline__ void quad_mfma(const bf16x8 (&af)[2][2], const bf16x8 (&bf)[4][2],
                                          f32x4 (&acc)[8][4]) {
#pragma unroll
  for (int mm = 0; mm < 2; ++mm)
#pragma unroll
    for (int n = 0; n < 4; ++n) {
      acc[Q * 2 + mm][n] = __builtin_amdgcn_mfma_f32_16x16x32_bf16(af[mm][0], bf[n][0], acc[Q * 2 + mm][n], 0, 0, 0);
      acc[Q * 2 + mm][n] = __builtin_amdgcn_mfma_f32_16x16x32_bf16(af[mm][1], bf[n][1], acc[Q * 2 + mm][n], 0, 0, 0);
    }
}
#define LOADA_TO(dst, Q)                                     \
  dst[0][0] = frg(ASr, rA0 + (Q)*32, 0, lhi);                \
  dst[0][1] = frg(ASr, rA0 + (Q)*32, 1, lhi);                \
  dst[1][0] = frg(ASr, rA0 + (Q)*32 + 16, 0, lhi);           \
  dst[1][1] = frg(ASr, rA0 + (Q)*32 + 16, 1, lhi);

__global__ __launch_bounds__(512) void k_gemm2(const u16* __restrict__ A, const u16* __restrict__ Bt,
                                               const float* __restrict__ bq, const float* __restrict__ bk,
                                               const float* __restrict__ bv,
                                               u16* __restrict__ oq, u16* __restrict__ ok, u16* __restrict__ ov,
                                               float* __restrict__ ql, float* __restrict__ kl) {
  __shared__ __align__(16) u16 AS[2][256 * 64];
  __shared__ __align__(16) u16 BS[2][256 * 64];
  __shared__ __align__(16) u16 obuf[8][16][70];
  const int t = threadIdx.x, lane = t & 63, wid = t >> 6;
  const int wm = wid >> 2, wn = wid & 3;
  const int bm = blockIdx.x, bn = blockIdx.y;
  const int l15 = lane & 15, lhi = lane >> 4;

  const int rowoff = t >> 3;
  const int cswz = (t & 7) ^ (rowoff & 7);
  const u16* aG = A + (((size_t)(bm * 256 + rowoff)) << 10) + (cswz << 3);
  const u16* bG = Bt + (((size_t)(bn * 256 + rowoff)) << 10) + (cswz << 3);

  const int rA0 = wm * 128 + l15;
  const int rB0 = wn * 64 + l15;

  f32x4 acc[8][4];
#pragma unroll
  for (int m = 0; m < 8; ++m)
#pragma unroll
    for (int n = 0; n < 4; ++n) acc[m][n] = (f32x4){0.f, 0.f, 0.f, 0.f};

  // prologue: tile 0 -> buf 0, full drain (no cross-barrier in-flight needed)
  issue(bG, 0, 0, BS[0], wid);
  issue(bG, 64, 0, BS[0], wid);
  issue(bG, 128, 0, BS[0], wid);
  issue(bG, 192, 0, BS[0], wid);
  issue(aG, 0, 0, AS[0], wid);
  issue(aG, 128, 0, AS[0], wid);
  issue(aG, 64, 0, AS[0], wid);
  issue(aG, 192, 0, AS[0], wid);
  WAIT_VM(0);
  BAR();

  for (int u = 0; u < 15; ++u) {
    const int pu = u & 1;
    const u16* ASr = AS[pu];
    const u16* BSr = BS[pu];
    u16* ASw = AS[pu ^ 1];
    u16* BSw = BS[pu ^ 1];
    const int tc = (u + 1) << 6;
    bf16x8 bfr[4][2];
    bf16x8 afA[2][2], afB[2][2];
    // P0: read B(8) + A-quad0 + A-quad1; issue next-tile B(4) + A-first(2); MFMA quad0
#pragma unroll
    for (int n = 0; n < 4; ++n) {
      bfr[n][0] = frg(BSr, rB0 + n * 16, 0, lhi);
      bfr[n][1] = frg(BSr, rB0 + n * 16, 1, lhi);
    }
    LOADA_TO(afA, 0)
    LOADA_TO(afB, 1)
    issue(bG, 0, tc, BSw, wid);
    issue(bG, 64, tc, BSw, wid);
    issue(bG, 128, tc, BSw, wid);
    issue(bG, 192, tc, BSw, wid);
    issue(aG, 0, tc, ASw, wid);
    issue(aG, 128, tc, ASw, wid);
    __builtin_amdgcn_s_setprio(1);
    quad_mfma<0>(afA, bfr, acc);   // A-quad1 reads in flight under these MFMAs
    __builtin_amdgcn_s_setprio(0);
    // P1: read A-quad2; issue next-tile A-second(2); MFMA quad1
    LOADA_TO(afA, 2)
    issue(aG, 64, tc, ASw, wid);
    issue(aG, 192, tc, ASw, wid);
    __builtin_amdgcn_s_setprio(1);
    quad_mfma<1>(afB, bfr, acc);
    __builtin_amdgcn_s_setprio(0);
    // P2: read A-quad3; MFMA quad2
    LOADA_TO(afB, 3)
    __builtin_amdgcn_s_setprio(1);
    quad_mfma<2>(afA, bfr, acc);
    __builtin_amdgcn_s_setprio(0);
    // P3: MFMA quad3
    __builtin_amdgcn_s_setprio(1);
    quad_mfma<3>(afB, bfr, acc);
    __builtin_amdgcn_s_setprio(0);
    WAIT_VM(0);  // per-wave: next-tile loads landed (issued 2.5-3.5 phases ago)
    BAR();       // publish buf, protect WAR on the buffer being swapped in
  }
  // peeled tile 15 (buf 1, no staging)
  {
    const u16* ASr = AS[1];
    const u16* BSr = BS[1];
    bf16x8 bfr[4][2];
    bf16x8 afA[2][2], afB[2][2];
#pragma unroll
    for (int n = 0; n < 4; ++n) {
      bfr[n][0] = frg(BSr, rB0 + n * 16, 0, lhi);
      bfr[n][1] = frg(BSr, rB0 + n * 16, 1, lhi);
    }
    LOADA_TO(afA, 0)
    LOADA_TO(afB, 1)
    quad_mfma<0>(afA, bfr, acc);
    LOADA_TO(afA, 2)
    quad_mfma<1>(afB, bfr, acc);
    LOADA_TO(afB, 3)
    quad_mfma<2>(afA, bfr, acc);
    quad_mfma<3>(afB, bfr, acc);
  }

  // ---- epilogue: bias+scale, LDS bounce, coalesced stores; fused landmark means ----
  const int which = bn >> 2;
  const float* bias = (which == 0) ? bq : ((which == 1) ? bk : bv);
  u16* op = (which == 0) ? oq : ((which == 1) ? ok : ov);
  const float scl = (which < 2) ? SCALE_QK : 1.0f;
  const int h = ((bn & 3) << 2) + wn;  // wave's single head
  const int rowBase2 = (bm << 8) + (wm << 7);
  const int rl = lhi << 2;
  const int srow = lane >> 2, d0 = (lane & 3) * 16;
  float bb[4];
#pragma unroll
  for (int n = 0; n < 4; ++n) bb[n] = bias[((bn & 3) << 8) + (wn << 6) + n * 16 + l15];
#pragma unroll
  for (int m = 0; m < 8; ++m) {
#pragma unroll
    for (int n = 0; n < 4; ++n)
#pragma unroll
      for (int r = 0; r < 4; ++r)
        obuf[wid][rl + r][n * 16 + l15] = f2bf((acc[m][n][r] + bb[n]) * scl);
    const int gm = rowBase2 + m * 16 + srow;
    const int b_ = gm >> 12, s = gm & 4095;
    u16* dst = op + (((size_t)b_ * 16 + h) * 4096 + s) * 64 + d0;
    *(u16x8*)dst = *(const u16x8*)&obuf[wid][srow][d0];
    *(u16x8*)(dst + 8) = *(const u16x8*)&obuf[wid][srow][d0 + 8];
  }
  // landmark segment means (q/k only): wave owns segments {wm*2, wm*2+1} of this bm-block
  if (which < 2) {
    float* lmp = (which == 0) ? ql : kl;
    const int bh = ((bm >> 4) << 4) + h;
#pragma unroll
    for (int sg = 0; sg < 2; ++sg) {
#pragma unroll
      for (int n = 0; n < 4; ++n) {
        float s = 0.f;
#pragma unroll
        for (int mi = 0; mi < 4; ++mi)
#pragma unroll
          for (int r = 0; r < 4; ++r) s += (acc[sg * 4 + mi][n][r] + bb[n]) * scl;
        s += __shfl_xor(s, 16, 64);
        s += __shfl_xor(s, 32, 64);
        if (lhi == 0) {
          const int lseg = ((bm & 15) << 2) + (wm << 1) + sg;
          lmp[(size_t)bh * 4096 + lseg * 64 + n * 16 + l15] = s * 0.015625f;
        }
      }
    }
  }
}

// ---------------- kernel_2 = softmax(ql@kl^T); k2t + colmax; also emit klb bf16 ----------------
__global__ __launch_bounds__(256) void k_k2(const float* __restrict__ ql, const float* __restrict__ kl,
                                            float* __restrict__ k2t, float* __restrict__ colmax,
                                            u16* __restrict__ klb) {
  __shared__ __align__(16) float qlT[64 * 68];
  __shared__ __align__(16) float klT[64 * 68];
  __shared__ __align__(16) float sc[64 * 68];
  const int bh = blockIdx.x, t = threadIdx.x;
  {
    const int r = t >> 2, c0 = (t & 3) * 16;
    const float* qp = ql + (size_t)bh * 4096 + r * 64 + c0;
    const float* kp = kl + (size_t)bh * 4096 + r * 64 + c0;
    u16* kb_ = klb + (size_t)bh * 4096 + r * 64 + c0;
#pragma unroll
    for (int j = 0; j < 16; ++j) {
      qlT[(c0 + j) * 68 + r] = qp[j];
      const float kv = kp[j];
      klT[(c0 + j) * 68 + r] = kv;
      kb_[j] = f2bf(kv);
    }
  }
  __syncthreads();
  {
    const int mg = (t >> 4) * 4, lg = (t & 15) * 4;
    float acc[4][4];
#pragma unroll
    for (int i = 0; i < 4; ++i)
#pragma unroll
      for (int j = 0; j < 4; ++j) acc[i][j] = 0.f;
    for (int d0 = 0; d0 < 64; ++d0) {
      f32x4 x = *(const f32x4*)&qlT[d0 * 68 + mg];
      f32x4 y = *(const f32x4*)&klT[d0 * 68 + lg];
#pragma unroll
      for (int i = 0; i < 4; ++i)
#pragma unroll
        for (int j = 0; j < 4; ++j) acc[i][j] += x[i] * y[j];
    }
#pragma unroll
    for (int i = 0; i < 4; ++i)
#pragma unroll
      for (int j = 0; j < 4; ++j) sc[(mg + i) * 68 + lg + j] = acc[i][j];
  }
  __syncthreads();
  if (t < 64) {
    float mx = -1e30f;
    for (int l = 0; l < 64; ++l) mx = fmaxf(mx, sc[t * 68 + l]);
    float sum = 0.f;
    for (int l = 0; l < 64; ++l) { float e = __expf(sc[t * 68 + l] - mx); sc[t * 68 + l] = e; sum += e; }
    const float inv = 1.0f / sum;
    for (int l = 0; l < 64; ++l) sc[t * 68 + l] *= inv;
  }
  __syncthreads();
  {
    const int r = t >> 2, c0 = (t & 3) * 16;
    float* ot = k2t + (size_t)bh * 4096 + r * 64 + c0;
#pragma unroll
    for (int j = 0; j < 16; ++j) ot[j] = sc[(c0 + j) * 68 + r];
  }
  if (t < 64) {
    float s = 0.f;
    for (int m = 0; m < 64; ++m) s += sc[m * 68 + t];
    for (int off = 32; off; off >>= 1) s = fmaxf(s, __shfl_down(s, off, 64));
    if (t == 0) colmax[bh] = s;
  }
}

// ---------------- global max ----------------
__global__ __launch_bounds__(64) void k_max(const float* __restrict__ colmax, float* __restrict__ gmax) {
  const int t = threadIdx.x;
  float v = colmax[t];
  for (int off = 32; off; off >>= 1) v = fmaxf(v, __shfl_down(v, off, 64));
  if (t == 0) *gmax = v;
}

// ---------------- iterative pinv (6 iters, f32, 512 threads) ----------------
__global__ __launch_bounds__(512) void k_pinv(const float* __restrict__ k2t, const float* __restrict__ gmaxp,
                                              float* __restrict__ pinv) {
  __shared__ float valN[4096];
  __shared__ float kvT[4096];
  __shared__ float t1N[4096];
  __shared__ float t2N[4096];
  const int bh = blockIdx.x, t = threadIdx.x;
  const float* aT = k2t + (size_t)bh * 4096;
  const float ginv = 1.0f / gmaxp[0];
  const int rt = t >> 3, ct0 = (t & 7) * 8;
  {
    const float* p = aT + rt * 64 + ct0;
#pragma unroll
    for (int j = 0; j < 8; ++j) valN[rt * 64 + ct0 + j] = p[j] * ginv;
  }
  __syncthreads();
  const int rg = (t >> 4) * 2, cg = (t & 15) * 4;
  float acc[2][4];
  for (int it = 0; it < 6; ++it) {
#pragma unroll
    for (int i = 0; i < 2; ++i)
#pragma unroll
      for (int j = 0; j < 4; ++j) acc[i][j] = 0.f;
    for (int k = 0; k < 64; ++k) {
      const float x0 = aT[k * 64 + rg], x1 = aT[k * 64 + rg + 1];
      f32x4 y = *(const f32x4*)&valN[k * 64 + cg];
#pragma unroll
      for (int j = 0; j < 4; ++j) { acc[0][j] += x0 * y[j]; acc[1][j] += x1 * y[j]; }
    }
#pragma unroll
    for (int i = 0; i < 2; ++i)
#pragma unroll
      for (int j = 0; j < 4; ++j) kvT[(cg + j) * 64 + rg + i] = acc[i][j];
    __syncthreads();
#pragma unroll
    for (int j = 0; j < 8; ++j) {
      const int c = ct0 + j;
      t1N[rt * 64 + c] = ((rt == c) ? 7.0f : 0.0f) - kvT[c * 64 + rt];
    }
    __syncthreads();
#pragma unroll
    for (int i = 0; i < 2; ++i)
#pragma unroll
      for (int j = 0; j < 4; ++j) acc[i][j] = 0.f;
    for (int k = 0; k < 64; ++k) {
      const float x0 = kvT[k * 64 + rg], x1 = kvT[k * 64 + rg + 1];
      f32x4 y = *(const f32x4*)&t1N[k * 64 + cg];
#pragma unroll
      for (int j = 0; j < 4; ++j) { acc[0][j] += x0 * y[j]; acc[1][j] += x1 * y[j]; }
    }
#pragma unroll
    for (int i = 0; i < 2; ++i)
#pragma unroll
      for (int j = 0; j < 4; ++j) {
        const int r_ = rg + i, c_ = cg + j;
        t2N[r_ * 64 + c_] = ((r_ == c_) ? 15.0f : 0.0f) - acc[i][j];
      }
    __syncthreads();
#pragma unroll
    for (int i = 0; i < 2; ++i)
#pragma unroll
      for (int j = 0; j < 4; ++j) acc[i][j] = 0.f;
    for (int k = 0; k < 64; ++k) {
      const float x0 = kvT[k * 64 + rg], x1 = kvT[k * 64 + rg + 1];
      f32x4 y = *(const f32x4*)&t2N[k * 64 + cg];
#pragma unroll
      for (int j = 0; j < 4; ++j) { acc[0][j] += x0 * y[j]; acc[1][j] += x1 * y[j]; }
    }
#pragma unroll
    for (int i = 0; i < 2; ++i)
#pragma unroll
      for (int j = 0; j < 4; ++j) {
        const int r_ = rg + i, c_ = cg + j;
        t1N[r_ * 64 + c_] = ((r_ == c_) ? 13.0f : 0.0f) - acc[i][j];
      }
    __syncthreads();
#pragma unroll
    for (int j = 0; j < 8; ++j) t2N[(ct0 + j) * 64 + rt] = valN[rt * 64 + ct0 + j];
    __syncthreads();
#pragma unroll
    for (int i = 0; i < 2; ++i)
#pragma unroll
      for (int j = 0; j < 4; ++j) acc[i][j] = 0.f;
    for (int k = 0; k < 64; ++k) {
      const float x0 = t2N[k * 64 + rg], x1 = t2N[k * 64 + rg + 1];
      f32x4 y = *(const f32x4*)&t1N[k * 64 + cg];
#pragma unroll
      for (int j = 0; j < 4; ++j) { acc[0][j] += x0 * y[j]; acc[1][j] += x1 * y[j]; }
    }
#pragma unroll
    for (int i = 0; i < 2; ++i)
#pragma unroll
      for (int j = 0; j < 4; ++j) valN[(rg + i) * 64 + cg + j] = 0.25f * acc[i][j];
    __syncthreads();
  }
  {
    float* o = pinv + (size_t)bh * 4096 + rt * 64 + ct0;
#pragma unroll
    for (int j = 0; j < 8; ++j) o[j] = valN[rt * 64 + ct0 + j];
  }
}

// ---------------- fused s3+nv: per (bh,scn) accumulate e@V in regs; partials out, no atomics ----------------
__global__ __launch_bounds__(256) void k_s3nv(const float* __restrict__ ql, const u16* __restrict__ kb,
                                              const u16* __restrict__ vb,
                                              float* __restrict__ nvp, float* __restrict__ zp) {
  __shared__ __align__(16) u16 VT[64][72];
  __shared__ __align__(16) u16 e_lds[4][16][72];
  const int bh = blockIdx.x, scn = blockIdx.y;
  const int t = threadIdx.x, lane = t & 63, w = t >> 6;
  const int l15 = lane & 15, kg = (lane >> 4) << 3, rl = (lane >> 4) << 2;
  const float* aRow = ql + (size_t)bh * 4096 + (w * 16 + l15) * 64 + kg;
  bf16x8 aql[2];
  aql[0] = ld_f32_to_bf8(aRow);
  aql[1] = ld_f32_to_bf8(aRow + 32);
  f32x4 accv[4];
#pragma unroll
  for (int n = 0; n < 4; ++n) accv[n] = (f32x4){0.f, 0.f, 0.f, 0.f};
  float zacc[4] = {0.f, 0.f, 0.f, 0.f};

  for (int sub = 0; sub < 16; ++sub) {
    const int s0 = scn * 1024 + sub * 64;
    __syncthreads();
    {
      const u16* vp = vb + ((size_t)bh * 4096 + s0 + lane) * 64 + w * 16;
      u16x8 h0 = *(const u16x8*)vp, h1 = *(const u16x8*)(vp + 8);
#pragma unroll
      for (int j = 0; j < 8; ++j) { VT[w * 16 + j][lane] = h0[j]; VT[w * 16 + 8 + j][lane] = h1[j]; }
    }
    __syncthreads();
    const u16* bRow = kb + ((size_t)bh * 4096 + s0 + l15) * 64 + kg;
    f32x4 e[4];
#pragma unroll
    for (int n = 0; n < 4; ++n) e[n] = (f32x4){0.f, 0.f, 0.f, 0.f};
#pragma unroll
    for (int ks = 0; ks < 2; ++ks)
#pragma unroll
      for (int n = 0; n < 4; ++n) {
        bf16x8 bk = *reinterpret_cast<const bf16x8*>(bRow + n * 1024 + ks * 32);
        e[n] = __builtin_amdgcn_mfma_f32_16x16x32_bf16(aql[ks], bk, e[n], 0, 0, 0);
      }
#pragma unroll
    for (int n = 0; n < 4; ++n)
#pragma unroll
      for (int r = 0; r < 4; ++r) {
        const float v = __expf(e[n][r]);
        zacc[r] += v;
        e_lds[w][rl + r][n * 16 + l15] = f2bf(v);
      }
    WAIT_LGKM0();
#pragma unroll
    for (int ks = 0; ks < 2; ++ks) {
      bf16x8 af = *reinterpret_cast<const bf16x8*>(&e_lds[w][l15][kg + ks * 32]);
#pragma unroll
      for (int n = 0; n < 4; ++n) {
        bf16x8 bf_ = *reinterpret_cast<const bf16x8*>(&VT[n * 16 + l15][kg + ks * 32]);
        accv[n] = __builtin_amdgcn_mfma_f32_16x16x32_bf16(af, bf_, accv[n], 0, 0, 0);
      }
    }
  }
#pragma unroll
  for (int r = 0; r < 4; ++r)
#pragma unroll
    for (int n = 0; n < 4; ++n)
      nvp[(((size_t)scn * 64 + bh) * 64 + w * 16 + rl + r) * 64 + n * 16 + l15] = accv[n][r];
#pragma unroll
  for (int r = 0; r < 4; ++r) {
    float s = zacc[r];
    s += __shfl_xor(s, 1, 64); s += __shfl_xor(s, 2, 64);
    s += __shfl_xor(s, 4, 64); s += __shfl_xor(s, 8, 64);
    if (l15 == 0) zp[((size_t)scn * 64 + bh) * 64 + w * 16 + rl + r] = s;
  }
}

// ---------------- M^T (bf16) = (pinv @ (sum(nvp)/sum(zp)))^T ----------------
__global__ __launch_bounds__(256) void k_pnv(const float* __restrict__ pinv, const float* __restrict__ nvp,
                                             const float* __restrict__ zp, u16* __restrict__ Mtb) {
  __shared__ __align__(16) float XT[64 * 68];
  __shared__ __align__(16) float Y[64 * 68];
  const int bh = blockIdx.x, t = threadIdx.x;
  {
    const int r = t >> 2, c0 = (t & 3) * 16;
    const float* pp = pinv + (size_t)bh * 4096 + r * 64 + c0;
#pragma unroll
    for (int j = 0; j < 16; ++j) XT[(c0 + j) * 68 + r] = pp[j];
    float zs = 0.f;
#pragma unroll
    for (int p = 0; p < 4; ++p) zs += zp[((size_t)p * 64 + bh) * 64 + r];
    const float iz = 1.0f / zs;
#pragma unroll
    for (int j = 0; j < 16; ++j) {
      float s = 0.f;
#pragma unroll
      for (int p = 0; p < 4; ++p) s += nvp[(((size_t)p * 64 + bh) * 64 + r) * 64 + c0 + j];
      Y[r * 68 + c0 + j] = s * iz;
    }
  }
  __syncthreads();
  const int rg = (t >> 4) * 4, cg = (t & 15) * 4;
  float acc[4][4];
#pragma unroll
  for (int i = 0; i < 4; ++i)
#pragma unroll
    for (int j = 0; j < 4; ++j) acc[i][j] = 0.f;
  for (int k = 0; k < 64; ++k) {
    f32x4 x = *(const f32x4*)&XT[k * 68 + rg];
    f32x4 y = *(const f32x4*)&Y[k * 68 + cg];
#pragma unroll
    for (int i = 0; i < 4; ++i)
#pragma unroll
      for (int j = 0; j < 4; ++j) acc[i][j] += x[i] * y[j];
  }
#pragma unroll
  for (int j = 0; j < 4; ++j) {
    u16x4 o = {f2bf(acc[0][j]), f2bf(acc[1][j]), f2bf(acc[2][j]), f2bf(acc[3][j])};
    *(u16x4*)&Mtb[(size_t)bh * 4096 + (cg + j) * 64 + rg] = o;
  }
}

// ---------------- final: softmax(q·kl^T) @ M^T + depthwise conv ----------------
__global__ __launch_bounds__(256) void k_out(const u16* __restrict__ qb, const u16* __restrict__ vb,
                                             const u16* __restrict__ klb, const u16* __restrict__ Mtb,
                                             const float* __restrict__ cw, float* __restrict__ out) {
  __shared__ __align__(16) u16 P_lds[4][16][72];
  __shared__ __align__(16) u16 vtile_t[64][100];  // [d][row]
  __shared__ float wsh[33];
  const int bid = blockIdx.x;
  const int bh = bid >> 6, st = bid & 63;
  const int b = bh >> 4, h = bh & 15;
  const int t = threadIdx.x, lane = t & 63, w = t >> 6;
  const int sbase = st * 64;
  const int l15 = lane & 15, kg = (lane >> 4) << 3, rl = (lane >> 4) << 2;

  if (t < 33) wsh[t] = cw[h * 33 + t];
  for (int idx = t; idx < 96 * 8; idx += 256) {
    const int row = idx >> 3, c8 = idx & 7;
    const int sg = sbase + row - 16;
    u16x8 val = {0, 0, 0, 0, 0, 0, 0, 0};
    if (sg >= 0 && sg < 4096) val = *(const u16x8*)(vb + ((size_t)bh * 4096 + sg) * 64 + c8 * 8);
#pragma unroll
    for (int j = 0; j < 8; ++j) vtile_t[c8 * 8 + j][row] = val[j];
  }

  f32x4 c1[4];
#pragma unroll
  for (int n = 0; n < 4; ++n) c1[n] = (f32x4){0.f, 0.f, 0.f, 0.f};
  {
    const u16* aRow = qb + ((size_t)bh * 4096 + sbase + w * 16 + l15) * 64 + kg;
    const u16* kRow = klb + (size_t)bh * 4096 + l15 * 64 + kg;
#pragma unroll
    for (int ks = 0; ks < 2; ++ks) {
      bf16x8 af = *reinterpret_cast<const bf16x8*>(aRow + ks * 32);
#pragma unroll
      for (int n = 0; n < 4; ++n) {
        bf16x8 bf_ = *reinterpret_cast<const bf16x8*>(kRow + n * 1024 + ks * 32);
        c1[n] = __builtin_amdgcn_mfma_f32_16x16x32_bf16(af, bf_, c1[n], 0, 0, 0);
      }
    }
  }
  float invZ[4];
  {
    float z[4] = {0.f, 0.f, 0.f, 0.f};
#pragma unroll
    for (int n = 0; n < 4; ++n)
#pragma unroll
      for (int r = 0; r < 4; ++r) { float v = __expf(c1[n][r]); c1[n][r] = v; z[r] += v; }
#pragma unroll
    for (int r = 0; r < 4; ++r) {
      float s = z[r];
      s += __shfl_xor(s, 1, 64); s += __shfl_xor(s, 2, 64);
      s += __shfl_xor(s, 4, 64); s += __shfl_xor(s, 8, 64);
      invZ[r] = 1.0f / s;
    }
#pragma unroll
    for (int n = 0; n < 4; ++n)
#pragma unroll
      for (int r = 0; r < 4; ++r)
        P_lds[w][rl + r][n * 16 + l15] = f2bf(c1[n][r]);
  }
  __syncthreads();
  f32x4 c2[4];
#pragma unroll
  for (int n = 0; n < 4; ++n) c2[n] = (f32x4){0.f, 0.f, 0.f, 0.f};
  {
    const u16* mRow = Mtb + (size_t)bh * 4096 + l15 * 64 + kg;
#pragma unroll
    for (int ks = 0; ks < 2; ++ks) {
      bf16x8 af = *reinterpret_cast<const bf16x8*>(&P_lds[w][l15][kg + ks * 32]);
#pragma unroll
      for (int n = 0; n < 4; ++n) {
        bf16x8 bf_ = *reinterpret_cast<const bf16x8*>(mRow + n * 1024 + ks * 32);
        c2[n] = __builtin_amdgcn_mfma_f32_16x16x32_bf16(af, bf_, c2[n], 0, 0, 0);
      }
    }
  }
  const int base = w * 16 + rl;
#pragma unroll
  for (int n = 0; n < 4; ++n) {
    const int d = n * 16 + l15;
    float vcol[36];
#pragma unroll
    for (int k8 = 0; k8 < 9; ++k8) {
      u16x4 vq = *(const u16x4*)&vtile_t[d][base + k8 * 4];
      vcol[k8 * 4 + 0] = bf2f(vq[0]); vcol[k8 * 4 + 1] = bf2f(vq[1]);
      vcol[k8 * 4 + 2] = bf2f(vq[2]); vcol[k8 * 4 + 3] = bf2f(vq[3]);
    }
    float cv[4] = {0.f, 0.f, 0.f, 0.f};
#pragma unroll
    for (int jt = 0; jt < 33; ++jt) {
      const float ww = wsh[jt];
#pragma unroll
      for (int r = 0; r < 4; ++r) cv[r] += ww * vcol[r + jt];
    }
#pragma unroll
    for (int r = 0; r < 4; ++r) {
      const int sgl = sbase + base + r;
      out[((size_t)b * 4096 + sgl) * 1024 + h * 64 + d] = c2[n][r] * invZ[r] + cv[r];
    }
  }
}

extern "C" void kernel_launch(void* const* d_in, const int* in_sizes, int n_in,
                              void* d_out, int out_size, void* d_ws, size_t ws_size,
                              hipStream_t stream) {
  const float* hidden = (const float*)d_in[0];
  const float* Wq = (const float*)d_in[1];
  const float* bq = (const float*)d_in[2];
  const float* Wk = (const float*)d_in[3];
  const float* bk = (const float*)d_in[4];
  const float* Wv = (const float*)d_in[5];
  const float* bv = (const float*)d_in[6];
  const float* cw = (const float*)d_in[7];
  float* out = (float*)d_out;

  char* ws = (char*)d_ws;
  u16* qb = (u16*)(ws);                           // 32MB
  u16* kb = (u16*)(ws + 33554432ull);             // 32MB
  u16* vb = (u16*)(ws + 67108864ull);             // 32MB
  float* ql = (float*)(ws + 100663296ull);        // 1MB
  float* kl = (float*)(ws + 101711872ull);        // 1MB
  float* k2t = (float*)(ws + 102760448ull);       // 1MB
  float* pinvb = (float*)(ws + 103809024ull);     // 1MB
  float* nvp = (float*)(ws + 104857600ull);       // 4MB
  float* zp = (float*)(ws + 109051904ull);        // 64KB
  u16* Mtb = (u16*)(ws + 109117440ull);           // 512KB
  u16* klb = (u16*)(ws + 109641728ull);           // 1MB
  float* stats = (float*)(ws + 110690304ull);     // 4KB
  u16* wt = (u16*)(ws + 110694400ull);            // 6MB, dead after k_gemm2
  u16* hb = (u16*)(ws + 116985856ull);            // 32MB, dead after k_gemm2

  k_wt<<<768, 256, 0, stream>>>(Wq, Wk, Wv, wt);
  k_hb<<<8192, 256, 0, stream>>>(hidden, hb);
  k_gemm2<<<dim3(64, 12), 512, 0, stream>>>(hb, wt, bq, bk, bv, qb, kb, vb, ql, kl);
  k_k2<<<64, 256, 0, stream>>>(ql, kl, k2t, stats, klb);
  k_max<<<1, 64, 0, stream>>>(stats, stats + 64);
  k_pinv<<<64, 512, 0, stream>>>(k2t, stats + 64, pinvb);
  k_s3nv<<<dim3(64, 4), 256, 0, stream>>>(ql, kb, vb, nvp, zp);
  k_pnv<<<64, 256, 0, stream>>>(pinvb, nvp, zp, Mtb);
  k_out<<<4096, 256, 0, stream>>>(qb, vb, klb, Mtb, cw, out);
  (void)in_sizes; (void)n_in; (void)out_size; (void)ws_size;
}

// Round 6
// 298.140 us; speedup vs baseline: 1.5803x; 1.0304x over previous
//
#include <hip/hip_runtime.h>
#include <stdint.h>

typedef unsigned short u16;
typedef float f32x4 __attribute__((ext_vector_type(4)));
typedef __bf16 bf16x8 __attribute__((ext_vector_type(8)));
typedef u16 u16x8 __attribute__((ext_vector_type(8)));
typedef u16 u16x4 __attribute__((ext_vector_type(4)));

#define SCALE_QK 0.35355339059327373f

#define BAR() asm volatile("s_barrier" ::: "memory")
#define WAIT_LGKM0() do { asm volatile("s_waitcnt lgkmcnt(0)" ::: "memory"); __builtin_amdgcn_sched_barrier(0); } while (0)
#define WAIT_VM(n) do { asm volatile("s_waitcnt vmcnt(" #n ")" ::: "memory"); __builtin_amdgcn_sched_barrier(0); } while (0)

__device__ __forceinline__ u16 f2bf(float f) {
  union { float f; uint32_t u; } x; x.f = f;
  uint32_t r = x.u + 0x7fffu + ((x.u >> 16) & 1u);
  return (u16)(r >> 16);
}
__device__ __forceinline__ float bf2f(u16 h) {
  union { uint32_t u; float f; } x; x.u = ((uint32_t)h) << 16;
  return x.f;
}
__device__ __forceinline__ void gload16(const void* g, void* l) {
  __builtin_amdgcn_global_load_lds((const __attribute__((address_space(1))) void*)g,
                                   (__attribute__((address_space(3))) void*)l, 16, 0, 0);
}
__device__ __forceinline__ bf16x8 ld_f32_to_bf8(const float* p) {
  f32x4 a = *(const f32x4*)p, b = *(const f32x4*)(p + 4);
  union { u16x8 u; bf16x8 h; } c;
  c.u[0] = f2bf(a[0]); c.u[1] = f2bf(a[1]); c.u[2] = f2bf(a[2]); c.u[3] = f2bf(a[3]);
  c.u[4] = f2bf(b[0]); c.u[5] = f2bf(b[1]); c.u[6] = f2bf(b[2]); c.u[7] = f2bf(b[3]);
  return c.h;
}

// ---------------- merged prep: hidden->bf16 (blocks 0..8191) + weight transpose (blocks 8192..8959) ----------------
__global__ __launch_bounds__(256) void k_prep(const float* __restrict__ hidden,
                                              const float* __restrict__ Wq, const float* __restrict__ Wk,
                                              const float* __restrict__ Wv,
                                              u16* __restrict__ hb, u16* __restrict__ Wt) {
  __shared__ float tile[64][65];
  const int bx = blockIdx.x;
  const int t = threadIdx.x;
  if (bx < 8192) {
    const size_t i = ((size_t)bx * 256 + t) * 8;
    f32x4 v0 = *(const f32x4*)(hidden + i);
    f32x4 v1 = *(const f32x4*)(hidden + i + 4);
    u16x8 o;
    o[0] = f2bf(v0[0]); o[1] = f2bf(v0[1]); o[2] = f2bf(v0[2]); o[3] = f2bf(v0[3]);
    o[4] = f2bf(v1[0]); o[5] = f2bf(v1[1]); o[6] = f2bf(v1[2]); o[7] = f2bf(v1[3]);
    *(u16x8*)(hb + i) = o;
    return;
  }
  const int bxx = bx - 8192;
  const int w = bxx >> 8, tn = (bxx >> 4) & 15, tk = bxx & 15;
  const float* W = (w == 0) ? Wq : ((w == 1) ? Wk : Wv);
  const int r = t >> 2, c0 = (t & 3) * 16;
  const float* src = W + (size_t)(tk * 64 + r) * 1024 + tn * 64 + c0;
#pragma unroll
  for (int j = 0; j < 16; j += 4) {
    f32x4 x = *(const f32x4*)(src + j);
    tile[r][c0 + j + 0] = x[0]; tile[r][c0 + j + 1] = x[1];
    tile[r][c0 + j + 2] = x[2]; tile[r][c0 + j + 3] = x[3];
  }
  __syncthreads();
  u16* dst = Wt + (size_t)(w * 1024 + tn * 64 + r) * 1024 + tk * 64 + c0;
#pragma unroll
  for (int j = 0; j < 16; ++j) dst[j] = f2bf(tile[c0 + j][r]);
}

// ---------------- 256x256x64 8-wave GEMM, counted-vmcnt cross-barrier pipeline ----------------
__device__ __forceinline__ bf16x8 frg(const u16* buf, int row, int ks, int lhi) {
  const int ck = (ks << 2) + lhi;
  return *reinterpret_cast<const bf16x8*>(buf + (row << 6) + ((ck ^ (row & 7)) << 3));
}
__device__ __forceinline__ void issue(const u16* g, int rowbase, int tc, u16* ldsbase, int wid) {
  gload16(g + (((size_t)rowbase) << 10) + tc, ldsbase + ((rowbase + (wid << 3)) << 6));
}
template <int Q>
__device__ __forceinline__ void quad_mfma(const bf16x8 (&af)[2][2], const bf16x8 (&bf)[4][2],
                                          f32x4 (&acc)[8][4]) {
#pragma unroll
  for (int mm = 0; mm < 2; ++mm)
#pragma unroll
    for (int n = 0; n < 4; ++n) {
      acc[Q * 2 + mm][n] = __builtin_amdgcn_mfma_f32_16x16x32_bf16(af[mm][0], bf[n][0], acc[Q * 2 + mm][n], 0, 0, 0);
      acc[Q * 2 + mm][n] = __builtin_amdgcn_mfma_f32_16x16x32_bf16(af[mm][1], bf[n][1], acc[Q * 2 + mm][n], 0, 0, 0);
    }
}
#define LOADA_TO(dst, Q)                                     \
  dst[0][0] = frg(ASr, rA0 + (Q)*32, 0, lhi);                \
  dst[0][1] = frg(ASr, rA0 + (Q)*32, 1, lhi);                \
  dst[1][0] = frg(ASr, rA0 + (Q)*32 + 16, 0, lhi);           \
  dst[1][1] = frg(ASr, rA0 + (Q)*32 + 16, 1, lhi);

__global__ __launch_bounds__(512) void k_gemm2(const u16* __restrict__ A, const u16* __restrict__ Bt,
                                               const float* __restrict__ bq, const float* __restrict__ bk,
                                               const float* __restrict__ bv,
                                               u16* __restrict__ oq, u16* __restrict__ ok, u16* __restrict__ ov,
                                               float* __restrict__ ql, float* __restrict__ kl) {
  __shared__ __align__(16) u16 AS[2][256 * 64];
  __shared__ __align__(16) u16 BS[2][256 * 64];
  __shared__ __align__(16) u16 obuf[8][16][70];
  const int t = threadIdx.x, lane = t & 63, wid = t >> 6;
  const int wm = wid >> 2, wn = wid & 3;
  const int bm = blockIdx.x, bn = blockIdx.y;
  const int l15 = lane & 15, lhi = lane >> 4;

  const int rowoff = t >> 3;
  const int cswz = (t & 7) ^ (rowoff & 7);
  const u16* aG = A + (((size_t)(bm * 256 + rowoff)) << 10) + (cswz << 3);
  const u16* bG = Bt + (((size_t)(bn * 256 + rowoff)) << 10) + (cswz << 3);

  const int rA0 = wm * 128 + l15;
  const int rB0 = wn * 64 + l15;

  f32x4 acc[8][4];
#pragma unroll
  for (int m = 0; m < 8; ++m)
#pragma unroll
    for (int n = 0; n < 4; ++n) acc[m][n] = (f32x4){0.f, 0.f, 0.f, 0.f};

  // prologue: tile 0 -> buf 0. Order: B x4, A-q01 x2, A-q23 x2.
  issue(bG, 0, 0, BS[0], wid);
  issue(bG, 64, 0, BS[0], wid);
  issue(bG, 128, 0, BS[0], wid);
  issue(bG, 192, 0, BS[0], wid);
  issue(aG, 0, 0, AS[0], wid);
  issue(aG, 128, 0, AS[0], wid);
  issue(aG, 64, 0, AS[0], wid);
  issue(aG, 192, 0, AS[0], wid);
  WAIT_VM(2);  // B + A-q01 landed (all waves rendezvous below); A-q23 in flight
  BAR();

  for (int u = 0; u < 15; ++u) {
    const int pu = u & 1;
    const u16* ASr = AS[pu];
    const u16* BSr = BS[pu];
    u16* ASw = AS[pu ^ 1];
    u16* BSw = BS[pu ^ 1];
    const int tc = (u + 1) << 6;
    bf16x8 bfr[4][2];
    bf16x8 afA[2][2], afB[2][2];
    // P0: read B(8) + A-q0 + A-q1; issue ALL 8 next-tile loads; MFMA q0
#pragma unroll
    for (int n = 0; n < 4; ++n) {
      bfr[n][0] = frg(BSr, rB0 + n * 16, 0, lhi);
      bfr[n][1] = frg(BSr, rB0 + n * 16, 1, lhi);
    }
    LOADA_TO(afA, 0)
    LOADA_TO(afB, 1)
    issue(bG, 0, tc, BSw, wid);
    issue(bG, 64, tc, BSw, wid);
    issue(bG, 128, tc, BSw, wid);
    issue(bG, 192, tc, BSw, wid);
    issue(aG, 0, tc, ASw, wid);
    issue(aG, 128, tc, ASw, wid);
    issue(aG, 64, tc, ASw, wid);
    issue(aG, 192, tc, ASw, wid);
    __builtin_amdgcn_s_setprio(1);
    quad_mfma<0>(afA, bfr, acc);
    __builtin_amdgcn_s_setprio(0);
    WAIT_VM(8);  // cur-tile A-q23 landed (8 next-tile loads remain in flight)
    BAR();       // rendezvous: all waves' A-q23 slices visible
    // P1: read A-q2; MFMA q1
    LOADA_TO(afA, 2)
    __builtin_amdgcn_s_setprio(1);
    quad_mfma<1>(afB, bfr, acc);
    __builtin_amdgcn_s_setprio(0);
    // P2: read A-q3; MFMA q2
    LOADA_TO(afB, 3)
    __builtin_amdgcn_s_setprio(1);
    quad_mfma<2>(afA, bfr, acc);
    __builtin_amdgcn_s_setprio(0);
    // P3: MFMA q3
    __builtin_amdgcn_s_setprio(1);
    quad_mfma<3>(afB, bfr, acc);
    __builtin_amdgcn_s_setprio(0);
    WAIT_VM(2);  // next-tile B + A-q01 landed; A-q23 stays in flight
    BAR();       // tile boundary
  }
  // peeled tile 15 (buf 1, no staging; 2 loads of its A-q23 still in flight at entry)
  {
    const u16* ASr = AS[1];
    const u16* BSr = BS[1];
    bf16x8 bfr[4][2];
    bf16x8 afA[2][2], afB[2][2];
#pragma unroll
    for (int n = 0; n < 4; ++n) {
      bfr[n][0] = frg(BSr, rB0 + n * 16, 0, lhi);
      bfr[n][1] = frg(BSr, rB0 + n * 16, 1, lhi);
    }
    LOADA_TO(afA, 0)
    LOADA_TO(afB, 1)
    quad_mfma<0>(afA, bfr, acc);
    WAIT_VM(0);
    BAR();
    LOADA_TO(afA, 2)
    quad_mfma<1>(afB, bfr, acc);
    LOADA_TO(afB, 3)
    quad_mfma<2>(afA, bfr, acc);
    quad_mfma<3>(afB, bfr, acc);
  }

  // ---- epilogue: bias+scale, LDS bounce, coalesced stores; fused landmark means ----
  const int which = bn >> 2;
  const float* bias = (which == 0) ? bq : ((which == 1) ? bk : bv);
  u16* op = (which == 0) ? oq : ((which == 1) ? ok : ov);
  const float scl = (which < 2) ? SCALE_QK : 1.0f;
  const int h = ((bn & 3) << 2) + wn;  // wave's single head
  const int rowBase2 = (bm << 8) + (wm << 7);
  const int rl = lhi << 2;
  const int srow = lane >> 2, d0 = (lane & 3) * 16;
  float bb[4];
#pragma unroll
  for (int n = 0; n < 4; ++n) bb[n] = bias[((bn & 3) << 8) + (wn << 6) + n * 16 + l15];
#pragma unroll
  for (int m = 0; m < 8; ++m) {
#pragma unroll
    for (int n = 0; n < 4; ++n)
#pragma unroll
      for (int r = 0; r < 4; ++r)
        obuf[wid][rl + r][n * 16 + l15] = f2bf((acc[m][n][r] + bb[n]) * scl);
    const int gm = rowBase2 + m * 16 + srow;
    const int b_ = gm >> 12, s = gm & 4095;
    u16* dst = op + (((size_t)b_ * 16 + h) * 4096 + s) * 64 + d0;
    *(u16x8*)dst = *(const u16x8*)&obuf[wid][srow][d0];
    *(u16x8*)(dst + 8) = *(const u16x8*)&obuf[wid][srow][d0 + 8];
  }
  // landmark segment means (q/k only): wave owns segments {wm*2, wm*2+1} of this bm-block
  if (which < 2) {
    float* lmp = (which == 0) ? ql : kl;
    const int bh = ((bm >> 4) << 4) + h;
#pragma unroll
    for (int sg = 0; sg < 2; ++sg) {
#pragma unroll
      for (int n = 0; n < 4; ++n) {
        float s = 0.f;
#pragma unroll
        for (int mi = 0; mi < 4; ++mi)
#pragma unroll
          for (int r = 0; r < 4; ++r) s += (acc[sg * 4 + mi][n][r] + bb[n]) * scl;
        s += __shfl_xor(s, 16, 64);
        s += __shfl_xor(s, 32, 64);
        if (lhi == 0) {
          const int lseg = ((bm & 15) << 2) + (wm << 1) + sg;
          lmp[(size_t)bh * 4096 + lseg * 64 + n * 16 + l15] = s * 0.015625f;
        }
      }
    }
  }
}

// ---------------- kernel_2 = softmax(ql@kl^T); k2t + colmax; also emit klb bf16 ----------------
__global__ __launch_bounds__(256) void k_k2(const float* __restrict__ ql, const float* __restrict__ kl,
                                            float* __restrict__ k2t, float* __restrict__ colmax,
                                            u16* __restrict__ klb) {
  __shared__ __align__(16) float qlT[64 * 68];
  __shared__ __align__(16) float klT[64 * 68];
  __shared__ __align__(16) float sc[64 * 68];
  const int bh = blockIdx.x, t = threadIdx.x;
  {
    const int r = t >> 2, c0 = (t & 3) * 16;
    const float* qp = ql + (size_t)bh * 4096 + r * 64 + c0;
    const float* kp = kl + (size_t)bh * 4096 + r * 64 + c0;
    u16* kb_ = klb + (size_t)bh * 4096 + r * 64 + c0;
#pragma unroll
    for (int j = 0; j < 16; ++j) {
      qlT[(c0 + j) * 68 + r] = qp[j];
      const float kv = kp[j];
      klT[(c0 + j) * 68 + r] = kv;
      kb_[j] = f2bf(kv);
    }
  }
  __syncthreads();
  {
    const int mg = (t >> 4) * 4, lg = (t & 15) * 4;
    float acc[4][4];
#pragma unroll
    for (int i = 0; i < 4; ++i)
#pragma unroll
      for (int j = 0; j < 4; ++j) acc[i][j] = 0.f;
    for (int d0 = 0; d0 < 64; ++d0) {
      f32x4 x = *(const f32x4*)&qlT[d0 * 68 + mg];
      f32x4 y = *(const f32x4*)&klT[d0 * 68 + lg];
#pragma unroll
      for (int i = 0; i < 4; ++i)
#pragma unroll
        for (int j = 0; j < 4; ++j) acc[i][j] += x[i] * y[j];
    }
#pragma unroll
    for (int i = 0; i < 4; ++i)
#pragma unroll
      for (int j = 0; j < 4; ++j) sc[(mg + i) * 68 + lg + j] = acc[i][j];
  }
  __syncthreads();
  if (t < 64) {
    float mx = -1e30f;
    for (int l = 0; l < 64; ++l) mx = fmaxf(mx, sc[t * 68 + l]);
    float sum = 0.f;
    for (int l = 0; l < 64; ++l) { float e = __expf(sc[t * 68 + l] - mx); sc[t * 68 + l] = e; sum += e; }
    const float inv = 1.0f / sum;
    for (int l = 0; l < 64; ++l) sc[t * 68 + l] *= inv;
  }
  __syncthreads();
  {
    const int r = t >> 2, c0 = (t & 3) * 16;
    float* ot = k2t + (size_t)bh * 4096 + r * 64 + c0;
#pragma unroll
    for (int j = 0; j < 16; ++j) ot[j] = sc[(c0 + j) * 68 + r];
  }
  if (t < 64) {
    float s = 0.f;
    for (int m = 0; m < 64; ++m) s += sc[m * 68 + t];
    for (int off = 32; off; off >>= 1) s = fmaxf(s, __shfl_down(s, off, 64));
    if (t == 0) colmax[bh] = s;
  }
}

// ---------------- iterative pinv (6 iters, f32, 512 threads; global max folded in) ----------------
__global__ __launch_bounds__(512) void k_pinv(const float* __restrict__ k2t, const float* __restrict__ colmax,
                                              float* __restrict__ pinv) {
  __shared__ float valN[4096];
  __shared__ float kvT[4096];
  __shared__ float t1N[4096];
  __shared__ float t2N[4096];
  __shared__ float gsh;
  const int bh = blockIdx.x, t = threadIdx.x;
  const float* aT = k2t + (size_t)bh * 4096;
  if (t < 64) {
    float v = colmax[t];
    for (int off = 32; off; off >>= 1) v = fmaxf(v, __shfl_down(v, off, 64));
    if (t == 0) gsh = v;
  }
  __syncthreads();
  const float ginv = 1.0f / gsh;
  const int rt = t >> 3, ct0 = (t & 7) * 8;
  {
    const float* p = aT + rt * 64 + ct0;
#pragma unroll
    for (int j = 0; j < 8; ++j) valN[rt * 64 + ct0 + j] = p[j] * ginv;
  }
  __syncthreads();
  const int rg = (t >> 4) * 2, cg = (t & 15) * 4;
  float acc[2][4];
  for (int it = 0; it < 6; ++it) {
#pragma unroll
    for (int i = 0; i < 2; ++i)
#pragma unroll
      for (int j = 0; j < 4; ++j) acc[i][j] = 0.f;
    for (int k = 0; k < 64; ++k) {
      const float x0 = aT[k * 64 + rg], x1 = aT[k * 64 + rg + 1];
      f32x4 y = *(const f32x4*)&valN[k * 64 + cg];
#pragma unroll
      for (int j = 0; j < 4; ++j) { acc[0][j] += x0 * y[j]; acc[1][j] += x1 * y[j]; }
    }
#pragma unroll
    for (int i = 0; i < 2; ++i)
#pragma unroll
      for (int j = 0; j < 4; ++j) kvT[(cg + j) * 64 + rg + i] = acc[i][j];
    __syncthreads();
#pragma unroll
    for (int j = 0; j < 8; ++j) {
      const int c = ct0 + j;
      t1N[rt * 64 + c] = ((rt == c) ? 7.0f : 0.0f) - kvT[c * 64 + rt];
    }
    __syncthreads();
#pragma unroll
    for (int i = 0; i < 2; ++i)
#pragma unroll
      for (int j = 0; j < 4; ++j) acc[i][j] = 0.f;
    for (int k = 0; k < 64; ++k) {
      const float x0 = kvT[k * 64 + rg], x1 = kvT[k * 64 + rg + 1];
      f32x4 y = *(const f32x4*)&t1N[k * 64 + cg];
#pragma unroll
      for (int j = 0; j < 4; ++j) { acc[0][j] += x0 * y[j]; acc[1][j] += x1 * y[j]; }
    }
#pragma unroll
    for (int i = 0; i < 2; ++i)
#pragma unroll
      for (int j = 0; j < 4; ++j) {
        const int r_ = rg + i, c_ = cg + j;
        t2N[r_ * 64 + c_] = ((r_ == c_) ? 15.0f : 0.0f) - acc[i][j];
      }
    __syncthreads();
#pragma unroll
    for (int i = 0; i < 2; ++i)
#pragma unroll
      for (int j = 0; j < 4; ++j) acc[i][j] = 0.f;
    for (int k = 0; k < 64; ++k) {
      const float x0 = kvT[k * 64 + rg], x1 = kvT[k * 64 + rg + 1];
      f32x4 y = *(const f32x4*)&t2N[k * 64 + cg];
#pragma unroll
      for (int j = 0; j < 4; ++j) { acc[0][j] += x0 * y[j]; acc[1][j] += x1 * y[j]; }
    }
#pragma unroll
    for (int i = 0; i < 2; ++i)
#pragma unroll
      for (int j = 0; j < 4; ++j) {
        const int r_ = rg + i, c_ = cg + j;
        t1N[r_ * 64 + c_] = ((r_ == c_) ? 13.0f : 0.0f) - acc[i][j];
      }
    __syncthreads();
#pragma unroll
    for (int j = 0; j < 8; ++j) t2N[(ct0 + j) * 64 + rt] = valN[rt * 64 + ct0 + j];
    __syncthreads();
#pragma unroll
    for (int i = 0; i < 2; ++i)
#pragma unroll
      for (int j = 0; j < 4; ++j) acc[i][j] = 0.f;
    for (int k = 0; k < 64; ++k) {
      const float x0 = t2N[k * 64 + rg], x1 = t2N[k * 64 + rg + 1];
      f32x4 y = *(const f32x4*)&t1N[k * 64 + cg];
#pragma unroll
      for (int j = 0; j < 4; ++j) { acc[0][j] += x0 * y[j]; acc[1][j] += x1 * y[j]; }
    }
#pragma unroll
    for (int i = 0; i < 2; ++i)
#pragma unroll
      for (int j = 0; j < 4; ++j) valN[(rg + i) * 64 + cg + j] = 0.25f * acc[i][j];
    __syncthreads();
  }
  {
    float* o = pinv + (size_t)bh * 4096 + rt * 64 + ct0;
#pragma unroll
    for (int j = 0; j < 8; ++j) o[j] = valN[rt * 64 + ct0 + j];
  }
}

// ---------------- fused s3+nv: ping-pong VT, V-prefetch, 1 barrier/iter ----------------
__global__ __launch_bounds__(256) void k_s3nv(const float* __restrict__ ql, const u16* __restrict__ kb,
                                              const u16* __restrict__ vb,
                                              float* __restrict__ nvp, float* __restrict__ zp) {
  __shared__ __align__(16) u16 VT[2][64][72];
  __shared__ __align__(16) u16 e_lds[4][16][72];
  const int bh = blockIdx.x, scn = blockIdx.y;  // scn < 8, covers 512 rows
  const int t = threadIdx.x, lane = t & 63, w = t >> 6;
  const int l15 = lane & 15, kg = (lane >> 4) << 3, rl = (lane >> 4) << 2;
  const float* aRow = ql + (size_t)bh * 4096 + (w * 16 + l15) * 64 + kg;
  bf16x8 aql[2];
  aql[0] = ld_f32_to_bf8(aRow);
  aql[1] = ld_f32_to_bf8(aRow + 32);
  f32x4 accv[4];
#pragma unroll
  for (int n = 0; n < 4; ++n) accv[n] = (f32x4){0.f, 0.f, 0.f, 0.f};
  float zacc[4] = {0.f, 0.f, 0.f, 0.f};
  const int sBase = scn * 512;
  // preload sub 0 into VT[0]
  {
    const u16* vp = vb + ((size_t)bh * 4096 + sBase + lane) * 64 + w * 16;
    u16x8 h0 = *(const u16x8*)vp, h1 = *(const u16x8*)(vp + 8);
#pragma unroll
    for (int j = 0; j < 8; ++j) { VT[0][w * 16 + j][lane] = h0[j]; VT[0][w * 16 + 8 + j][lane] = h1[j]; }
  }
  __syncthreads();
  for (int sub = 0; sub < 8; ++sub) {
    const int s0 = sBase + sub * 64;
    u16x8 hn0 = {0,0,0,0,0,0,0,0}, hn1 = {0,0,0,0,0,0,0,0};
    if (sub < 7) {  // prefetch next V tile into regs (latency hides under K-MFMA/exp)
      const u16* vpn = vb + ((size_t)bh * 4096 + s0 + 64 + lane) * 64 + w * 16;
      hn0 = *(const u16x8*)vpn; hn1 = *(const u16x8*)(vpn + 8);
    }
    const u16* bRow = kb + ((size_t)bh * 4096 + s0 + l15) * 64 + kg;
    f32x4 e[4];
#pragma unroll
    for (int n = 0; n < 4; ++n) e[n] = (f32x4){0.f, 0.f, 0.f, 0.f};
#pragma unroll
    for (int ks = 0; ks < 2; ++ks)
#pragma unroll
      for (int n = 0; n < 4; ++n) {
        bf16x8 bk = *reinterpret_cast<const bf16x8*>(bRow + n * 1024 + ks * 32);
        e[n] = __builtin_amdgcn_mfma_f32_16x16x32_bf16(aql[ks], bk, e[n], 0, 0, 0);
      }
#pragma unroll
    for (int n = 0; n < 4; ++n)
#pragma unroll
      for (int r = 0; r < 4; ++r) {
        const float v = __expf(e[n][r]);
        zacc[r] += v;
        e_lds[w][rl + r][n * 16 + l15] = f2bf(v);
      }
    if (sub < 7) {
      const int nb = (sub + 1) & 1;
#pragma unroll
      for (int j = 0; j < 8; ++j) { VT[nb][w * 16 + j][lane] = hn0[j]; VT[nb][w * 16 + 8 + j][lane] = hn1[j]; }
    }
    WAIT_LGKM0();  // own e_lds + VT writes complete
    const int cb = sub & 1;
#pragma unroll
    for (int ks = 0; ks < 2; ++ks) {
      bf16x8 af = *reinterpret_cast<const bf16x8*>(&e_lds[w][l15][kg + ks * 32]);
#pragma unroll
      for (int n = 0; n < 4; ++n) {
        bf16x8 bf_ = *reinterpret_cast<const bf16x8*>(&VT[cb][n * 16 + l15][kg + ks * 32]);
        accv[n] = __builtin_amdgcn_mfma_f32_16x16x32_bf16(af, bf_, accv[n], 0, 0, 0);
      }
    }
    BAR();  // publish VT[(sub+1)&1] for next iter; separates WAR on VT[sub&1]
  }
#pragma unroll
  for (int r = 0; r < 4; ++r)
#pragma unroll
    for (int n = 0; n < 4; ++n)
      nvp[(((size_t)scn * 64 + bh) * 64 + w * 16 + rl + r) * 64 + n * 16 + l15] = accv[n][r];
#pragma unroll
  for (int r = 0; r < 4; ++r) {
    float s = zacc[r];
    s += __shfl_xor(s, 1, 64); s += __shfl_xor(s, 2, 64);
    s += __shfl_xor(s, 4, 64); s += __shfl_xor(s, 8, 64);
    if (l15 == 0) zp[((size_t)scn * 64 + bh) * 64 + w * 16 + rl + r] = s;
  }
}

// ---------------- M^T (bf16) = (pinv @ (sum(nvp)/sum(zp)))^T ----------------
__global__ __launch_bounds__(256) void k_pnv(const float* __restrict__ pinv, const float* __restrict__ nvp,
                                             const float* __restrict__ zp, u16* __restrict__ Mtb) {
  __shared__ __align__(16) float XT[64 * 68];
  __shared__ __align__(16) float Y[64 * 68];
  const int bh = blockIdx.x, t = threadIdx.x;
  {
    const int r = t >> 2, c0 = (t & 3) * 16;
    const float* pp = pinv + (size_t)bh * 4096 + r * 64 + c0;
#pragma unroll
    for (int j = 0; j < 16; ++j) XT[(c0 + j) * 68 + r] = pp[j];
    float zs = 0.f;
#pragma unroll
    for (int p = 0; p < 8; ++p) zs += zp[((size_t)p * 64 + bh) * 64 + r];
    const float iz = 1.0f / zs;
#pragma unroll
    for (int j = 0; j < 16; ++j) {
      float s = 0.f;
#pragma unroll
      for (int p = 0; p < 8; ++p) s += nvp[(((size_t)p * 64 + bh) * 64 + r) * 64 + c0 + j];
      Y[r * 68 + c0 + j] = s * iz;
    }
  }
  __syncthreads();
  const int rg = (t >> 4) * 4, cg = (t & 15) * 4;
  float acc[4][4];
#pragma unroll
  for (int i = 0; i < 4; ++i)
#pragma unroll
    for (int j = 0; j < 4; ++j) acc[i][j] = 0.f;
  for (int k = 0; k < 64; ++k) {
    f32x4 x = *(const f32x4*)&XT[k * 68 + rg];
    f32x4 y = *(const f32x4*)&Y[k * 68 + cg];
#pragma unroll
    for (int i = 0; i < 4; ++i)
#pragma unroll
      for (int j = 0; j < 4; ++j) acc[i][j] += x[i] * y[j];
  }
#pragma unroll
  for (int j = 0; j < 4; ++j) {
    u16x4 o = {f2bf(acc[0][j]), f2bf(acc[1][j]), f2bf(acc[2][j]), f2bf(acc[3][j])};
    *(u16x4*)&Mtb[(size_t)bh * 4096 + (cg + j) * 64 + rg] = o;
  }
}

// ---------------- final: softmax(q·kl^T) @ M^T + depthwise conv ----------------
__global__ __launch_bounds__(256) void k_out(const u16* __restrict__ qb, const u16* __restrict__ vb,
                                             const u16* __restrict__ klb, const u16* __restrict__ Mtb,
                                             const float* __restrict__ cw, float* __restrict__ out) {
  __shared__ __align__(16) u16 P_lds[4][16][72];
  __shared__ __align__(16) u16 vtile_t[64][100];  // [d][row]
  __shared__ float wsh[33];
  const int bid = blockIdx.x;
  const int bh = bid >> 6, st = bid & 63;
  const int b = bh >> 4, h = bh & 15;
  const int t = threadIdx.x, lane = t & 63, w = t >> 6;
  const int sbase = st * 64;
  const int l15 = lane & 15, kg = (lane >> 4) << 3, rl = (lane >> 4) << 2;

  if (t < 33) wsh[t] = cw[h * 33 + t];
  for (int idx = t; idx < 96 * 8; idx += 256) {
    const int row = idx >> 3, c8 = idx & 7;
    const int sg = sbase + row - 16;
    u16x8 val = {0, 0, 0, 0, 0, 0, 0, 0};
    if (sg >= 0 && sg < 4096) val = *(const u16x8*)(vb + ((size_t)bh * 4096 + sg) * 64 + c8 * 8);
#pragma unroll
    for (int j = 0; j < 8; ++j) vtile_t[c8 * 8 + j][row] = val[j];
  }

  f32x4 c1[4];
#pragma unroll
  for (int n = 0; n < 4; ++n) c1[n] = (f32x4){0.f, 0.f, 0.f, 0.f};
  {
    const u16* aRow = qb + ((size_t)bh * 4096 + sbase + w * 16 + l15) * 64 + kg;
    const u16* kRow = klb + (size_t)bh * 4096 + l15 * 64 + kg;
#pragma unroll
    for (int ks = 0; ks < 2; ++ks) {
      bf16x8 af = *reinterpret_cast<const bf16x8*>(aRow + ks * 32);
#pragma unroll
      for (int n = 0; n < 4; ++n) {
        bf16x8 bf_ = *reinterpret_cast<const bf16x8*>(kRow + n * 1024 + ks * 32);
        c1[n] = __builtin_amdgcn_mfma_f32_16x16x32_bf16(af, bf_, c1[n], 0, 0, 0);
      }
    }
  }
  float invZ[4];
  {
    float z[4] = {0.f, 0.f, 0.f, 0.f};
#pragma unroll
    for (int n = 0; n < 4; ++n)
#pragma unroll
      for (int r = 0; r < 4; ++r) { float v = __expf(c1[n][r]); c1[n][r] = v; z[r] += v; }
#pragma unroll
    for (int r = 0; r < 4; ++r) {
      float s = z[r];
      s += __shfl_xor(s, 1, 64); s += __shfl_xor(s, 2, 64);
      s += __shfl_xor(s, 4, 64); s += __shfl_xor(s, 8, 64);
      invZ[r] = 1.0f / s;
    }
#pragma unroll
    for (int n = 0; n < 4; ++n)
#pragma unroll
      for (int r = 0; r < 4; ++r)
        P_lds[w][rl + r][n * 16 + l15] = f2bf(c1[n][r]);
  }
  __syncthreads();
  f32x4 c2[4];
#pragma unroll
  for (int n = 0; n < 4; ++n) c2[n] = (f32x4){0.f, 0.f, 0.f, 0.f};
  {
    const u16* mRow = Mtb + (size_t)bh * 4096 + l15 * 64 + kg;
#pragma unroll
    for (int ks = 0; ks < 2; ++ks) {
      bf16x8 af = *reinterpret_cast<const bf16x8*>(&P_lds[w][l15][kg + ks * 32]);
#pragma unroll
      for (int n = 0; n < 4; ++n) {
        bf16x8 bf_ = *reinterpret_cast<const bf16x8*>(mRow + n * 1024 + ks * 32);
        c2[n] = __builtin_amdgcn_mfma_f32_16x16x32_bf16(af, bf_, c2[n], 0, 0, 0);
      }
    }
  }
  const int base = w * 16 + rl;
#pragma unroll
  for (int n = 0; n < 4; ++n) {
    const int d = n * 16 + l15;
    float vcol[36];
#pragma unroll
    for (int k8 = 0; k8 < 9; ++k8) {
      u16x4 vq = *(const u16x4*)&vtile_t[d][base + k8 * 4];
      vcol[k8 * 4 + 0] = bf2f(vq[0]); vcol[k8 * 4 + 1] = bf2f(vq[1]);
      vcol[k8 * 4 + 2] = bf2f(vq[2]); vcol[k8 * 4 + 3] = bf2f(vq[3]);
    }
    float cv[4] = {0.f, 0.f, 0.f, 0.f};
#pragma unroll
    for (int jt = 0; jt < 33; ++jt) {
      const float ww = wsh[jt];
#pragma unroll
      for (int r = 0; r < 4; ++r) cv[r] += ww * vcol[r + jt];
    }
#pragma unroll
    for (int r = 0; r < 4; ++r) {
      const int sgl = sbase + base + r;
      out[((size_t)b * 4096 + sgl) * 1024 + h * 64 + d] = c2[n][r] * invZ[r] + cv[r];
    }
  }
}

extern "C" void kernel_launch(void* const* d_in, const int* in_sizes, int n_in,
                              void* d_out, int out_size, void* d_ws, size_t ws_size,
                              hipStream_t stream) {
  const float* hidden = (const float*)d_in[0];
  const float* Wq = (const float*)d_in[1];
  const float* bq = (const float*)d_in[2];
  const float* Wk = (const float*)d_in[3];
  const float* bk = (const float*)d_in[4];
  const float* Wv = (const float*)d_in[5];
  const float* bv = (const float*)d_in[6];
  const float* cw = (const float*)d_in[7];
  float* out = (float*)d_out;

  char* ws = (char*)d_ws;
  u16* qb = (u16*)(ws);                           // 32MB
  u16* kb = (u16*)(ws + 33554432ull);             // 32MB
  u16* vb = (u16*)(ws + 67108864ull);             // 32MB
  float* ql = (float*)(ws + 100663296ull);        // 1MB
  float* kl = (float*)(ws + 101711872ull);        // 1MB
  float* k2t = (float*)(ws + 102760448ull);       // 1MB
  float* pinvb = (float*)(ws + 103809024ull);     // 1MB
  u16* Mtb = (u16*)(ws + 104857600ull);           // 512KB
  u16* klb = (u16*)(ws + 105381888ull);           // 1MB
  float* stats = (float*)(ws + 106430464ull);     // 4KB
  u16* wt = (u16*)(ws + 106434560ull);            // 6MB, dead after k_gemm2
  u16* hb = (u16*)(ws + 112726016ull);            // 32MB, dead after k_gemm2
  float* nvp = (float*)(ws + 112726016ull);       // 8MB, aliases hb (dead)
  float* zp = (float*)(ws + 121114624ull);        // 128KB

  k_prep<<<8960, 256, 0, stream>>>(hidden, Wq, Wk, Wv, hb, wt);
  k_gemm2<<<dim3(64, 12), 512, 0, stream>>>(hb, wt, bq, bk, bv, qb, kb, vb, ql, kl);
  k_k2<<<64, 256, 0, stream>>>(ql, kl, k2t, stats, klb);
  k_pinv<<<64, 512, 0, stream>>>(k2t, stats, pinvb);
  k_s3nv<<<dim3(64, 8), 256, 0, stream>>>(ql, kb, vb, nvp, zp);
  k_pnv<<<64, 256, 0, stream>>>(pinvb, nvp, zp, Mtb);
  k_out<<<4096, 256, 0, stream>>>(qb, vb, klb, Mtb, cw, out);
  (void)in_sizes; (void)n_in; (void)out_size; (void)ws_size;
}